// Round 5
// baseline (2857.317 us; speedup 1.0000x reference)
//
#include <hip/hip_runtime.h>
#include <cstdint>

static constexpr int N_NODES = 300000;
static constexpr int N_NETS  = 200000;
static constexpr int E_SINK  = 1000000;
static constexpr int NODE_DIM = 32;
static constexpr int NET_DIM  = 16;
static constexpr int EMB = 64;
static constexpr int NUM_VN = 1000;
#define SLOPE 0.01f

typedef __attribute__((ext_vector_type(8))) short bhalf8;
typedef __attribute__((ext_vector_type(4))) float floatx4;

__device__ __forceinline__ float leaky(float x) { return x >= 0.f ? x : SLOPE * x; }

// ---------- bf16 split helpers ----------
__device__ __forceinline__ unsigned bf16_rne(float x) {
    unsigned u = __float_as_uint(x);
    return (u + 0x7FFFu + ((u >> 16) & 1u)) >> 16;
}
__device__ __forceinline__ void split8(const float* x, bhalf8& ah, bhalf8& al) {
#pragma unroll
    for (int e = 0; e < 8; ++e) {
        unsigned h = bf16_rne(x[e]);
        float fh = __uint_as_float(h << 16);
        unsigned l = bf16_rne(x[e] - fh);
        ah[e] = (short)h; al[e] = (short)l;
    }
}

template<bool LK>
__device__ __forceinline__ void afrag_g(const float* rowp, int kbase, bhalf8& ah, bhalf8& al) {
    float4 v0 = *(const float4*)(rowp + kbase);
    float4 v1 = *(const float4*)(rowp + kbase + 4);
    float x[8] = {v0.x, v0.y, v0.z, v0.w, v1.x, v1.y, v1.z, v1.w};
    if (LK) {
#pragma unroll
        for (int e = 0; e < 8; ++e) x[e] = leaky(x[e]);
    }
    split8(x, ah, al);
}

__device__ __forceinline__ void afrag_l(const float* tp, bhalf8& ah, bhalf8& al) {
    float4 v0 = *(const float4*)tp;
    float4 v1 = *(const float4*)(tp + 4);
    float x[8] = {v0.x, v0.y, v0.z, v0.w, v1.x, v1.y, v1.z, v1.w};
    split8(x, ah, al);
}

__device__ __forceinline__ void wfrag(const float* W, int cols, int K, int col, bool colok,
                                      int kt, int g, bhalf8& wh, bhalf8& wl) {
    float x[8];
#pragma unroll
    for (int e = 0; e < 8; ++e) {
        int k = kt * 32 + g * 8 + e;
        x[e] = (k < K && colok) ? W[(size_t)k * cols + col] : 0.f;
    }
    split8(x, wh, wl);
}

__device__ __forceinline__ floatx4 mm3(bhalf8 ah, bhalf8 al, bhalf8 wh, bhalf8 wl, floatx4 c) {
    c = __builtin_amdgcn_mfma_f32_16x16x32_bf16(ah, wh, c, 0, 0, 0);
    c = __builtin_amdgcn_mfma_f32_16x16x32_bf16(ah, wl, c, 0, 0, 0);
    c = __builtin_amdgcn_mfma_f32_16x16x32_bf16(al, wh, c, 0, 0, 0);
    return c;
}

// ===================== CSR build =====================
__global__ void k_hist_edges(const int* __restrict__ sink_nets, const int* __restrict__ sink_nodes,
                             int* __restrict__ cnt_net, int* __restrict__ cnt_node)
{
    int e = blockIdx.x * 256 + threadIdx.x;
    if (e >= E_SINK) return;
    atomicAdd(&cnt_net[sink_nets[e]], 1);
    atomicAdd(&cnt_node[sink_nodes[e]], 1);
}

__global__ void k_hist_misc(const int* __restrict__ src_nodes, const int* __restrict__ batch,
                            int* __restrict__ cnt_src, int* __restrict__ cnt_vn)
{
    int i = blockIdx.x * 256 + threadIdx.x;
    if (i < N_NETS) atomicAdd(&cnt_src[src_nodes[i]], 1);
    if (i < N_NODES) atomicAdd(&cnt_vn[batch[i]], 1);
}

__global__ void k_scan1(const int* __restrict__ cnt, int n, int* __restrict__ bsum) {
    __shared__ int s[256];
    int i = blockIdx.x * 256 + threadIdx.x;
    s[threadIdx.x] = (i < n) ? cnt[i] : 0;
    __syncthreads();
    for (int off = 128; off; off >>= 1) {
        if (threadIdx.x < off) s[threadIdx.x] += s[threadIdx.x + off];
        __syncthreads();
    }
    if (threadIdx.x == 0) bsum[blockIdx.x] = s[0];
}

__global__ void k_scan2(int* __restrict__ data, int n) {
    __shared__ int s[256];
    __shared__ int carry_s;
    int tid = threadIdx.x;
    if (tid == 0) carry_s = 0;
    __syncthreads();
    for (int base = 0; base < n; base += 256) {
        int i = base + tid;
        int v = (i < n) ? data[i] : 0;
        s[tid] = v;
        __syncthreads();
        for (int off = 1; off < 256; off <<= 1) {
            int t = (tid >= off) ? s[tid - off] : 0;
            __syncthreads();
            s[tid] += t;
            __syncthreads();
        }
        int excl = s[tid] - v + carry_s;
        if (i < n) data[i] = excl;
        __syncthreads();
        if (tid == 255) carry_s = excl + v;
        __syncthreads();
    }
}

__global__ void k_scan3(const int* __restrict__ cnt, int n, const int* __restrict__ bsum,
                        int* __restrict__ start) {
    __shared__ int s[256];
    int i = blockIdx.x * 256 + threadIdx.x;
    int v = (i < n) ? cnt[i] : 0;
    s[threadIdx.x] = v;
    __syncthreads();
    for (int off = 1; off < 256; off <<= 1) {
        int t = (threadIdx.x >= off) ? s[threadIdx.x - off] : 0;
        __syncthreads();
        s[threadIdx.x] += t;
        __syncthreads();
    }
    int excl = s[threadIdx.x] - v + bsum[blockIdx.x];
    if (i < n) start[i] = excl;
    if (i == n - 1) start[n] = excl + v;
}

__global__ void k_fill_edges(const int* __restrict__ sink_nets, const int* __restrict__ sink_nodes,
                             const float* __restrict__ ew,
                             const int* __restrict__ net_start, const int* __restrict__ node_start,
                             int* __restrict__ cur_net, int* __restrict__ cur_node,
                             int* __restrict__ e_node, float* __restrict__ e_w,
                             int* __restrict__ e2_net, float* __restrict__ e2_w)
{
    int e = blockIdx.x * 256 + threadIdx.x;
    if (e >= E_SINK) return;
    int tn = sink_nets[e], dn = sink_nodes[e];
    float w = ew[e];
    int p = net_start[tn] + atomicAdd(&cur_net[tn], 1);
    e_node[p] = dn; e_w[p] = w;
    int q = node_start[dn] + atomicAdd(&cur_node[dn], 1);
    e2_net[q] = tn; e2_w[q] = w;
}

__global__ void k_fill_misc(const int* __restrict__ src_nodes, const int* __restrict__ batch,
                            const int* __restrict__ src_start, const int* __restrict__ vn_start,
                            int* __restrict__ cur_src, int* __restrict__ cur_vn,
                            int* __restrict__ s_net, int* __restrict__ b_node)
{
    int i = blockIdx.x * 256 + threadIdx.x;
    if (i < N_NETS) {
        int d = src_nodes[i];
        int p = src_start[d] + atomicAdd(&cur_src[d], 1);
        s_net[p] = i;
    }
    if (i < N_NODES) {
        int v = batch[i];
        int p = vn_start[v] + atomicAdd(&cur_vn[v], 1);
        b_node[p] = i;
    }
}

// ================= fused node encoder: 32 -> 128 (leaky) -> 64 =================
__global__ __launch_bounds__(256) void k_node_enc_mfma(
    const float* __restrict__ x, const float* __restrict__ W1, const float* __restrict__ b1,
    const float* __restrict__ W2, const float* __restrict__ b2, float* __restrict__ h)
{
    __shared__ __align__(16) float t[64][132];
    int lane = threadIdx.x & 63, wid = threadIdx.x >> 6;
    int g16 = lane >> 4, l15 = lane & 15;
    int rbase = blockIdx.x * 64;

    bhalf8 W1H[2], W1L[2];
#pragma unroll
    for (int s = 0; s < 2; ++s)
        wfrag(W1, 128, 32, wid * 16 + s * 64 + l15, true, 0, g16, W1H[s], W1L[s]);
    bhalf8 W2H[4], W2L[4];
#pragma unroll
    for (int kt = 0; kt < 4; ++kt)
        wfrag(W2, 64, 128, wid * 16 + l15, true, kt, g16, W2H[kt], W2L[kt]);

#pragma unroll
    for (int ms = 0; ms < 4; ++ms) {
        int r = min(rbase + ms * 16 + l15, N_NODES - 1);
        bhalf8 ah, al;
        afrag_g<false>(x + (size_t)r * NODE_DIM, g16 * 8, ah, al);
#pragma unroll
        for (int s = 0; s < 2; ++s) {
            floatx4 acc = {0.f, 0.f, 0.f, 0.f};
            acc = mm3(ah, al, W1H[s], W1L[s], acc);
            int hc = wid * 16 + s * 64 + l15;
            float bb = b1[hc];
#pragma unroll
            for (int i = 0; i < 4; ++i)
                t[ms * 16 + g16 * 4 + i][hc] = leaky(acc[i] + bb);
        }
    }
    __syncthreads();

    int cs = wid * 16 + l15;
    float bias = b2[cs];
#pragma unroll
    for (int ms = 0; ms < 4; ++ms) {
        floatx4 acc = {0.f, 0.f, 0.f, 0.f};
#pragma unroll
        for (int kt = 0; kt < 4; ++kt) {
            bhalf8 ah, al;
            afrag_l(&t[ms * 16 + l15][kt * 32 + g16 * 8], ah, al);
            acc = mm3(ah, al, W2H[kt], W2L[kt], acc);
        }
#pragma unroll
        for (int i = 0; i < 4; ++i) {
            int r = rbase + ms * 16 + g16 * 4 + i;
            if (r < N_NODES) h[(size_t)r * 64 + cs] = acc[i] + bias;
        }
    }
}

// ================= fused net encoder: 16 -> 64 (leaky) -> 64 =================
__global__ __launch_bounds__(256) void k_net_enc_mfma(
    const float* __restrict__ x, const float* __restrict__ W1, const float* __restrict__ b1,
    const float* __restrict__ W2, const float* __restrict__ b2, float* __restrict__ g)
{
    __shared__ __align__(16) float t[64][68];
    int lane = threadIdx.x & 63, wid = threadIdx.x >> 6;
    int g16 = lane >> 4, l15 = lane & 15;
    int rbase = blockIdx.x * 64;
    int cs = wid * 16 + l15;

    bhalf8 W1H, W1L;
    wfrag(W1, 64, 16, cs, true, 0, g16, W1H, W1L);
    bhalf8 W2H[2], W2L[2];
#pragma unroll
    for (int kt = 0; kt < 2; ++kt)
        wfrag(W2, 64, 64, cs, true, kt, g16, W2H[kt], W2L[kt]);

#pragma unroll
    for (int ms = 0; ms < 4; ++ms) {
        int r = min(rbase + ms * 16 + l15, N_NETS - 1);
        bhalf8 ah = {0,0,0,0,0,0,0,0}, al = {0,0,0,0,0,0,0,0};
        if (g16 < 2) afrag_g<false>(x + (size_t)r * NET_DIM, g16 * 8, ah, al);
        floatx4 acc = {0.f, 0.f, 0.f, 0.f};
        acc = mm3(ah, al, W1H, W1L, acc);
        float bb = b1[cs];
#pragma unroll
        for (int i = 0; i < 4; ++i)
            t[ms * 16 + g16 * 4 + i][cs] = leaky(acc[i] + bb);
    }
    __syncthreads();

    float bias = b2[cs];
#pragma unroll
    for (int ms = 0; ms < 4; ++ms) {
        floatx4 acc = {0.f, 0.f, 0.f, 0.f};
#pragma unroll
        for (int kt = 0; kt < 2; ++kt) {
            bhalf8 ah, al;
            afrag_l(&t[ms * 16 + l15][kt * 32 + g16 * 8], ah, al);
            acc = mm3(ah, al, W2H[kt], W2L[kt], acc);
        }
#pragma unroll
        for (int i = 0; i < 4; ++i) {
            int r = rbase + ms * 16 + g16 * 4 + i;
            if (r < N_NETS) g[(size_t)r * 64 + cs] = acc[i] + bias;
        }
    }
}

// ================= misc elementwise =================
__global__ void k_vn_init(float* __restrict__ vn, const float* __restrict__ vn_emb) {
    int idx = blockIdx.x * blockDim.x + threadIdx.x;
    if (idx < NUM_VN * EMB) vn[idx] = vn_emb[idx & 63];
}

__global__ void k_add_vn(float4* __restrict__ h4, const float* __restrict__ vn,
                         const int* __restrict__ batch) {
    int idx = blockIdx.x * blockDim.x + threadIdx.x;
    if (idx >= N_NODES * 16) return;
    int n = idx >> 4, c4 = idx & 15;
    const float4* vr = (const float4*)(vn + (size_t)batch[n] * 64);
    float4 hv = h4[idx], vv = vr[c4];
    h4[idx] = make_float4(hv.x + vv.x, hv.y + vv.y, hv.z + vv.z, hv.w + vv.w);
}

// ===== conv_net fused: agg gather (CSR) + g_new = cat(g|leaky, h[src], agg) @ W + b =====
__global__ __launch_bounds__(256) void k_conv_net_fused(
    float* __restrict__ g, const float* __restrict__ h, const int* __restrict__ src,
    const int* __restrict__ net_start, const int* __restrict__ e_node, const float* __restrict__ e_w,
    const float* __restrict__ W, const float* __restrict__ b, int lk0)
{
    __shared__ __align__(16) float aggT[64][68];
    int lane = threadIdx.x & 63, wid = threadIdx.x >> 6;
    int g16 = lane >> 4, l15 = lane & 15;
    int rbase = blockIdx.x * 64;
    int cs = wid * 16 + l15;

    bhalf8 WH[6], WL[6];
#pragma unroll
    for (int kt = 0; kt < 6; ++kt) wfrag(W, 64, 192, cs, true, kt, g16, WH[kt], WL[kt]);

    // prefetch in-place seg0 (g) fragments (all g reads precede the barrier)
    bhalf8 GH[4][2], GL[4][2];
#pragma unroll
    for (int ms = 0; ms < 4; ++ms) {
        int r = min(rbase + ms * 16 + l15, N_NETS - 1);
        const float* rp = g + (size_t)r * 64;
#pragma unroll
        for (int kt = 0; kt < 2; ++kt) {
            if (lk0) afrag_g<true>(rp, kt * 32 + g16 * 8, GH[ms][kt], GL[ms][kt]);
            else     afrag_g<false>(rp, kt * 32 + g16 * 8, GH[ms][kt], GL[ms][kt]);
        }
    }

    // CSR gather: agg_sink rows for this block -> LDS
#pragma unroll 1
    for (int rr = 0; rr < 16; ++rr) {
        int r = rbase + wid * 16 + rr;
        float acc = 0.f;
        if (r < N_NETS) {
            int j0 = net_start[r], j1 = net_start[r + 1];
            for (int jb = j0; jb < j1; jb += 64) {
                int nj = min(64, j1 - jb);
                int mi = 0; float mw = 0.f;
                if (lane < nj) { mi = e_node[jb + lane]; mw = e_w[jb + lane]; }
                for (int t = 0; t < nj; ++t) {
                    int idx = __shfl(mi, t, 64);
                    float w = __shfl(mw, t, 64);
                    acc += h[(size_t)idx * 64 + lane] * w;
                }
            }
        }
        aggT[wid * 16 + rr][lane] = acc;
    }
    __syncthreads();

    float bias = b[cs];
#pragma unroll
    for (int ms = 0; ms < 4; ++ms) {
        floatx4 acc = {0.f, 0.f, 0.f, 0.f};
#pragma unroll
        for (int kt = 0; kt < 2; ++kt) acc = mm3(GH[ms][kt], GL[ms][kt], WH[kt], WL[kt], acc);
        int ar = min(rbase + ms * 16 + l15, N_NETS - 1);
        const float* hp = h + (size_t)src[ar] * 64;
#pragma unroll
        for (int kt = 0; kt < 2; ++kt) {
            bhalf8 ah, al;
            afrag_g<false>(hp, kt * 32 + g16 * 8, ah, al);
            acc = mm3(ah, al, WH[2 + kt], WL[2 + kt], acc);
        }
#pragma unroll
        for (int kt = 0; kt < 2; ++kt) {
            bhalf8 ah, al;
            afrag_l(&aggT[ms * 16 + l15][kt * 32 + g16 * 8], ah, al);
            acc = mm3(ah, al, WH[4 + kt], WL[4 + kt], acc);
        }
#pragma unroll
        for (int i = 0; i < 4; ++i) {
            int r = rbase + ms * 16 + g16 * 4 + i;
            if (r < N_NETS) g[(size_t)r * 64 + cs] = acc[i] + bias;
        }
    }
}

// ===== conv_node fused: back gather (2 CSRs) + h_new = leaky(cat(h, back) @ W + b) =====
__global__ __launch_bounds__(256) void k_conv_node_fused(
    float* __restrict__ h, const float* __restrict__ g,
    const int* __restrict__ src_start, const int* __restrict__ s_net,
    const int* __restrict__ node_start, const int* __restrict__ e2_net, const float* __restrict__ e2_w,
    const float* __restrict__ W, const float* __restrict__ b)
{
    __shared__ __align__(16) float backT[64][68];
    int lane = threadIdx.x & 63, wid = threadIdx.x >> 6;
    int g16 = lane >> 4, l15 = lane & 15;
    int rbase = blockIdx.x * 64;
    int cs = wid * 16 + l15;

    bhalf8 WH[4], WL[4];
#pragma unroll
    for (int kt = 0; kt < 4; ++kt) wfrag(W, 64, 128, cs, true, kt, g16, WH[kt], WL[kt]);

    // prefetch in-place seg0 (h) fragments (all h reads precede the barrier)
    bhalf8 HH[4][2], HL[4][2];
#pragma unroll
    for (int ms = 0; ms < 4; ++ms) {
        int r = min(rbase + ms * 16 + l15, N_NODES - 1);
        const float* rp = h + (size_t)r * 64;
#pragma unroll
        for (int kt = 0; kt < 2; ++kt)
            afrag_g<false>(rp, kt * 32 + g16 * 8, HH[ms][kt], HL[ms][kt]);
    }

    // CSR gather: back rows = sum(src edges) + sum(sink edges * w) -> LDS
#pragma unroll 1
    for (int rr = 0; rr < 16; ++rr) {
        int r = rbase + wid * 16 + rr;
        float acc = 0.f;
        if (r < N_NODES) {
            int j0 = src_start[r], j1 = src_start[r + 1];
            for (int jb = j0; jb < j1; jb += 64) {
                int nj = min(64, j1 - jb);
                int mi = 0;
                if (lane < nj) mi = s_net[jb + lane];
                for (int t = 0; t < nj; ++t) {
                    int idx = __shfl(mi, t, 64);
                    acc += g[(size_t)idx * 64 + lane];
                }
            }
            j0 = node_start[r]; j1 = node_start[r + 1];
            for (int jb = j0; jb < j1; jb += 64) {
                int nj = min(64, j1 - jb);
                int mi = 0; float mw = 0.f;
                if (lane < nj) { mi = e2_net[jb + lane]; mw = e2_w[jb + lane]; }
                for (int t = 0; t < nj; ++t) {
                    int idx = __shfl(mi, t, 64);
                    float w = __shfl(mw, t, 64);
                    acc += g[(size_t)idx * 64 + lane] * w;
                }
            }
        }
        backT[wid * 16 + rr][lane] = acc;
    }
    __syncthreads();

    float bias = b[cs];
#pragma unroll
    for (int ms = 0; ms < 4; ++ms) {
        floatx4 acc = {0.f, 0.f, 0.f, 0.f};
#pragma unroll
        for (int kt = 0; kt < 2; ++kt) acc = mm3(HH[ms][kt], HL[ms][kt], WH[kt], WL[kt], acc);
#pragma unroll
        for (int kt = 0; kt < 2; ++kt) {
            bhalf8 ah, al;
            afrag_l(&backT[ms * 16 + l15][kt * 32 + g16 * 8], ah, al);
            acc = mm3(ah, al, WH[2 + kt], WL[2 + kt], acc);
        }
#pragma unroll
        for (int i = 0; i < 4; ++i) {
            int r = rbase + ms * 16 + g16 * 4 + i;
            if (r < N_NODES) h[(size_t)r * 64 + cs] = leaky(acc[i] + bias);
        }
    }
}

// ================= pooling: block-per-VN gather max =================
__global__ __launch_bounds__(256) void k_pool_gather(
    float* __restrict__ pooled, const float* __restrict__ h,
    const int* __restrict__ vn_start, const int* __restrict__ b_node)
{
    __shared__ float red[4][64];
    int lane = threadIdx.x & 63, wid = threadIdx.x >> 6;
    int v = blockIdx.x;
    int j0 = vn_start[v], j1 = vn_start[v + 1];
    float m = -__builtin_inff();
    for (int jb = j0 + wid * 64; jb < j1; jb += 256) {
        int nj = min(64, j1 - jb);
        int mi = 0;
        if (lane < nj) mi = b_node[jb + lane];
        for (int t = 0; t < nj; ++t) {
            int nd = __shfl(mi, t, 64);
            m = fmaxf(m, h[(size_t)nd * 64 + lane]);
        }
    }
    red[wid][lane] = m;
    __syncthreads();
    if (wid == 0) {
        m = fmaxf(fmaxf(red[0][lane], red[1][lane]), fmaxf(red[2][lane], red[3][lane]));
        pooled[(size_t)v * 64 + lane] = m;
    }
}

// ================= virtual-node MLP (tiny: 1000 rows) =================
__global__ __launch_bounds__(256) void k_vn_update(
    float* __restrict__ vn, const float* __restrict__ pooled,
    const float* __restrict__ W1, const float* __restrict__ b1,
    const float* __restrict__ W2, const float* __restrict__ b2)
{
    int wv = threadIdx.x >> 6, lane = threadIdx.x & 63;
    int v = blockIdx.x * 4 + wv;
    if (v >= NUM_VN) return;
    float p = pooled[(size_t)v * 64 + lane];
    float vv = vn[v * 64 + lane];
    float tmp = p + vv;
    float t1 = b1[lane];
#pragma unroll 16
    for (int k = 0; k < 64; ++k) t1 += __shfl(tmp, k, 64) * W1[k * 64 + lane];
    t1 = leaky(t1);
    float t2 = b2[lane];
#pragma unroll 16
    for (int k = 0; k < 64; ++k) t2 += __shfl(t1, k, 64) * W2[k * 64 + lane];
    vn[v * 64 + lane] = vv + t2;
}

// ========== fc_node head: 64 -> 256 (leaky) -> 4, abs ==========
__global__ __launch_bounds__(256) void k_fc_node_mfma(
    float* __restrict__ out, const float* __restrict__ h,
    const float* __restrict__ W1, const float* __restrict__ b1,
    const float* __restrict__ W2, const float* __restrict__ b2)
{
    __shared__ __align__(16) float t[64][260];
    int lane = threadIdx.x & 63, wid = threadIdx.x >> 6;
    int g16 = lane >> 4, l15 = lane & 15;
    int rbase = blockIdx.x * 64;

    bhalf8 W1H[4][2], W1L[4][2];
#pragma unroll
    for (int s = 0; s < 4; ++s)
#pragma unroll
        for (int kt = 0; kt < 2; ++kt)
            wfrag(W1, 256, 64, wid * 16 + s * 64 + l15, true, kt, g16, W1H[s][kt], W1L[s][kt]);

#pragma unroll
    for (int ms = 0; ms < 4; ++ms) {
        int r = min(rbase + ms * 16 + l15, N_NODES - 1);
        bhalf8 ah[2], al[2];
#pragma unroll
        for (int kt = 0; kt < 2; ++kt)
            afrag_g<false>(h + (size_t)r * 64, kt * 32 + g16 * 8, ah[kt], al[kt]);
#pragma unroll
        for (int s = 0; s < 4; ++s) {
            floatx4 acc = {0.f, 0.f, 0.f, 0.f};
#pragma unroll
            for (int kt = 0; kt < 2; ++kt) acc = mm3(ah[kt], al[kt], W1H[s][kt], W1L[s][kt], acc);
            int hc = wid * 16 + s * 64 + l15;
            float bb = b1[hc];
#pragma unroll
            for (int i = 0; i < 4; ++i)
                t[ms * 16 + g16 * 4 + i][hc] = leaky(acc[i] + bb);
        }
    }
    __syncthreads();

    bhalf8 W2H[8], W2L[8];
#pragma unroll
    for (int kt = 0; kt < 8; ++kt)
        wfrag(W2, 4, 256, l15, l15 < 4, kt, g16, W2H[kt], W2L[kt]);

    floatx4 acc = {0.f, 0.f, 0.f, 0.f};
#pragma unroll
    for (int kt = 0; kt < 8; ++kt) {
        bhalf8 ah, al;
        afrag_l(&t[wid * 16 + l15][kt * 32 + g16 * 8], ah, al);
        acc = mm3(ah, al, W2H[kt], W2L[kt], acc);
    }
    if (l15 < 4) {
        float bo = b2[l15];
#pragma unroll
        for (int i = 0; i < 4; ++i) {
            int r = rbase + wid * 16 + g16 * 4 + i;
            if (r < N_NODES) out[(size_t)r * 4 + l15] = fabsf(acc[i] + bo);
        }
    }
}

// ========== fc_net head: 64 -> 64 (leaky) -> 4, abs  (g stored pre-leaky) ==========
__global__ __launch_bounds__(256) void k_fc_net_mfma(
    float* __restrict__ out, const float* __restrict__ g,
    const float* __restrict__ W1, const float* __restrict__ b1,
    const float* __restrict__ W2, const float* __restrict__ b2)
{
    __shared__ __align__(16) float t[64][68];
    int lane = threadIdx.x & 63, wid = threadIdx.x >> 6;
    int g16 = lane >> 4, l15 = lane & 15;
    int rbase = blockIdx.x * 64;
    int cs = wid * 16 + l15;

    bhalf8 W1H[2], W1L[2];
#pragma unroll
    for (int kt = 0; kt < 2; ++kt) wfrag(W1, 64, 64, cs, true, kt, g16, W1H[kt], W1L[kt]);

#pragma unroll
    for (int ms = 0; ms < 4; ++ms) {
        int r = min(rbase + ms * 16 + l15, N_NETS - 1);
        floatx4 acc = {0.f, 0.f, 0.f, 0.f};
#pragma unroll
        for (int kt = 0; kt < 2; ++kt) {
            bhalf8 ah, al;
            afrag_g<true>(g + (size_t)r * 64, kt * 32 + g16 * 8, ah, al);
            acc = mm3(ah, al, W1H[kt], W1L[kt], acc);
        }
        float bb = b1[cs];
#pragma unroll
        for (int i = 0; i < 4; ++i)
            t[ms * 16 + g16 * 4 + i][cs] = leaky(acc[i] + bb);
    }
    __syncthreads();

    bhalf8 W2H[2], W2L[2];
#pragma unroll
    for (int kt = 0; kt < 2; ++kt)
        wfrag(W2, 4, 64, l15, l15 < 4, kt, g16, W2H[kt], W2L[kt]);

    floatx4 acc = {0.f, 0.f, 0.f, 0.f};
#pragma unroll
    for (int kt = 0; kt < 2; ++kt) {
        bhalf8 ah, al;
        afrag_l(&t[wid * 16 + l15][kt * 32 + g16 * 8], ah, al);
        acc = mm3(ah, al, W2H[kt], W2L[kt], acc);
    }
    if (l15 < 4) {
        float bo = b2[l15];
#pragma unroll
        for (int i = 0; i < 4; ++i) {
            int r = rbase + wid * 16 + g16 * 4 + i;
            if (r < N_NETS) out[(size_t)r * 4 + l15] = fabsf(acc[i] + bo);
        }
    }
}

extern "C" void kernel_launch(void* const* d_in, const int* in_sizes, int n_in,
                              void* d_out, int out_size, void* d_ws, size_t ws_size,
                              hipStream_t stream)
{
    const float* node_features = (const float*)d_in[0];
    const float* net_features  = (const float*)d_in[1];
    const int*   src_nodes     = (const int*)d_in[2];
    const int*   sink_nodes    = (const int*)d_in[3];
    const int*   sink_nets     = (const int*)d_in[4];
    const float* edge_weight   = (const float*)d_in[5];
    const int*   batch         = (const int*)d_in[6];
    const float* ne_W1 = (const float*)d_in[7];
    const float* ne_b1 = (const float*)d_in[8];
    const float* ne_W2 = (const float*)d_in[9];
    const float* ne_b2 = (const float*)d_in[10];
    const float* te_W1 = (const float*)d_in[11];
    const float* te_b1 = (const float*)d_in[12];
    const float* te_W2 = (const float*)d_in[13];
    const float* te_b2 = (const float*)d_in[14];
    const float* vn_emb = (const float*)d_in[15];
    const float* conv_Wnet  = (const float*)d_in[16];
    const float* conv_bnet  = (const float*)d_in[17];
    const float* conv_Wnode = (const float*)d_in[18];
    const float* conv_bnode = (const float*)d_in[19];
    const float* vn_W1 = (const float*)d_in[20];
    const float* vn_b1 = (const float*)d_in[21];
    const float* vn_W2 = (const float*)d_in[22];
    const float* vn_b2 = (const float*)d_in[23];
    const float* fc1n_W = (const float*)d_in[24];
    const float* fc1n_b = (const float*)d_in[25];
    const float* fc2n_W = (const float*)d_in[26];
    const float* fc2n_b = (const float*)d_in[27];
    const float* fc1e_W = (const float*)d_in[28];
    const float* fc1e_b = (const float*)d_in[29];
    const float* fc2e_W = (const float*)d_in[30];
    const float* fc2e_b = (const float*)d_in[31];

    float* out_node = (float*)d_out;
    float* out_net  = out_node + (size_t)N_NODES * 4;

    // ---------- workspace layout ----------
    float* h      = (float*)d_ws;                        // N_NODES*64
    float* g      = h + (size_t)N_NODES * EMB;           // N_NETS*64
    float* vn     = g + (size_t)N_NETS * EMB;            // NUM_VN*64
    float* pooled = vn + (size_t)NUM_VN * EMB;           // NUM_VN*64
    int* net_start  = (int*)(pooled + (size_t)NUM_VN * EMB);  // N_NETS+1
    int* node_start = net_start + (N_NETS + 1);               // N_NODES+1
    int* src_start  = node_start + (N_NODES + 1);             // N_NODES+1
    int* vn_start   = src_start + (N_NODES + 1);              // NUM_VN+1
    int*   e_node = vn_start + (NUM_VN + 1);                  // E
    float* e_w    = (float*)(e_node + E_SINK);                // E
    int*   e2_net = (int*)(e_w + E_SINK);                     // E
    float* e2_w   = (float*)(e2_net + E_SINK);                // E
    int*   s_net  = (int*)(e2_w + E_SINK);                    // N_NETS
    int*   b_node = s_net + N_NETS;                           // N_NODES
    int*   cnt    = b_node + N_NODES;   // N_NETS + N_NODES + N_NODES + NUM_VN
    int*   cnt_net  = cnt;
    int*   cnt_node = cnt + N_NETS;
    int*   cnt_src  = cnt_node + N_NODES;
    int*   cnt_vn   = cnt_src + N_NODES;
    const int CNT_TOTAL = N_NETS + N_NODES + N_NODES + NUM_VN;
    int*   bsum   = cnt + CNT_TOTAL;                          // 2048

    const int nodeTiles = (N_NODES + 63) / 64;
    const int netTiles  = (N_NETS + 63) / 64;
    const int vnBlocks  = (NUM_VN + 3) / 4;
    const int vnElemBlocks   = (NUM_VN * EMB + 255) / 256;
    const int nodeVec4Blocks = (N_NODES * 16 + 255) / 256;
    const int edgeThreadBlocks = (E_SINK + 255) / 256;
    const int miscThreadBlocks = (N_NODES + 255) / 256;

    // ---------- CSR build ----------
    hipMemsetAsync(cnt, 0, (size_t)CNT_TOTAL * sizeof(int), stream);
    k_hist_edges<<<edgeThreadBlocks, 256, 0, stream>>>(sink_nets, sink_nodes, cnt_net, cnt_node);
    k_hist_misc<<<miscThreadBlocks, 256, 0, stream>>>(src_nodes, batch, cnt_src, cnt_vn);

    auto scan = [&](int* cnt_arr, int n, int* start_arr) {
        int nb = (n + 255) / 256;
        k_scan1<<<nb, 256, 0, stream>>>(cnt_arr, n, bsum);
        k_scan2<<<1, 256, 0, stream>>>(bsum, nb);
        k_scan3<<<nb, 256, 0, stream>>>(cnt_arr, n, bsum, start_arr);
    };
    scan(cnt_net, N_NETS, net_start);
    scan(cnt_node, N_NODES, node_start);
    scan(cnt_src, N_NODES, src_start);
    scan(cnt_vn, NUM_VN, vn_start);

    hipMemsetAsync(cnt, 0, (size_t)CNT_TOTAL * sizeof(int), stream);
    k_fill_edges<<<edgeThreadBlocks, 256, 0, stream>>>(sink_nets, sink_nodes, edge_weight,
        net_start, node_start, cnt_net, cnt_node, e_node, e_w, e2_net, e2_w);
    k_fill_misc<<<miscThreadBlocks, 256, 0, stream>>>(src_nodes, batch, src_start, vn_start,
        cnt_src, cnt_vn, s_net, b_node);

    // ---------- encoders ----------
    k_node_enc_mfma<<<nodeTiles, 256, 0, stream>>>(node_features, ne_W1, ne_b1, ne_W2, ne_b2, h);
    k_net_enc_mfma<<<netTiles, 256, 0, stream>>>(net_features, te_W1, te_b1, te_W2, te_b2, g);
    k_vn_init<<<vnElemBlocks, 256, 0, stream>>>(vn, vn_emb);

    // ---------- layers ----------
    for (int l = 0; l < 3; ++l) {
        k_add_vn<<<nodeVec4Blocks, 256, 0, stream>>>((float4*)h, vn, batch);

        k_conv_net_fused<<<netTiles, 256, 0, stream>>>(g, h, src_nodes,
            net_start, e_node, e_w,
            conv_Wnet + (size_t)l * 192 * 64, conv_bnet + (size_t)l * 64, l > 0 ? 1 : 0);

        k_conv_node_fused<<<nodeTiles, 256, 0, stream>>>(h, g,
            src_start, s_net, node_start, e2_net, e2_w,
            conv_Wnode + (size_t)l * 128 * 64, conv_bnode + (size_t)l * 64);

        if (l < 2) {
            k_pool_gather<<<NUM_VN, 256, 0, stream>>>(pooled, h, vn_start, b_node);
            k_vn_update<<<vnBlocks, 256, 0, stream>>>(vn, pooled,
                vn_W1 + (size_t)l * 64 * 64, vn_b1 + (size_t)l * 64,
                vn_W2 + (size_t)l * 64 * 64, vn_b2 + (size_t)l * 64);
        }
    }

    // ---------- heads ----------
    k_fc_node_mfma<<<nodeTiles, 256, 0, stream>>>(out_node, h, fc1n_W, fc1n_b, fc2n_W, fc2n_b);
    k_fc_net_mfma<<<netTiles, 256, 0, stream>>>(out_net, g, fc1e_W, fc1e_b, fc2e_W, fc2e_b);
}

// Round 6
// 1882.286 us; speedup vs baseline: 1.5180x; 1.5180x over previous
//
#include <hip/hip_runtime.h>
#include <cstdint>

static constexpr int N_NODES = 300000;
static constexpr int N_NETS  = 200000;
static constexpr int E_SINK  = 1000000;
static constexpr int NODE_DIM = 32;
static constexpr int NET_DIM  = 16;
static constexpr int EMB = 64;
static constexpr int NUM_VN = 1000;
#define SLOPE 0.01f

typedef __attribute__((ext_vector_type(8))) short bhalf8;
typedef __attribute__((ext_vector_type(4))) float floatx4;

__device__ __forceinline__ float leaky(float x) { return x >= 0.f ? x : SLOPE * x; }

// ---------- bf16 split helpers ----------
__device__ __forceinline__ unsigned bf16_rne(float x) {
    unsigned u = __float_as_uint(x);
    return (u + 0x7FFFu + ((u >> 16) & 1u)) >> 16;
}
__device__ __forceinline__ void split8(const float* x, bhalf8& ah, bhalf8& al) {
#pragma unroll
    for (int e = 0; e < 8; ++e) {
        unsigned h = bf16_rne(x[e]);
        float fh = __uint_as_float(h << 16);
        unsigned l = bf16_rne(x[e] - fh);
        ah[e] = (short)h; al[e] = (short)l;
    }
}

template<bool LK>
__device__ __forceinline__ void afrag_g(const float* rowp, int kbase, bhalf8& ah, bhalf8& al) {
    float4 v0 = *(const float4*)(rowp + kbase);
    float4 v1 = *(const float4*)(rowp + kbase + 4);
    float x[8] = {v0.x, v0.y, v0.z, v0.w, v1.x, v1.y, v1.z, v1.w};
    if (LK) {
#pragma unroll
        for (int e = 0; e < 8; ++e) x[e] = leaky(x[e]);
    }
    split8(x, ah, al);
}

__device__ __forceinline__ void afrag_l(const float* tp, bhalf8& ah, bhalf8& al) {
    float4 v0 = *(const float4*)tp;
    float4 v1 = *(const float4*)(tp + 4);
    float x[8] = {v0.x, v0.y, v0.z, v0.w, v1.x, v1.y, v1.z, v1.w};
    split8(x, ah, al);
}

__device__ __forceinline__ void wfrag(const float* W, int cols, int K, int col, bool colok,
                                      int kt, int g, bhalf8& wh, bhalf8& wl) {
    float x[8];
#pragma unroll
    for (int e = 0; e < 8; ++e) {
        int k = kt * 32 + g * 8 + e;
        x[e] = (k < K && colok) ? W[(size_t)k * cols + col] : 0.f;
    }
    split8(x, wh, wl);
}

__device__ __forceinline__ floatx4 mm3(bhalf8 ah, bhalf8 al, bhalf8 wh, bhalf8 wl, floatx4 c) {
    c = __builtin_amdgcn_mfma_f32_16x16x32_bf16(ah, wh, c, 0, 0, 0);
    c = __builtin_amdgcn_mfma_f32_16x16x32_bf16(ah, wl, c, 0, 0, 0);
    c = __builtin_amdgcn_mfma_f32_16x16x32_bf16(al, wh, c, 0, 0, 0);
    return c;
}

// ===================== CSR build =====================
__global__ void k_hist_edges(const int* __restrict__ sink_nets, const int* __restrict__ sink_nodes,
                             int* __restrict__ cnt_net, int* __restrict__ cnt_node)
{
    int e = blockIdx.x * 256 + threadIdx.x;
    if (e >= E_SINK) return;
    atomicAdd(&cnt_net[sink_nets[e]], 1);
    atomicAdd(&cnt_node[sink_nodes[e]], 1);
}

__global__ void k_hist_misc(const int* __restrict__ src_nodes, const int* __restrict__ batch,
                            int* __restrict__ cnt_src, int* __restrict__ cnt_vn)
{
    int i = blockIdx.x * 256 + threadIdx.x;
    if (i < N_NETS) atomicAdd(&cnt_src[src_nodes[i]], 1);
    if (i < N_NODES) atomicAdd(&cnt_vn[batch[i]], 1);
}

__global__ void k_scan1(const int* __restrict__ cnt, int n, int* __restrict__ bsum) {
    __shared__ int s[256];
    int i = blockIdx.x * 256 + threadIdx.x;
    s[threadIdx.x] = (i < n) ? cnt[i] : 0;
    __syncthreads();
    for (int off = 128; off; off >>= 1) {
        if (threadIdx.x < off) s[threadIdx.x] += s[threadIdx.x + off];
        __syncthreads();
    }
    if (threadIdx.x == 0) bsum[blockIdx.x] = s[0];
}

__global__ void k_scan2(int* __restrict__ data, int n) {
    __shared__ int s[256];
    __shared__ int carry_s;
    int tid = threadIdx.x;
    if (tid == 0) carry_s = 0;
    __syncthreads();
    for (int base = 0; base < n; base += 256) {
        int i = base + tid;
        int v = (i < n) ? data[i] : 0;
        s[tid] = v;
        __syncthreads();
        for (int off = 1; off < 256; off <<= 1) {
            int t = (tid >= off) ? s[tid - off] : 0;
            __syncthreads();
            s[tid] += t;
            __syncthreads();
        }
        int excl = s[tid] - v + carry_s;
        if (i < n) data[i] = excl;
        __syncthreads();
        if (tid == 255) carry_s = excl + v;
        __syncthreads();
    }
}

__global__ void k_scan3(const int* __restrict__ cnt, int n, const int* __restrict__ bsum,
                        int* __restrict__ start) {
    __shared__ int s[256];
    int i = blockIdx.x * 256 + threadIdx.x;
    int v = (i < n) ? cnt[i] : 0;
    s[threadIdx.x] = v;
    __syncthreads();
    for (int off = 1; off < 256; off <<= 1) {
        int t = (threadIdx.x >= off) ? s[threadIdx.x - off] : 0;
        __syncthreads();
        s[threadIdx.x] += t;
        __syncthreads();
    }
    int excl = s[threadIdx.x] - v + bsum[blockIdx.x];
    if (i < n) start[i] = excl;
    if (i == n - 1) start[n] = excl + v;
}

__global__ void k_fill_edges(const int* __restrict__ sink_nets, const int* __restrict__ sink_nodes,
                             const float* __restrict__ ew,
                             const int* __restrict__ net_start, const int* __restrict__ node_start,
                             int* __restrict__ cur_net, int* __restrict__ cur_node,
                             int* __restrict__ e_node, float* __restrict__ e_w,
                             int* __restrict__ e2_net, float* __restrict__ e2_w)
{
    int e = blockIdx.x * 256 + threadIdx.x;
    if (e >= E_SINK) return;
    int tn = sink_nets[e], dn = sink_nodes[e];
    float w = ew[e];
    int p = net_start[tn] + atomicAdd(&cur_net[tn], 1);
    e_node[p] = dn; e_w[p] = w;
    int q = node_start[dn] + atomicAdd(&cur_node[dn], 1);
    e2_net[q] = tn; e2_w[q] = w;
}

__global__ void k_fill_misc(const int* __restrict__ src_nodes, const int* __restrict__ batch,
                            const int* __restrict__ src_start, const int* __restrict__ vn_start,
                            int* __restrict__ cur_src, int* __restrict__ cur_vn,
                            int* __restrict__ s_net, int* __restrict__ b_node)
{
    int i = blockIdx.x * 256 + threadIdx.x;
    if (i < N_NETS) {
        int d = src_nodes[i];
        int p = src_start[d] + atomicAdd(&cur_src[d], 1);
        s_net[p] = i;
    }
    if (i < N_NODES) {
        int v = batch[i];
        int p = vn_start[v] + atomicAdd(&cur_vn[v], 1);
        b_node[p] = i;
    }
}

// ===================== gathers (wave per row, 4-edge groups) =====================
__global__ __launch_bounds__(256) void k_gather_agg(
    float* __restrict__ agg, const float* __restrict__ h,
    const int* __restrict__ net_start, const int* __restrict__ e_node, const float* __restrict__ e_w)
{
    int w = (blockIdx.x * 256 + threadIdx.x) >> 6;
    if (w >= N_NETS) return;
    int lane = threadIdx.x & 63;
    int grp = lane >> 4, l15 = lane & 15;
    int j0 = net_start[w], j1 = net_start[w + 1];
    float ax = 0.f, ay = 0.f, az = 0.f, aw = 0.f;
    for (int j = j0 + grp; j < j1; j += 4) {
        int idx = e_node[j];
        float wt = e_w[j];
        float4 v = ((const float4*)(h + (size_t)idx * 64))[l15];
        ax += wt * v.x; ay += wt * v.y; az += wt * v.z; aw += wt * v.w;
    }
    ax += __shfl_xor(ax, 16, 64); ay += __shfl_xor(ay, 16, 64);
    az += __shfl_xor(az, 16, 64); aw += __shfl_xor(aw, 16, 64);
    ax += __shfl_xor(ax, 32, 64); ay += __shfl_xor(ay, 32, 64);
    az += __shfl_xor(az, 32, 64); aw += __shfl_xor(aw, 32, 64);
    if (grp == 0)
        ((float4*)(agg + (size_t)w * 64))[l15] = make_float4(ax, ay, az, aw);
}

__global__ __launch_bounds__(256) void k_gather_back(
    float* __restrict__ back, const float* __restrict__ g,
    const int* __restrict__ src_start, const int* __restrict__ s_net,
    const int* __restrict__ node_start, const int* __restrict__ e2_net, const float* __restrict__ e2_w)
{
    int w = (blockIdx.x * 256 + threadIdx.x) >> 6;
    if (w >= N_NODES) return;
    int lane = threadIdx.x & 63;
    int grp = lane >> 4, l15 = lane & 15;
    float ax = 0.f, ay = 0.f, az = 0.f, aw = 0.f;
    int j0 = src_start[w], j1 = src_start[w + 1];
    for (int j = j0 + grp; j < j1; j += 4) {
        int idx = s_net[j];
        float4 v = ((const float4*)(g + (size_t)idx * 64))[l15];
        ax += v.x; ay += v.y; az += v.z; aw += v.w;
    }
    j0 = node_start[w]; j1 = node_start[w + 1];
    for (int j = j0 + grp; j < j1; j += 4) {
        int idx = e2_net[j];
        float wt = e2_w[j];
        float4 v = ((const float4*)(g + (size_t)idx * 64))[l15];
        ax += wt * v.x; ay += wt * v.y; az += wt * v.z; aw += wt * v.w;
    }
    ax += __shfl_xor(ax, 16, 64); ay += __shfl_xor(ay, 16, 64);
    az += __shfl_xor(az, 16, 64); aw += __shfl_xor(aw, 16, 64);
    ax += __shfl_xor(ax, 32, 64); ay += __shfl_xor(ay, 32, 64);
    az += __shfl_xor(az, 32, 64); aw += __shfl_xor(aw, 32, 64);
    if (grp == 0)
        ((float4*)(back + (size_t)w * 64))[l15] = make_float4(ax, ay, az, aw);
}

// ================= pooling: block-per-VN gather max (16 edge groups) =================
__global__ __launch_bounds__(256) void k_pool_gather(
    float* __restrict__ pooled, const float* __restrict__ h,
    const int* __restrict__ vn_start, const int* __restrict__ b_node)
{
    __shared__ float4 red[16][16];
    int tid = threadIdx.x;
    int grp = tid >> 4, l15 = tid & 15;
    int v = blockIdx.x;
    int j0 = vn_start[v], j1 = vn_start[v + 1];
    const float NEG = -__builtin_inff();
    float mx = NEG, my = NEG, mz = NEG, mw = NEG;
    for (int j = j0 + grp; j < j1; j += 16) {
        int nd = b_node[j];
        float4 val = ((const float4*)(h + (size_t)nd * 64))[l15];
        mx = fmaxf(mx, val.x); my = fmaxf(my, val.y);
        mz = fmaxf(mz, val.z); mw = fmaxf(mw, val.w);
    }
    red[grp][l15] = make_float4(mx, my, mz, mw);
    __syncthreads();
    if (tid < 16) {
        float4 m = red[0][tid];
#pragma unroll
        for (int q = 1; q < 16; ++q) {
            float4 r = red[q][tid];
            m.x = fmaxf(m.x, r.x); m.y = fmaxf(m.y, r.y);
            m.z = fmaxf(m.z, r.z); m.w = fmaxf(m.w, r.w);
        }
        ((float4*)(pooled + (size_t)v * 64))[tid] = m;
    }
}

// ================= fused node encoder: 32 -> 128 (leaky) -> 64 =================
__global__ __launch_bounds__(256) void k_node_enc_mfma(
    const float* __restrict__ x, const float* __restrict__ W1, const float* __restrict__ b1,
    const float* __restrict__ W2, const float* __restrict__ b2, float* __restrict__ h)
{
    __shared__ __align__(16) float t[64][132];
    int lane = threadIdx.x & 63, wid = threadIdx.x >> 6;
    int g16 = lane >> 4, l15 = lane & 15;
    int rbase = blockIdx.x * 64;

    bhalf8 W1H[2], W1L[2];
#pragma unroll
    for (int s = 0; s < 2; ++s)
        wfrag(W1, 128, 32, wid * 16 + s * 64 + l15, true, 0, g16, W1H[s], W1L[s]);
    bhalf8 W2H[4], W2L[4];
#pragma unroll
    for (int kt = 0; kt < 4; ++kt)
        wfrag(W2, 64, 128, wid * 16 + l15, true, kt, g16, W2H[kt], W2L[kt]);

#pragma unroll
    for (int ms = 0; ms < 4; ++ms) {
        int r = min(rbase + ms * 16 + l15, N_NODES - 1);
        bhalf8 ah, al;
        afrag_g<false>(x + (size_t)r * NODE_DIM, g16 * 8, ah, al);
#pragma unroll
        for (int s = 0; s < 2; ++s) {
            floatx4 acc = {0.f, 0.f, 0.f, 0.f};
            acc = mm3(ah, al, W1H[s], W1L[s], acc);
            int hc = wid * 16 + s * 64 + l15;
            float bb = b1[hc];
#pragma unroll
            for (int i = 0; i < 4; ++i)
                t[ms * 16 + g16 * 4 + i][hc] = leaky(acc[i] + bb);
        }
    }
    __syncthreads();

    int cs = wid * 16 + l15;
    float bias = b2[cs];
#pragma unroll
    for (int ms = 0; ms < 4; ++ms) {
        floatx4 acc = {0.f, 0.f, 0.f, 0.f};
#pragma unroll
        for (int kt = 0; kt < 4; ++kt) {
            bhalf8 ah, al;
            afrag_l(&t[ms * 16 + l15][kt * 32 + g16 * 8], ah, al);
            acc = mm3(ah, al, W2H[kt], W2L[kt], acc);
        }
#pragma unroll
        for (int i = 0; i < 4; ++i) {
            int r = rbase + ms * 16 + g16 * 4 + i;
            if (r < N_NODES) h[(size_t)r * 64 + cs] = acc[i] + bias;
        }
    }
}

// ================= fused net encoder: 16 -> 64 (leaky) -> 64 =================
__global__ __launch_bounds__(256) void k_net_enc_mfma(
    const float* __restrict__ x, const float* __restrict__ W1, const float* __restrict__ b1,
    const float* __restrict__ W2, const float* __restrict__ b2, float* __restrict__ g)
{
    __shared__ __align__(16) float t[64][68];
    int lane = threadIdx.x & 63, wid = threadIdx.x >> 6;
    int g16 = lane >> 4, l15 = lane & 15;
    int rbase = blockIdx.x * 64;
    int cs = wid * 16 + l15;

    bhalf8 W1H, W1L;
    wfrag(W1, 64, 16, cs, true, 0, g16, W1H, W1L);
    bhalf8 W2H[2], W2L[2];
#pragma unroll
    for (int kt = 0; kt < 2; ++kt)
        wfrag(W2, 64, 64, cs, true, kt, g16, W2H[kt], W2L[kt]);

#pragma unroll
    for (int ms = 0; ms < 4; ++ms) {
        int r = min(rbase + ms * 16 + l15, N_NETS - 1);
        bhalf8 ah = {0,0,0,0,0,0,0,0}, al = {0,0,0,0,0,0,0,0};
        if (g16 < 2) afrag_g<false>(x + (size_t)r * NET_DIM, g16 * 8, ah, al);
        floatx4 acc = {0.f, 0.f, 0.f, 0.f};
        acc = mm3(ah, al, W1H, W1L, acc);
        float bb = b1[cs];
#pragma unroll
        for (int i = 0; i < 4; ++i)
            t[ms * 16 + g16 * 4 + i][cs] = leaky(acc[i] + bb);
    }
    __syncthreads();

    float bias = b2[cs];
#pragma unroll
    for (int ms = 0; ms < 4; ++ms) {
        floatx4 acc = {0.f, 0.f, 0.f, 0.f};
#pragma unroll
        for (int kt = 0; kt < 2; ++kt) {
            bhalf8 ah, al;
            afrag_l(&t[ms * 16 + l15][kt * 32 + g16 * 8], ah, al);
            acc = mm3(ah, al, W2H[kt], W2L[kt], acc);
        }
#pragma unroll
        for (int i = 0; i < 4; ++i) {
            int r = rbase + ms * 16 + g16 * 4 + i;
            if (r < N_NETS) g[(size_t)r * 64 + cs] = acc[i] + bias;
        }
    }
}

// ================= misc elementwise =================
__global__ void k_vn_init(float* __restrict__ vn, const float* __restrict__ vn_emb) {
    int idx = blockIdx.x * blockDim.x + threadIdx.x;
    if (idx < NUM_VN * EMB) vn[idx] = vn_emb[idx & 63];
}

__global__ void k_add_vn(float4* __restrict__ h4, const float* __restrict__ vn,
                         const int* __restrict__ batch) {
    int idx = blockIdx.x * blockDim.x + threadIdx.x;
    if (idx >= N_NODES * 16) return;
    int n = idx >> 4, c4 = idx & 15;
    const float4* vr = (const float4*)(vn + (size_t)batch[n] * 64);
    float4 hv = h4[idx], vv = vr[c4];
    h4[idx] = make_float4(hv.x + vv.x, hv.y + vv.y, hv.z + vv.z, hv.w + vv.w);
}

// ========== conv_net: g_new = cat(g|leaky, h[src], aggsink) @ W(192x64) + b ==========
__global__ __launch_bounds__(256) void k_conv_net_mfma(
    float* __restrict__ g, const float* __restrict__ h, const float* __restrict__ agg,
    const int* __restrict__ src, const float* __restrict__ W, const float* __restrict__ b, int lk0)
{
    int lane = threadIdx.x & 63, wid = threadIdx.x >> 6;
    int g16 = lane >> 4, l15 = lane & 15;
    int rbase = blockIdx.x * 64;
    int cs = wid * 16 + l15;

    bhalf8 WH[6], WL[6];
#pragma unroll
    for (int kt = 0; kt < 6; ++kt) wfrag(W, 64, 192, cs, true, kt, g16, WH[kt], WL[kt]);

    bhalf8 GH[4][2], GL[4][2];
#pragma unroll
    for (int ms = 0; ms < 4; ++ms) {
        int r = min(rbase + ms * 16 + l15, N_NETS - 1);
        const float* rp = g + (size_t)r * 64;
#pragma unroll
        for (int kt = 0; kt < 2; ++kt) {
            if (lk0) afrag_g<true>(rp, kt * 32 + g16 * 8, GH[ms][kt], GL[ms][kt]);
            else     afrag_g<false>(rp, kt * 32 + g16 * 8, GH[ms][kt], GL[ms][kt]);
        }
    }
    __syncthreads();

    float bias = b[cs];
#pragma unroll
    for (int ms = 0; ms < 4; ++ms) {
        floatx4 acc = {0.f, 0.f, 0.f, 0.f};
#pragma unroll
        for (int kt = 0; kt < 2; ++kt) acc = mm3(GH[ms][kt], GL[ms][kt], WH[kt], WL[kt], acc);
        int ar = min(rbase + ms * 16 + l15, N_NETS - 1);
        const float* hp = h + (size_t)src[ar] * 64;
#pragma unroll
        for (int kt = 0; kt < 2; ++kt) {
            bhalf8 ah, al;
            afrag_g<false>(hp, kt * 32 + g16 * 8, ah, al);
            acc = mm3(ah, al, WH[2 + kt], WL[2 + kt], acc);
        }
        const float* ap = agg + (size_t)ar * 64;
#pragma unroll
        for (int kt = 0; kt < 2; ++kt) {
            bhalf8 ah, al;
            afrag_g<false>(ap, kt * 32 + g16 * 8, ah, al);
            acc = mm3(ah, al, WH[4 + kt], WL[4 + kt], acc);
        }
#pragma unroll
        for (int i = 0; i < 4; ++i) {
            int r = rbase + ms * 16 + g16 * 4 + i;
            if (r < N_NETS) g[(size_t)r * 64 + cs] = acc[i] + bias;
        }
    }
}

// ========== conv_node: h_new = leaky( cat(h, back) @ W(128x64) + b ) ==========
__global__ __launch_bounds__(256) void k_conv_node_mfma(
    float* __restrict__ h, const float* __restrict__ back,
    const float* __restrict__ W, const float* __restrict__ b)
{
    int lane = threadIdx.x & 63, wid = threadIdx.x >> 6;
    int g16 = lane >> 4, l15 = lane & 15;
    int rbase = blockIdx.x * 64;
    int cs = wid * 16 + l15;

    bhalf8 WH[4], WL[4];
#pragma unroll
    for (int kt = 0; kt < 4; ++kt) wfrag(W, 64, 128, cs, true, kt, g16, WH[kt], WL[kt]);

    bhalf8 HH[4][2], HL[4][2];
#pragma unroll
    for (int ms = 0; ms < 4; ++ms) {
        int r = min(rbase + ms * 16 + l15, N_NODES - 1);
        const float* rp = h + (size_t)r * 64;
#pragma unroll
        for (int kt = 0; kt < 2; ++kt)
            afrag_g<false>(rp, kt * 32 + g16 * 8, HH[ms][kt], HL[ms][kt]);
    }
    __syncthreads();

    float bias = b[cs];
#pragma unroll
    for (int ms = 0; ms < 4; ++ms) {
        floatx4 acc = {0.f, 0.f, 0.f, 0.f};
#pragma unroll
        for (int kt = 0; kt < 2; ++kt) acc = mm3(HH[ms][kt], HL[ms][kt], WH[kt], WL[kt], acc);
        int ar = min(rbase + ms * 16 + l15, N_NODES - 1);
        const float* bp = back + (size_t)ar * 64;
#pragma unroll
        for (int kt = 0; kt < 2; ++kt) {
            bhalf8 ah, al;
            afrag_g<false>(bp, kt * 32 + g16 * 8, ah, al);
            acc = mm3(ah, al, WH[2 + kt], WL[2 + kt], acc);
        }
#pragma unroll
        for (int i = 0; i < 4; ++i) {
            int r = rbase + ms * 16 + g16 * 4 + i;
            if (r < N_NODES) h[(size_t)r * 64 + cs] = leaky(acc[i] + bias);
        }
    }
}

// ================= virtual-node MLP (tiny: 1000 rows) =================
__global__ __launch_bounds__(256) void k_vn_update(
    float* __restrict__ vn, const float* __restrict__ pooled,
    const float* __restrict__ W1, const float* __restrict__ b1,
    const float* __restrict__ W2, const float* __restrict__ b2)
{
    int wv = threadIdx.x >> 6, lane = threadIdx.x & 63;
    int v = blockIdx.x * 4 + wv;
    if (v >= NUM_VN) return;
    float p = pooled[(size_t)v * 64 + lane];
    float vv = vn[v * 64 + lane];
    float tmp = p + vv;
    float t1 = b1[lane];
#pragma unroll 16
    for (int k = 0; k < 64; ++k) t1 += __shfl(tmp, k, 64) * W1[k * 64 + lane];
    t1 = leaky(t1);
    float t2 = b2[lane];
#pragma unroll 16
    for (int k = 0; k < 64; ++k) t2 += __shfl(t1, k, 64) * W2[k * 64 + lane];
    vn[v * 64 + lane] = vv + t2;
}

// ========== fc_node head: 64 -> 256 (leaky) -> 4, abs ==========
__global__ __launch_bounds__(256) void k_fc_node_mfma(
    float* __restrict__ out, const float* __restrict__ h,
    const float* __restrict__ W1, const float* __restrict__ b1,
    const float* __restrict__ W2, const float* __restrict__ b2)
{
    __shared__ __align__(16) float t[64][260];
    int lane = threadIdx.x & 63, wid = threadIdx.x >> 6;
    int g16 = lane >> 4, l15 = lane & 15;
    int rbase = blockIdx.x * 64;

    bhalf8 W1H[4][2], W1L[4][2];
#pragma unroll
    for (int s = 0; s < 4; ++s)
#pragma unroll
        for (int kt = 0; kt < 2; ++kt)
            wfrag(W1, 256, 64, wid * 16 + s * 64 + l15, true, kt, g16, W1H[s][kt], W1L[s][kt]);

#pragma unroll
    for (int ms = 0; ms < 4; ++ms) {
        int r = min(rbase + ms * 16 + l15, N_NODES - 1);
        bhalf8 ah[2], al[2];
#pragma unroll
        for (int kt = 0; kt < 2; ++kt)
            afrag_g<false>(h + (size_t)r * 64, kt * 32 + g16 * 8, ah[kt], al[kt]);
#pragma unroll
        for (int s = 0; s < 4; ++s) {
            floatx4 acc = {0.f, 0.f, 0.f, 0.f};
#pragma unroll
            for (int kt = 0; kt < 2; ++kt) acc = mm3(ah[kt], al[kt], W1H[s][kt], W1L[s][kt], acc);
            int hc = wid * 16 + s * 64 + l15;
            float bb = b1[hc];
#pragma unroll
            for (int i = 0; i < 4; ++i)
                t[ms * 16 + g16 * 4 + i][hc] = leaky(acc[i] + bb);
        }
    }
    __syncthreads();

    bhalf8 W2H[8], W2L[8];
#pragma unroll
    for (int kt = 0; kt < 8; ++kt)
        wfrag(W2, 4, 256, l15, l15 < 4, kt, g16, W2H[kt], W2L[kt]);

    floatx4 acc = {0.f, 0.f, 0.f, 0.f};
#pragma unroll
    for (int kt = 0; kt < 8; ++kt) {
        bhalf8 ah, al;
        afrag_l(&t[wid * 16 + l15][kt * 32 + g16 * 8], ah, al);
        acc = mm3(ah, al, W2H[kt], W2L[kt], acc);
    }
    if (l15 < 4) {
        float bo = b2[l15];
#pragma unroll
        for (int i = 0; i < 4; ++i) {
            int r = rbase + wid * 16 + g16 * 4 + i;
            if (r < N_NODES) out[(size_t)r * 4 + l15] = fabsf(acc[i] + bo);
        }
    }
}

// ========== fc_net head: 64 -> 64 (leaky) -> 4, abs  (g stored pre-leaky) ==========
__global__ __launch_bounds__(256) void k_fc_net_mfma(
    float* __restrict__ out, const float* __restrict__ g,
    const float* __restrict__ W1, const float* __restrict__ b1,
    const float* __restrict__ W2, const float* __restrict__ b2)
{
    __shared__ __align__(16) float t[64][68];
    int lane = threadIdx.x & 63, wid = threadIdx.x >> 6;
    int g16 = lane >> 4, l15 = lane & 15;
    int rbase = blockIdx.x * 64;
    int cs = wid * 16 + l15;

    bhalf8 W1H[2], W1L[2];
#pragma unroll
    for (int kt = 0; kt < 2; ++kt) wfrag(W1, 64, 64, cs, true, kt, g16, W1H[kt], W1L[kt]);

#pragma unroll
    for (int ms = 0; ms < 4; ++ms) {
        int r = min(rbase + ms * 16 + l15, N_NETS - 1);
        floatx4 acc = {0.f, 0.f, 0.f, 0.f};
#pragma unroll
        for (int kt = 0; kt < 2; ++kt) {
            bhalf8 ah, al;
            afrag_g<true>(g + (size_t)r * 64, kt * 32 + g16 * 8, ah, al);
            acc = mm3(ah, al, W1H[kt], W1L[kt], acc);
        }
        float bb = b1[cs];
#pragma unroll
        for (int i = 0; i < 4; ++i)
            t[ms * 16 + g16 * 4 + i][cs] = leaky(acc[i] + bb);
    }
    __syncthreads();

    bhalf8 W2H[2], W2L[2];
#pragma unroll
    for (int kt = 0; kt < 2; ++kt)
        wfrag(W2, 4, 64, l15, l15 < 4, kt, g16, W2H[kt], W2L[kt]);

    floatx4 acc = {0.f, 0.f, 0.f, 0.f};
#pragma unroll
    for (int kt = 0; kt < 2; ++kt) {
        bhalf8 ah, al;
        afrag_l(&t[wid * 16 + l15][kt * 32 + g16 * 8], ah, al);
        acc = mm3(ah, al, W2H[kt], W2L[kt], acc);
    }
    if (l15 < 4) {
        float bo = b2[l15];
#pragma unroll
        for (int i = 0; i < 4; ++i) {
            int r = rbase + wid * 16 + g16 * 4 + i;
            if (r < N_NETS) out[(size_t)r * 4 + l15] = fabsf(acc[i] + bo);
        }
    }
}

extern "C" void kernel_launch(void* const* d_in, const int* in_sizes, int n_in,
                              void* d_out, int out_size, void* d_ws, size_t ws_size,
                              hipStream_t stream)
{
    const float* node_features = (const float*)d_in[0];
    const float* net_features  = (const float*)d_in[1];
    const int*   src_nodes     = (const int*)d_in[2];
    const int*   sink_nodes    = (const int*)d_in[3];
    const int*   sink_nets     = (const int*)d_in[4];
    const float* edge_weight   = (const float*)d_in[5];
    const int*   batch         = (const int*)d_in[6];
    const float* ne_W1 = (const float*)d_in[7];
    const float* ne_b1 = (const float*)d_in[8];
    const float* ne_W2 = (const float*)d_in[9];
    const float* ne_b2 = (const float*)d_in[10];
    const float* te_W1 = (const float*)d_in[11];
    const float* te_b1 = (const float*)d_in[12];
    const float* te_W2 = (const float*)d_in[13];
    const float* te_b2 = (const float*)d_in[14];
    const float* vn_emb = (const float*)d_in[15];
    const float* conv_Wnet  = (const float*)d_in[16];
    const float* conv_bnet  = (const float*)d_in[17];
    const float* conv_Wnode = (const float*)d_in[18];
    const float* conv_bnode = (const float*)d_in[19];
    const float* vn_W1 = (const float*)d_in[20];
    const float* vn_b1 = (const float*)d_in[21];
    const float* vn_W2 = (const float*)d_in[22];
    const float* vn_b2 = (const float*)d_in[23];
    const float* fc1n_W = (const float*)d_in[24];
    const float* fc1n_b = (const float*)d_in[25];
    const float* fc2n_W = (const float*)d_in[26];
    const float* fc2n_b = (const float*)d_in[27];
    const float* fc1e_W = (const float*)d_in[28];
    const float* fc1e_b = (const float*)d_in[29];
    const float* fc2e_W = (const float*)d_in[30];
    const float* fc2e_b = (const float*)d_in[31];

    float* out_node = (float*)d_out;
    float* out_net  = out_node + (size_t)N_NODES * 4;

    // ---------- workspace layout ----------
    float* h      = (float*)d_ws;                        // N_NODES*64
    float* g      = h + (size_t)N_NODES * EMB;           // N_NETS*64
    float* scratch = g + (size_t)N_NETS * EMB;           // N_NODES*64 (agg then back)
    float* vn     = scratch + (size_t)N_NODES * EMB;     // NUM_VN*64
    float* pooled = vn + (size_t)NUM_VN * EMB;           // NUM_VN*64
    int* net_start  = (int*)(pooled + (size_t)NUM_VN * EMB);  // N_NETS+1
    int* node_start = net_start + (N_NETS + 1);               // N_NODES+1
    int* src_start  = node_start + (N_NODES + 1);             // N_NODES+1
    int* vn_start   = src_start + (N_NODES + 1);              // NUM_VN+1
    int*   e_node = vn_start + (NUM_VN + 1);                  // E
    float* e_w    = (float*)(e_node + E_SINK);                // E
    int*   e2_net = (int*)(e_w + E_SINK);                     // E
    float* e2_w   = (float*)(e2_net + E_SINK);                // E
    int*   s_net  = (int*)(e2_w + E_SINK);                    // N_NETS
    int*   b_node = s_net + N_NETS;                           // N_NODES
    int*   cnt    = b_node + N_NODES;
    int*   cnt_net  = cnt;
    int*   cnt_node = cnt + N_NETS;
    int*   cnt_src  = cnt_node + N_NODES;
    int*   cnt_vn   = cnt_src + N_NODES;
    const int CNT_TOTAL = N_NETS + N_NODES + N_NODES + NUM_VN;
    int*   bsum   = cnt + CNT_TOTAL;                          // 2048

    const int nodeTiles = (N_NODES + 63) / 64;
    const int netTiles  = (N_NETS + 63) / 64;
    const int vnBlocks  = (NUM_VN + 3) / 4;
    const int vnElemBlocks   = (NUM_VN * EMB + 255) / 256;
    const int nodeVec4Blocks = (N_NODES * 16 + 255) / 256;
    const int edgeThreadBlocks = (E_SINK + 255) / 256;
    const int miscThreadBlocks = (N_NODES + 255) / 256;
    const int netWaveBlocks  = (N_NETS + 3) / 4;    // 1 wave per row
    const int nodeWaveBlocks = (N_NODES + 3) / 4;

    // ---------- CSR build ----------
    hipMemsetAsync(cnt, 0, (size_t)CNT_TOTAL * sizeof(int), stream);
    k_hist_edges<<<edgeThreadBlocks, 256, 0, stream>>>(sink_nets, sink_nodes, cnt_net, cnt_node);
    k_hist_misc<<<miscThreadBlocks, 256, 0, stream>>>(src_nodes, batch, cnt_src, cnt_vn);

    auto scan = [&](int* cnt_arr, int n, int* start_arr) {
        int nb = (n + 255) / 256;
        k_scan1<<<nb, 256, 0, stream>>>(cnt_arr, n, bsum);
        k_scan2<<<1, 256, 0, stream>>>(bsum, nb);
        k_scan3<<<nb, 256, 0, stream>>>(cnt_arr, n, bsum, start_arr);
    };
    scan(cnt_net, N_NETS, net_start);
    scan(cnt_node, N_NODES, node_start);
    scan(cnt_src, N_NODES, src_start);
    scan(cnt_vn, NUM_VN, vn_start);

    hipMemsetAsync(cnt, 0, (size_t)CNT_TOTAL * sizeof(int), stream);
    k_fill_edges<<<edgeThreadBlocks, 256, 0, stream>>>(sink_nets, sink_nodes, edge_weight,
        net_start, node_start, cnt_net, cnt_node, e_node, e_w, e2_net, e2_w);
    k_fill_misc<<<miscThreadBlocks, 256, 0, stream>>>(src_nodes, batch, src_start, vn_start,
        cnt_src, cnt_vn, s_net, b_node);

    // ---------- encoders ----------
    k_node_enc_mfma<<<nodeTiles, 256, 0, stream>>>(node_features, ne_W1, ne_b1, ne_W2, ne_b2, h);
    k_net_enc_mfma<<<netTiles, 256, 0, stream>>>(net_features, te_W1, te_b1, te_W2, te_b2, g);
    k_vn_init<<<vnElemBlocks, 256, 0, stream>>>(vn, vn_emb);

    // ---------- layers ----------
    for (int l = 0; l < 3; ++l) {
        k_add_vn<<<nodeVec4Blocks, 256, 0, stream>>>((float4*)h, vn, batch);

        k_gather_agg<<<netWaveBlocks, 256, 0, stream>>>(scratch, h, net_start, e_node, e_w);
        k_conv_net_mfma<<<netTiles, 256, 0, stream>>>(g, h, scratch, src_nodes,
            conv_Wnet + (size_t)l * 192 * 64, conv_bnet + (size_t)l * 64, l > 0 ? 1 : 0);

        k_gather_back<<<nodeWaveBlocks, 256, 0, stream>>>(scratch, g,
            src_start, s_net, node_start, e2_net, e2_w);
        k_conv_node_mfma<<<nodeTiles, 256, 0, stream>>>(h, scratch,
            conv_Wnode + (size_t)l * 128 * 64, conv_bnode + (size_t)l * 64);

        if (l < 2) {
            k_pool_gather<<<NUM_VN, 256, 0, stream>>>(pooled, h, vn_start, b_node);
            k_vn_update<<<vnBlocks, 256, 0, stream>>>(vn, pooled,
                vn_W1 + (size_t)l * 64 * 64, vn_b1 + (size_t)l * 64,
                vn_W2 + (size_t)l * 64 * 64, vn_b2 + (size_t)l * 64);
        }
    }

    // ---------- heads ----------
    k_fc_node_mfma<<<nodeTiles, 256, 0, stream>>>(out_node, h, fc1n_W, fc1n_b, fc2n_W, fc2n_b);
    k_fc_net_mfma<<<netTiles, 256, 0, stream>>>(out_net, g, fc1e_W, fc1e_b, fc2e_W, fc2e_b);
}

// Round 7
// 1791.737 us; speedup vs baseline: 1.5947x; 1.0505x over previous
//
#include <hip/hip_runtime.h>
#include <cstdint>

static constexpr int N_NODES = 300000;
static constexpr int N_NETS  = 200000;
static constexpr int E_SINK  = 1000000;
static constexpr int NODE_DIM = 32;
static constexpr int NET_DIM  = 16;
static constexpr int EMB = 64;
static constexpr int NUM_VN = 1000;
#define SLOPE 0.01f

typedef __attribute__((ext_vector_type(8))) short bhalf8;
typedef __attribute__((ext_vector_type(4))) float floatx4;
typedef unsigned short u16;

__device__ __forceinline__ float leaky(float x) { return x >= 0.f ? x : SLOPE * x; }

// ---------- bf16 split / reconstruct ----------
__device__ __forceinline__ unsigned bf16_rne(float x) {
    unsigned u = __float_as_uint(x);
    return (u + 0x7FFFu + ((u >> 16) & 1u)) >> 16;
}
__device__ __forceinline__ void split1(float x, u16& hh, u16& ll) {
    unsigned hb = bf16_rne(x);
    float fh = __uint_as_float(hb << 16);
    unsigned lb = bf16_rne(x - fh);
    hh = (u16)hb; ll = (u16)lb;
}
__device__ __forceinline__ void split8v(const float* x, bhalf8& ah, bhalf8& al) {
#pragma unroll
    for (int e = 0; e < 8; ++e) {
        u16 hh, ll; split1(x[e], hh, ll);
        ah[e] = (short)hh; al[e] = (short)ll;
    }
}
__device__ __forceinline__ float rec1(short h, short l) {
    return __uint_as_float(((unsigned)(u16)h) << 16) +
           __uint_as_float(((unsigned)(u16)l) << 16);
}

// A-fragment from f32 global (encoders only)
__device__ __forceinline__ void afrag_f32(const float* rowp, int kbase, bhalf8& ah, bhalf8& al) {
    float4 v0 = *(const float4*)(rowp + kbase);
    float4 v1 = *(const float4*)(rowp + kbase + 4);
    float x[8] = {v0.x, v0.y, v0.z, v0.w, v1.x, v1.y, v1.z, v1.w};
    split8v(x, ah, al);
}
// A-fragment from planar hi/lo
__device__ __forceinline__ void afrag_hl(const u16* hi, const u16* lo, size_t off,
                                         bhalf8& ah, bhalf8& al) {
    ah = *(const bhalf8*)(hi + off);
    al = *(const bhalf8*)(lo + off);
}

__device__ __forceinline__ floatx4 mm3(bhalf8 ah, bhalf8 al, bhalf8 wh, bhalf8 wl, floatx4 c) {
    c = __builtin_amdgcn_mfma_f32_16x16x32_bf16(ah, wh, c, 0, 0, 0);
    c = __builtin_amdgcn_mfma_f32_16x16x32_bf16(ah, wl, c, 0, 0, 0);
    c = __builtin_amdgcn_mfma_f32_16x16x32_bf16(al, wh, c, 0, 0, 0);
    return c;
}

// ============ weight fragment prep ============
// frag-shorts layout per weight: idx = ((kt*ncols + col)*4 + g16)*8 + e ; k = kt*32+g16*8+e
static constexpr int OFF_NEW1 = 0;              // ncols=128 K=32  -> 4096
static constexpr int OFF_NEW2 = 4096;           // ncols=64  K=128 -> 8192
static constexpr int OFF_TEW1 = 12288;          // ncols=64  K=16  -> 2048
static constexpr int OFF_TEW2 = 14336;          // ncols=64  K=64  -> 4096
static constexpr int OFF_CWNET = 18432;         // 3 x (ncols=64 K=192 -> 12288)
static constexpr int OFF_CWNODE = 55296;        // 3 x (ncols=64 K=128 -> 8192)
static constexpr int OFF_FC1N = 79872;          // ncols=256 K=64  -> 16384
static constexpr int OFF_FC1E = 96256;          // ncols=64  K=64  -> 4096
static constexpr int W_TOTAL  = 100352;

__global__ void k_prep_w(const float* __restrict__ neW1, const float* __restrict__ neW2,
                         const float* __restrict__ teW1, const float* __restrict__ teW2,
                         const float* __restrict__ cWnet, const float* __restrict__ cWnode,
                         const float* __restrict__ fc1n, const float* __restrict__ fc1e,
                         u16* __restrict__ wfh, u16* __restrict__ wfl)
{
    int i = blockIdx.x * 256 + threadIdx.x;
    if (i >= W_TOTAL) return;
    int r, ncols, K; const float* src;
    if (i < OFF_NEW2)        { r = i;             src = neW1;  ncols = 128; K = 32; }
    else if (i < OFF_TEW1)   { r = i - OFF_NEW2;  src = neW2;  ncols = 64;  K = 128; }
    else if (i < OFF_TEW2)   { r = i - OFF_TEW1;  src = teW1;  ncols = 64;  K = 16; }
    else if (i < OFF_CWNET)  { r = i - OFF_TEW2;  src = teW2;  ncols = 64;  K = 64; }
    else if (i < OFF_CWNODE) { int t = i - OFF_CWNET;  int l = t / 12288; r = t % 12288;
                               src = cWnet + (size_t)l * 192 * 64; ncols = 64; K = 192; }
    else if (i < OFF_FC1N)   { int t = i - OFF_CWNODE; int l = t / 8192;  r = t % 8192;
                               src = cWnode + (size_t)l * 128 * 64; ncols = 64; K = 128; }
    else if (i < OFF_FC1E)   { r = i - OFF_FC1N;  src = fc1n;  ncols = 256; K = 64; }
    else                     { r = i - OFF_FC1E;  src = fc1e;  ncols = 64;  K = 64; }
    int e = r & 7, g = (r >> 3) & 3;
    int cidx = r >> 5;
    int col = cidx % ncols, kt = cidx / ncols;
    int k = kt * 32 + g * 8 + e;
    float v = (k < K) ? src[(size_t)k * ncols + col] : 0.f;
    u16 hh, ll; split1(v, hh, ll);
    wfh[i] = hh; wfl[i] = ll;
}

__device__ __forceinline__ bhalf8 ldw(const u16* p, int idx) {
    return *(const bhalf8*)(p + idx);
}

// ===================== CSR build =====================
__global__ void k_hist_edges(const int* __restrict__ sink_nets, const int* __restrict__ sink_nodes,
                             int* __restrict__ cnt_net, int* __restrict__ cnt_node)
{
    int e = blockIdx.x * 256 + threadIdx.x;
    if (e >= E_SINK) return;
    atomicAdd(&cnt_net[sink_nets[e]], 1);
    atomicAdd(&cnt_node[sink_nodes[e]], 1);
}

__global__ void k_hist_misc(const int* __restrict__ src_nodes, const int* __restrict__ batch,
                            int* __restrict__ cnt_src, int* __restrict__ cnt_vn)
{
    int i = blockIdx.x * 256 + threadIdx.x;
    if (i < N_NETS) atomicAdd(&cnt_src[src_nodes[i]], 1);
    if (i < N_NODES) atomicAdd(&cnt_vn[batch[i]], 1);
}

__global__ void k_scan1(const int* __restrict__ cnt, int n, int* __restrict__ bsum) {
    __shared__ int s[256];
    int i = blockIdx.x * 256 + threadIdx.x;
    s[threadIdx.x] = (i < n) ? cnt[i] : 0;
    __syncthreads();
    for (int off = 128; off; off >>= 1) {
        if (threadIdx.x < off) s[threadIdx.x] += s[threadIdx.x + off];
        __syncthreads();
    }
    if (threadIdx.x == 0) bsum[blockIdx.x] = s[0];
}

__global__ void k_scan2(int* __restrict__ data, int n) {
    __shared__ int s[256];
    __shared__ int carry_s;
    int tid = threadIdx.x;
    if (tid == 0) carry_s = 0;
    __syncthreads();
    for (int base = 0; base < n; base += 256) {
        int i = base + tid;
        int v = (i < n) ? data[i] : 0;
        s[tid] = v;
        __syncthreads();
        for (int off = 1; off < 256; off <<= 1) {
            int t = (tid >= off) ? s[tid - off] : 0;
            __syncthreads();
            s[tid] += t;
            __syncthreads();
        }
        int excl = s[tid] - v + carry_s;
        if (i < n) data[i] = excl;
        __syncthreads();
        if (tid == 255) carry_s = excl + v;
        __syncthreads();
    }
}

__global__ void k_scan3(const int* __restrict__ cnt, int n, const int* __restrict__ bsum,
                        int* __restrict__ start) {
    __shared__ int s[256];
    int i = blockIdx.x * 256 + threadIdx.x;
    int v = (i < n) ? cnt[i] : 0;
    s[threadIdx.x] = v;
    __syncthreads();
    for (int off = 1; off < 256; off <<= 1) {
        int t = (threadIdx.x >= off) ? s[threadIdx.x - off] : 0;
        __syncthreads();
        s[threadIdx.x] += t;
        __syncthreads();
    }
    int excl = s[threadIdx.x] - v + bsum[blockIdx.x];
    if (i < n) start[i] = excl;
    if (i == n - 1) start[n] = excl + v;
}

__global__ void k_fill_edges(const int* __restrict__ sink_nets, const int* __restrict__ sink_nodes,
                             const float* __restrict__ ew,
                             const int* __restrict__ net_start, const int* __restrict__ node_start,
                             int* __restrict__ cur_net, int* __restrict__ cur_node,
                             int* __restrict__ e_node, float* __restrict__ e_w,
                             int* __restrict__ e2_net, float* __restrict__ e2_w)
{
    int e = blockIdx.x * 256 + threadIdx.x;
    if (e >= E_SINK) return;
    int tn = sink_nets[e], dn = sink_nodes[e];
    float w = ew[e];
    int p = net_start[tn] + atomicAdd(&cur_net[tn], 1);
    e_node[p] = dn; e_w[p] = w;
    int q = node_start[dn] + atomicAdd(&cur_node[dn], 1);
    e2_net[q] = tn; e2_w[q] = w;
}

__global__ void k_fill_misc(const int* __restrict__ src_nodes, const int* __restrict__ batch,
                            const int* __restrict__ src_start, const int* __restrict__ vn_start,
                            int* __restrict__ cur_src, int* __restrict__ cur_vn,
                            int* __restrict__ s_net, int* __restrict__ b_node)
{
    int i = blockIdx.x * 256 + threadIdx.x;
    if (i < N_NETS) {
        int d = src_nodes[i];
        int p = src_start[d] + atomicAdd(&cur_src[d], 1);
        s_net[p] = i;
    }
    if (i < N_NODES) {
        int v = batch[i];
        int p = vn_start[v] + atomicAdd(&cur_vn[v], 1);
        b_node[p] = i;
    }
}

// ===================== gathers (wave per row, 8 lanes/edge) =====================
__global__ __launch_bounds__(256) void k_gather_agg(
    u16* __restrict__ agg_hi, u16* __restrict__ agg_lo,
    const u16* __restrict__ h_hi, const u16* __restrict__ h_lo,
    const int* __restrict__ net_start, const int* __restrict__ e_node, const float* __restrict__ e_w)
{
    int w = (blockIdx.x * 256 + threadIdx.x) >> 6;
    if (w >= N_NETS) return;
    int lane = threadIdx.x & 63;
    int grp = lane >> 3, l8 = lane & 7;
    int j0 = net_start[w], j1 = net_start[w + 1];
    float a[8] = {0.f, 0.f, 0.f, 0.f, 0.f, 0.f, 0.f, 0.f};
    for (int j = j0 + grp; j < j1; j += 8) {
        int idx = e_node[j];
        float wt = e_w[j];
        size_t off = (size_t)idx * 64 + l8 * 8;
        bhalf8 vh = *(const bhalf8*)(h_hi + off);
        bhalf8 vl = *(const bhalf8*)(h_lo + off);
#pragma unroll
        for (int e = 0; e < 8; ++e) a[e] += wt * rec1(vh[e], vl[e]);
    }
#pragma unroll
    for (int e = 0; e < 8; ++e) {
        a[e] += __shfl_xor(a[e], 8, 64);
        a[e] += __shfl_xor(a[e], 16, 64);
        a[e] += __shfl_xor(a[e], 32, 64);
    }
    if (grp == 0) {
        bhalf8 oh, ol;
        split8v(a, oh, ol);
        size_t off = (size_t)w * 64 + l8 * 8;
        *(bhalf8*)(agg_hi + off) = oh;
        *(bhalf8*)(agg_lo + off) = ol;
    }
}

// back = segsum(g_raw, src) + segsum(g_raw[sink_nets]*w, sink); g stored leaky -> invert
__global__ __launch_bounds__(256) void k_gather_back(
    u16* __restrict__ back_hi, u16* __restrict__ back_lo,
    const u16* __restrict__ g_hi, const u16* __restrict__ g_lo,
    const int* __restrict__ src_start, const int* __restrict__ s_net,
    const int* __restrict__ node_start, const int* __restrict__ e2_net, const float* __restrict__ e2_w)
{
    int w = (blockIdx.x * 256 + threadIdx.x) >> 6;
    if (w >= N_NODES) return;
    int lane = threadIdx.x & 63;
    int grp = lane >> 3, l8 = lane & 7;
    float a[8] = {0.f, 0.f, 0.f, 0.f, 0.f, 0.f, 0.f, 0.f};
    int j0 = src_start[w], j1 = src_start[w + 1];
    for (int j = j0 + grp; j < j1; j += 8) {
        int idx = s_net[j];
        size_t off = (size_t)idx * 64 + l8 * 8;
        bhalf8 vh = *(const bhalf8*)(g_hi + off);
        bhalf8 vl = *(const bhalf8*)(g_lo + off);
#pragma unroll
        for (int e = 0; e < 8; ++e) {
            float f = rec1(vh[e], vl[e]);
            a[e] += (f >= 0.f) ? f : f * 100.f;   // inverse leaky
        }
    }
    j0 = node_start[w]; j1 = node_start[w + 1];
    for (int j = j0 + grp; j < j1; j += 8) {
        int idx = e2_net[j];
        float wt = e2_w[j];
        size_t off = (size_t)idx * 64 + l8 * 8;
        bhalf8 vh = *(const bhalf8*)(g_hi + off);
        bhalf8 vl = *(const bhalf8*)(g_lo + off);
#pragma unroll
        for (int e = 0; e < 8; ++e) {
            float f = rec1(vh[e], vl[e]);
            a[e] += wt * ((f >= 0.f) ? f : f * 100.f);
        }
    }
#pragma unroll
    for (int e = 0; e < 8; ++e) {
        a[e] += __shfl_xor(a[e], 8, 64);
        a[e] += __shfl_xor(a[e], 16, 64);
        a[e] += __shfl_xor(a[e], 32, 64);
    }
    if (grp == 0) {
        bhalf8 oh, ol;
        split8v(a, oh, ol);
        size_t off = (size_t)w * 64 + l8 * 8;
        *(bhalf8*)(back_hi + off) = oh;
        *(bhalf8*)(back_lo + off) = ol;
    }
}

// ================= pooling: block per VN =================
__global__ __launch_bounds__(256) void k_pool_gather(
    float* __restrict__ pooled, const u16* __restrict__ h_hi, const u16* __restrict__ h_lo,
    const int* __restrict__ vn_start, const int* __restrict__ b_node)
{
    __shared__ float red[32][64];
    int tid = threadIdx.x;
    int grp = tid >> 3, l8 = tid & 7;
    int v = blockIdx.x;
    int j0 = vn_start[v], j1 = vn_start[v + 1];
    const float NEG = -__builtin_inff();
    float m[8] = {NEG, NEG, NEG, NEG, NEG, NEG, NEG, NEG};
    for (int j = j0 + grp; j < j1; j += 32) {
        int nd = b_node[j];
        size_t off = (size_t)nd * 64 + l8 * 8;
        bhalf8 vh = *(const bhalf8*)(h_hi + off);
        bhalf8 vl = *(const bhalf8*)(h_lo + off);
#pragma unroll
        for (int e = 0; e < 8; ++e) m[e] = fmaxf(m[e], rec1(vh[e], vl[e]));
    }
#pragma unroll
    for (int e = 0; e < 8; ++e) red[grp][l8 * 8 + e] = m[e];
    __syncthreads();
    if (tid < 64) {
        float mm = red[0][tid];
#pragma unroll
        for (int q = 1; q < 32; ++q) mm = fmaxf(mm, red[q][tid]);
        pooled[(size_t)v * 64 + tid] = mm;
    }
}

// ================= encoders =================
// node: 32 -> 128 (leaky) -> 64 ; writes h hi/lo
__global__ __launch_bounds__(256) void k_node_enc(
    const float* __restrict__ x, const u16* __restrict__ wfh, const u16* __restrict__ wfl,
    const float* __restrict__ b1, const float* __restrict__ b2,
    u16* __restrict__ h_hi, u16* __restrict__ h_lo)
{
    __shared__ u16 t_hi[64][136];
    __shared__ u16 t_lo[64][136];
    int lane = threadIdx.x & 63, wid = threadIdx.x >> 6;
    int g16 = lane >> 4, l15 = lane & 15;
    int rbase = blockIdx.x * 64;

    bhalf8 W1H[2], W1L[2];
#pragma unroll
    for (int s = 0; s < 2; ++s) {
        int col = wid * 16 + s * 64 + l15;
        int fo = OFF_NEW1 + (col * 4 + g16) * 8;
        W1H[s] = ldw(wfh, fo); W1L[s] = ldw(wfl, fo);
    }
    bhalf8 W2H[4], W2L[4];
    int cs = wid * 16 + l15;
#pragma unroll
    for (int kt = 0; kt < 4; ++kt) {
        int fo = OFF_NEW2 + ((kt * 64 + cs) * 4 + g16) * 8;
        W2H[kt] = ldw(wfh, fo); W2L[kt] = ldw(wfl, fo);
    }

#pragma unroll
    for (int ms = 0; ms < 4; ++ms) {
        int r = min(rbase + ms * 16 + l15, N_NODES - 1);
        bhalf8 ah, al;
        afrag_f32(x + (size_t)r * NODE_DIM, g16 * 8, ah, al);
#pragma unroll
        for (int s = 0; s < 2; ++s) {
            floatx4 acc = {0.f, 0.f, 0.f, 0.f};
            acc = mm3(ah, al, W1H[s], W1L[s], acc);
            int hc = wid * 16 + s * 64 + l15;
            float bb = b1[hc];
#pragma unroll
            for (int i = 0; i < 4; ++i) {
                u16 hh, ll;
                split1(leaky(acc[i] + bb), hh, ll);
                t_hi[ms * 16 + g16 * 4 + i][hc] = hh;
                t_lo[ms * 16 + g16 * 4 + i][hc] = ll;
            }
        }
    }
    __syncthreads();

    float bias = b2[cs];
#pragma unroll
    for (int ms = 0; ms < 4; ++ms) {
        floatx4 acc = {0.f, 0.f, 0.f, 0.f};
#pragma unroll
        for (int kt = 0; kt < 4; ++kt) {
            bhalf8 ah = *(const bhalf8*)(&t_hi[ms * 16 + l15][kt * 32 + g16 * 8]);
            bhalf8 al = *(const bhalf8*)(&t_lo[ms * 16 + l15][kt * 32 + g16 * 8]);
            acc = mm3(ah, al, W2H[kt], W2L[kt], acc);
        }
#pragma unroll
        for (int i = 0; i < 4; ++i) {
            int r = rbase + ms * 16 + g16 * 4 + i;
            if (r < N_NODES) {
                u16 hh, ll;
                split1(acc[i] + bias, hh, ll);
                h_hi[(size_t)r * 64 + cs] = hh;
                h_lo[(size_t)r * 64 + cs] = ll;
            }
        }
    }
}

// net: 16 -> 64 (leaky) -> 64 ; writes g hi/lo (raw encoder output)
__global__ __launch_bounds__(256) void k_net_enc(
    const float* __restrict__ x, const u16* __restrict__ wfh, const u16* __restrict__ wfl,
    const float* __restrict__ b1, const float* __restrict__ b2,
    u16* __restrict__ g_hi, u16* __restrict__ g_lo)
{
    __shared__ u16 t_hi[64][72];
    __shared__ u16 t_lo[64][72];
    int lane = threadIdx.x & 63, wid = threadIdx.x >> 6;
    int g16 = lane >> 4, l15 = lane & 15;
    int rbase = blockIdx.x * 64;
    int cs = wid * 16 + l15;

    int fo = OFF_TEW1 + (cs * 4 + g16) * 8;
    bhalf8 W1H = ldw(wfh, fo), W1L = ldw(wfl, fo);
    bhalf8 W2H[2], W2L[2];
#pragma unroll
    for (int kt = 0; kt < 2; ++kt) {
        int f2 = OFF_TEW2 + ((kt * 64 + cs) * 4 + g16) * 8;
        W2H[kt] = ldw(wfh, f2); W2L[kt] = ldw(wfl, f2);
    }

#pragma unroll
    for (int ms = 0; ms < 4; ++ms) {
        int r = min(rbase + ms * 16 + l15, N_NETS - 1);
        bhalf8 ah = {0,0,0,0,0,0,0,0}, al = {0,0,0,0,0,0,0,0};
        if (g16 < 2) afrag_f32(x + (size_t)r * NET_DIM, g16 * 8, ah, al);
        floatx4 acc = {0.f, 0.f, 0.f, 0.f};
        acc = mm3(ah, al, W1H, W1L, acc);
        float bb = b1[cs];
#pragma unroll
        for (int i = 0; i < 4; ++i) {
            u16 hh, ll;
            split1(leaky(acc[i] + bb), hh, ll);
            t_hi[ms * 16 + g16 * 4 + i][cs] = hh;
            t_lo[ms * 16 + g16 * 4 + i][cs] = ll;
        }
    }
    __syncthreads();

    float bias = b2[cs];
#pragma unroll
    for (int ms = 0; ms < 4; ++ms) {
        floatx4 acc = {0.f, 0.f, 0.f, 0.f};
#pragma unroll
        for (int kt = 0; kt < 2; ++kt) {
            bhalf8 ah = *(const bhalf8*)(&t_hi[ms * 16 + l15][kt * 32 + g16 * 8]);
            bhalf8 al = *(const bhalf8*)(&t_lo[ms * 16 + l15][kt * 32 + g16 * 8]);
            acc = mm3(ah, al, W2H[kt], W2L[kt], acc);
        }
#pragma unroll
        for (int i = 0; i < 4; ++i) {
            int r = rbase + ms * 16 + g16 * 4 + i;
            if (r < N_NETS) {
                u16 hh, ll;
                split1(acc[i] + bias, hh, ll);   // raw (no leaky) for l=0 cat
                g_hi[(size_t)r * 64 + cs] = hh;
                g_lo[(size_t)r * 64 + cs] = ll;
            }
        }
    }
}

// ================= misc elementwise =================
__global__ void k_vn_init(float* __restrict__ vn, const float* __restrict__ vn_emb) {
    int idx = blockIdx.x * blockDim.x + threadIdx.x;
    if (idx < NUM_VN * EMB) vn[idx] = vn_emb[idx & 63];
}

__global__ void k_add_vn(u16* __restrict__ h_hi, u16* __restrict__ h_lo,
                         const float* __restrict__ vn, const int* __restrict__ batch) {
    int idx = blockIdx.x * blockDim.x + threadIdx.x;
    if (idx >= N_NODES * 8) return;
    int n = idx >> 3, c8 = idx & 7;
    size_t off = (size_t)n * 64 + c8 * 8;
    bhalf8 vh = *(const bhalf8*)(h_hi + off);
    bhalf8 vl = *(const bhalf8*)(h_lo + off);
    const float* vr = vn + (size_t)batch[n] * 64 + c8 * 8;
    float out[8];
#pragma unroll
    for (int e = 0; e < 8; ++e) out[e] = rec1(vh[e], vl[e]) + vr[e];
    bhalf8 oh, ol;
    split8v(out, oh, ol);
    *(bhalf8*)(h_hi + off) = oh;
    *(bhalf8*)(h_lo + off) = ol;
}

// ========== conv_net: g_new_cat = leaky(cat(g_cat, h[src], agg) @ W + b); stored hi/lo ==========
__global__ __launch_bounds__(256) void k_conv_net(
    u16* g_hi, u16* g_lo,
    const u16* __restrict__ h_hi, const u16* __restrict__ h_lo,
    const u16* __restrict__ s_hi, const u16* __restrict__ s_lo,
    const int* __restrict__ src,
    const u16* __restrict__ wfh, const u16* __restrict__ wfl, int wbase,
    const float* __restrict__ b)
{
    int lane = threadIdx.x & 63, wid = threadIdx.x >> 6;
    int g16 = lane >> 4, l15 = lane & 15;
    int rbase = blockIdx.x * 64;
    int cs = wid * 16 + l15;

    bhalf8 WH[6], WL[6];
#pragma unroll
    for (int kt = 0; kt < 6; ++kt) {
        int fo = wbase + ((kt * 64 + cs) * 4 + g16) * 8;
        WH[kt] = ldw(wfh, fo); WL[kt] = ldw(wfl, fo);
    }

    // prefetch own g rows (in-place hazard) then barrier
    bhalf8 GH[4][2], GL[4][2];
#pragma unroll
    for (int ms = 0; ms < 4; ++ms) {
        int r = min(rbase + ms * 16 + l15, N_NETS - 1);
#pragma unroll
        for (int kt = 0; kt < 2; ++kt)
            afrag_hl(g_hi, g_lo, (size_t)r * 64 + kt * 32 + g16 * 8, GH[ms][kt], GL[ms][kt]);
    }
    __syncthreads();

    float bias = b[cs];
#pragma unroll
    for (int ms = 0; ms < 4; ++ms) {
        floatx4 acc = {0.f, 0.f, 0.f, 0.f};
#pragma unroll
        for (int kt = 0; kt < 2; ++kt) acc = mm3(GH[ms][kt], GL[ms][kt], WH[kt], WL[kt], acc);
        int ar = min(rbase + ms * 16 + l15, N_NETS - 1);
        size_t srow = (size_t)src[ar] * 64;
#pragma unroll
        for (int kt = 0; kt < 2; ++kt) {
            bhalf8 ah, al;
            afrag_hl(h_hi, h_lo, srow + kt * 32 + g16 * 8, ah, al);
            acc = mm3(ah, al, WH[2 + kt], WL[2 + kt], acc);
        }
#pragma unroll
        for (int kt = 0; kt < 2; ++kt) {
            bhalf8 ah, al;
            afrag_hl(s_hi, s_lo, (size_t)ar * 64 + kt * 32 + g16 * 8, ah, al);
            acc = mm3(ah, al, WH[4 + kt], WL[4 + kt], acc);
        }
#pragma unroll
        for (int i = 0; i < 4; ++i) {
            int r = rbase + ms * 16 + g16 * 4 + i;
            if (r < N_NETS) {
                u16 hh, ll;
                split1(leaky(acc[i] + bias), hh, ll);
                g_hi[(size_t)r * 64 + cs] = hh;
                g_lo[(size_t)r * 64 + cs] = ll;
            }
        }
    }
}

// ========== conv_node: h_new = leaky(cat(h, back) @ W + b); stored hi/lo ==========
__global__ __launch_bounds__(256) void k_conv_node(
    u16* h_hi, u16* h_lo,
    const u16* __restrict__ s_hi, const u16* __restrict__ s_lo,
    const u16* __restrict__ wfh, const u16* __restrict__ wfl, int wbase,
    const float* __restrict__ b)
{
    int lane = threadIdx.x & 63, wid = threadIdx.x >> 6;
    int g16 = lane >> 4, l15 = lane & 15;
    int rbase = blockIdx.x * 64;
    int cs = wid * 16 + l15;

    bhalf8 WH[4], WL[4];
#pragma unroll
    for (int kt = 0; kt < 4; ++kt) {
        int fo = wbase + ((kt * 64 + cs) * 4 + g16) * 8;
        WH[kt] = ldw(wfh, fo); WL[kt] = ldw(wfl, fo);
    }

    bhalf8 HH[4][2], HL[4][2];
#pragma unroll
    for (int ms = 0; ms < 4; ++ms) {
        int r = min(rbase + ms * 16 + l15, N_NODES - 1);
#pragma unroll
        for (int kt = 0; kt < 2; ++kt)
            afrag_hl(h_hi, h_lo, (size_t)r * 64 + kt * 32 + g16 * 8, HH[ms][kt], HL[ms][kt]);
    }
    __syncthreads();

    float bias = b[cs];
#pragma unroll
    for (int ms = 0; ms < 4; ++ms) {
        floatx4 acc = {0.f, 0.f, 0.f, 0.f};
#pragma unroll
        for (int kt = 0; kt < 2; ++kt) acc = mm3(HH[ms][kt], HL[ms][kt], WH[kt], WL[kt], acc);
        int ar = min(rbase + ms * 16 + l15, N_NODES - 1);
#pragma unroll
        for (int kt = 0; kt < 2; ++kt) {
            bhalf8 ah, al;
            afrag_hl(s_hi, s_lo, (size_t)ar * 64 + kt * 32 + g16 * 8, ah, al);
            acc = mm3(ah, al, WH[2 + kt], WL[2 + kt], acc);
        }
#pragma unroll
        for (int i = 0; i < 4; ++i) {
            int r = rbase + ms * 16 + g16 * 4 + i;
            if (r < N_NODES) {
                u16 hh, ll;
                split1(leaky(acc[i] + bias), hh, ll);
                h_hi[(size_t)r * 64 + cs] = hh;
                h_lo[(size_t)r * 64 + cs] = ll;
            }
        }
    }
}

// ================= virtual-node MLP (f32, tiny) =================
__global__ __launch_bounds__(256) void k_vn_update(
    float* __restrict__ vn, const float* __restrict__ pooled,
    const float* __restrict__ W1, const float* __restrict__ b1,
    const float* __restrict__ W2, const float* __restrict__ b2)
{
    int wv = threadIdx.x >> 6, lane = threadIdx.x & 63;
    int v = blockIdx.x * 4 + wv;
    if (v >= NUM_VN) return;
    float p = pooled[(size_t)v * 64 + lane];
    float vv = vn[v * 64 + lane];
    float tmp = p + vv;
    float t1 = b1[lane];
#pragma unroll 16
    for (int k = 0; k < 64; ++k) t1 += __shfl(tmp, k, 64) * W1[k * 64 + lane];
    t1 = leaky(t1);
    float t2 = b2[lane];
#pragma unroll 16
    for (int k = 0; k < 64; ++k) t2 += __shfl(t1, k, 64) * W2[k * 64 + lane];
    vn[v * 64 + lane] = vv + t2;
}

// ========== fc_node head: 64 -> 256 (leaky) -> 4, abs ; layer2 in f32 VALU ==========
__global__ __launch_bounds__(256) void k_fc_node(
    float* __restrict__ out, const u16* __restrict__ h_hi, const u16* __restrict__ h_lo,
    const u16* __restrict__ wfh, const u16* __restrict__ wfl,
    const float* __restrict__ b1, const float* __restrict__ W2, const float* __restrict__ b2)
{
    __shared__ float red[4][64][4];
    int lane = threadIdx.x & 63, wid = threadIdx.x >> 6;
    int g16 = lane >> 4, l15 = lane & 15;
    int rbase = blockIdx.x * 64;

    bhalf8 W1H[4][2], W1L[4][2];
    float4 w2v[4];
    float b1v[4];
#pragma unroll
    for (int s = 0; s < 4; ++s) {
        int hc = wid * 16 + s * 64 + l15;
#pragma unroll
        for (int kt = 0; kt < 2; ++kt) {
            int fo = OFF_FC1N + ((kt * 256 + hc) * 4 + g16) * 8;
            W1H[s][kt] = ldw(wfh, fo); W1L[s][kt] = ldw(wfl, fo);
        }
        w2v[s] = *(const float4*)(W2 + hc * 4);
        b1v[s] = b1[hc];
    }

#pragma unroll
    for (int ms = 0; ms < 4; ++ms) {
        int r = min(rbase + ms * 16 + l15, N_NODES - 1);
        bhalf8 ah[2], al[2];
#pragma unroll
        for (int kt = 0; kt < 2; ++kt)
            afrag_hl(h_hi, h_lo, (size_t)r * 64 + kt * 32 + g16 * 8, ah[kt], al[kt]);
        float po[4][4] = {{0.f,0.f,0.f,0.f},{0.f,0.f,0.f,0.f},{0.f,0.f,0.f,0.f},{0.f,0.f,0.f,0.f}};
#pragma unroll
        for (int s = 0; s < 4; ++s) {
            floatx4 acc = {0.f, 0.f, 0.f, 0.f};
#pragma unroll
            for (int kt = 0; kt < 2; ++kt) acc = mm3(ah[kt], al[kt], W1H[s][kt], W1L[s][kt], acc);
#pragma unroll
            for (int i = 0; i < 4; ++i) {
                float act = leaky(acc[i] + b1v[s]);
                po[i][0] += act * w2v[s].x;
                po[i][1] += act * w2v[s].y;
                po[i][2] += act * w2v[s].z;
                po[i][3] += act * w2v[s].w;
            }
        }
#pragma unroll
        for (int i = 0; i < 4; ++i)
#pragma unroll
            for (int o = 0; o < 4; ++o) {
                po[i][o] += __shfl_xor(po[i][o], 1, 64);
                po[i][o] += __shfl_xor(po[i][o], 2, 64);
                po[i][o] += __shfl_xor(po[i][o], 4, 64);
                po[i][o] += __shfl_xor(po[i][o], 8, 64);
            }
        if (l15 == 0) {
#pragma unroll
            for (int i = 0; i < 4; ++i)
#pragma unroll
                for (int o = 0; o < 4; ++o)
                    red[wid][ms * 16 + g16 * 4 + i][o] = po[i][o];
        }
    }
    __syncthreads();
    int tid = threadIdx.x;
    int row = tid >> 2, o = tid & 3;
    float sum = red[0][row][o] + red[1][row][o] + red[2][row][o] + red[3][row][o];
    int r = rbase + row;
    if (r < N_NODES) out[(size_t)r * 4 + o] = fabsf(sum + b2[o]);
}

// ========== fc_net head: 64 -> 64 (leaky) -> 4, abs ; g stored leaky already ==========
__global__ __launch_bounds__(256) void k_fc_net(
    float* __restrict__ out, const u16* __restrict__ g_hi, const u16* __restrict__ g_lo,
    const u16* __restrict__ wfh, const u16* __restrict__ wfl,
    const float* __restrict__ b1, const float* __restrict__ W2, const float* __restrict__ b2)
{
    __shared__ float red[4][64][4];
    int lane = threadIdx.x & 63, wid = threadIdx.x >> 6;
    int g16 = lane >> 4, l15 = lane & 15;
    int rbase = blockIdx.x * 64;
    int cs = wid * 16 + l15;

    bhalf8 W1H[2], W1L[2];
#pragma unroll
    for (int kt = 0; kt < 2; ++kt) {
        int fo = OFF_FC1E + ((kt * 64 + cs) * 4 + g16) * 8;
        W1H[kt] = ldw(wfh, fo); W1L[kt] = ldw(wfl, fo);
    }
    float4 w2v = *(const float4*)(W2 + cs * 4);
    float b1v = b1[cs];

#pragma unroll
    for (int ms = 0; ms < 4; ++ms) {
        int r = min(rbase + ms * 16 + l15, N_NETS - 1);
        bhalf8 ah[2], al[2];
#pragma unroll
        for (int kt = 0; kt < 2; ++kt)
            afrag_hl(g_hi, g_lo, (size_t)r * 64 + kt * 32 + g16 * 8, ah[kt], al[kt]);
        floatx4 acc = {0.f, 0.f, 0.f, 0.f};
#pragma unroll
        for (int kt = 0; kt < 2; ++kt) acc = mm3(ah[kt], al[kt], W1H[kt], W1L[kt], acc);
        float po[4][4];
#pragma unroll
        for (int i = 0; i < 4; ++i) {
            float act = leaky(acc[i] + b1v);
            po[i][0] = act * w2v.x;
            po[i][1] = act * w2v.y;
            po[i][2] = act * w2v.z;
            po[i][3] = act * w2v.w;
        }
#pragma unroll
        for (int i = 0; i < 4; ++i)
#pragma unroll
            for (int o = 0; o < 4; ++o) {
                po[i][o] += __shfl_xor(po[i][o], 1, 64);
                po[i][o] += __shfl_xor(po[i][o], 2, 64);
                po[i][o] += __shfl_xor(po[i][o], 4, 64);
                po[i][o] += __shfl_xor(po[i][o], 8, 64);
            }
        if (l15 == 0) {
#pragma unroll
            for (int i = 0; i < 4; ++i)
#pragma unroll
                for (int o = 0; o < 4; ++o)
                    red[wid][ms * 16 + g16 * 4 + i][o] = po[i][o];
        }
    }
    __syncthreads();
    int tid = threadIdx.x;
    int row = tid >> 2, o = tid & 3;
    float sum = red[0][row][o] + red[1][row][o] + red[2][row][o] + red[3][row][o];
    int r = rbase + row;
    if (r < N_NETS) out[(size_t)r * 4 + o] = fabsf(sum + b2[o]);
}

extern "C" void kernel_launch(void* const* d_in, const int* in_sizes, int n_in,
                              void* d_out, int out_size, void* d_ws, size_t ws_size,
                              hipStream_t stream)
{
    const float* node_features = (const float*)d_in[0];
    const float* net_features  = (const float*)d_in[1];
    const int*   src_nodes     = (const int*)d_in[2];
    const int*   sink_nodes    = (const int*)d_in[3];
    const int*   sink_nets     = (const int*)d_in[4];
    const float* edge_weight   = (const float*)d_in[5];
    const int*   batch         = (const int*)d_in[6];
    const float* ne_W1 = (const float*)d_in[7];
    const float* ne_b1 = (const float*)d_in[8];
    const float* ne_W2 = (const float*)d_in[9];
    const float* ne_b2 = (const float*)d_in[10];
    const float* te_W1 = (const float*)d_in[11];
    const float* te_b1 = (const float*)d_in[12];
    const float* te_W2 = (const float*)d_in[13];
    const float* te_b2 = (const float*)d_in[14];
    const float* vn_emb = (const float*)d_in[15];
    const float* conv_Wnet  = (const float*)d_in[16];
    const float* conv_bnet  = (const float*)d_in[17];
    const float* conv_Wnode = (const float*)d_in[18];
    const float* conv_bnode = (const float*)d_in[19];
    const float* vn_W1 = (const float*)d_in[20];
    const float* vn_b1 = (const float*)d_in[21];
    const float* vn_W2 = (const float*)d_in[22];
    const float* vn_b2 = (const float*)d_in[23];
    const float* fc1n_W = (const float*)d_in[24];
    const float* fc1n_b = (const float*)d_in[25];
    const float* fc2n_W = (const float*)d_in[26];
    const float* fc2n_b = (const float*)d_in[27];
    const float* fc1e_W = (const float*)d_in[28];
    const float* fc1e_b = (const float*)d_in[29];
    const float* fc2e_W = (const float*)d_in[30];
    const float* fc2e_b = (const float*)d_in[31];

    float* out_node = (float*)d_out;
    float* out_net  = out_node + (size_t)N_NODES * 4;

    // ---------- workspace ----------
    u16* h_hi = (u16*)d_ws;
    u16* h_lo = h_hi + (size_t)N_NODES * 64;
    u16* g_hi = h_lo + (size_t)N_NODES * 64;
    u16* g_lo = g_hi + (size_t)N_NETS * 64;
    u16* s_hi = g_lo + (size_t)N_NETS * 64;
    u16* s_lo = s_hi + (size_t)N_NODES * 64;
    u16* wfh  = s_lo + (size_t)N_NODES * 64;
    u16* wfl  = wfh + W_TOTAL;
    float* vn     = (float*)(wfl + W_TOTAL);
    float* pooled = vn + (size_t)NUM_VN * EMB;
    int* net_start  = (int*)(pooled + (size_t)NUM_VN * EMB);
    int* node_start = net_start + (N_NETS + 1);
    int* src_start  = node_start + (N_NODES + 1);
    int* vn_start   = src_start + (N_NODES + 1);
    int*   e_node = vn_start + (NUM_VN + 1);
    float* e_w    = (float*)(e_node + E_SINK);
    int*   e2_net = (int*)(e_w + E_SINK);
    float* e2_w   = (float*)(e2_net + E_SINK);
    int*   s_net  = (int*)(e2_w + E_SINK);
    int*   b_node = s_net + N_NETS;
    int*   cnt    = b_node + N_NODES;
    int*   cnt_net  = cnt;
    int*   cnt_node = cnt + N_NETS;
    int*   cnt_src  = cnt_node + N_NODES;
    int*   cnt_vn   = cnt_src + N_NODES;
    const int CNT_TOTAL = N_NETS + N_NODES + N_NODES + NUM_VN;
    int*   bsum   = cnt + CNT_TOTAL;

    const int nodeTiles = (N_NODES + 63) / 64;
    const int netTiles  = (N_NETS + 63) / 64;
    const int vnBlocks  = (NUM_VN + 3) / 4;
    const int vnElemBlocks  = (NUM_VN * EMB + 255) / 256;
    const int addVnBlocks  = (N_NODES * 8 + 255) / 256;
    const int edgeThreadBlocks = (E_SINK + 255) / 256;
    const int miscThreadBlocks = (N_NODES + 255) / 256;
    const int netWaveBlocks  = (N_NETS + 3) / 4;
    const int nodeWaveBlocks = (N_NODES + 3) / 4;
    const int prepBlocks = (W_TOTAL + 255) / 256;

    // ---------- CSR build ----------
    hipMemsetAsync(cnt, 0, (size_t)CNT_TOTAL * sizeof(int), stream);
    k_hist_edges<<<edgeThreadBlocks, 256, 0, stream>>>(sink_nets, sink_nodes, cnt_net, cnt_node);
    k_hist_misc<<<miscThreadBlocks, 256, 0, stream>>>(src_nodes, batch, cnt_src, cnt_vn);

    auto scan = [&](int* cnt_arr, int n, int* start_arr) {
        int nb = (n + 255) / 256;
        k_scan1<<<nb, 256, 0, stream>>>(cnt_arr, n, bsum);
        k_scan2<<<1, 256, 0, stream>>>(bsum, nb);
        k_scan3<<<nb, 256, 0, stream>>>(cnt_arr, n, bsum, start_arr);
    };
    scan(cnt_net, N_NETS, net_start);
    scan(cnt_node, N_NODES, node_start);
    scan(cnt_src, N_NODES, src_start);
    scan(cnt_vn, NUM_VN, vn_start);

    hipMemsetAsync(cnt, 0, (size_t)CNT_TOTAL * sizeof(int), stream);
    k_fill_edges<<<edgeThreadBlocks, 256, 0, stream>>>(sink_nets, sink_nodes, edge_weight,
        net_start, node_start, cnt_net, cnt_node, e_node, e_w, e2_net, e2_w);
    k_fill_misc<<<miscThreadBlocks, 256, 0, stream>>>(src_nodes, batch, src_start, vn_start,
        cnt_src, cnt_vn, s_net, b_node);

    // ---------- weight frags + encoders ----------
    k_prep_w<<<prepBlocks, 256, 0, stream>>>(ne_W1, ne_W2, te_W1, te_W2,
                                             conv_Wnet, conv_Wnode, fc1n_W, fc1e_W, wfh, wfl);
    k_node_enc<<<nodeTiles, 256, 0, stream>>>(node_features, wfh, wfl, ne_b1, ne_b2, h_hi, h_lo);
    k_net_enc<<<netTiles, 256, 0, stream>>>(net_features, wfh, wfl, te_b1, te_b2, g_hi, g_lo);
    k_vn_init<<<vnElemBlocks, 256, 0, stream>>>(vn, vn_emb);

    // ---------- layers ----------
    for (int l = 0; l < 3; ++l) {
        k_add_vn<<<addVnBlocks, 256, 0, stream>>>(h_hi, h_lo, vn, batch);

        k_gather_agg<<<netWaveBlocks, 256, 0, stream>>>(s_hi, s_lo, h_hi, h_lo,
                                                        net_start, e_node, e_w);
        k_conv_net<<<netTiles, 256, 0, stream>>>(g_hi, g_lo, h_hi, h_lo, s_hi, s_lo, src_nodes,
            wfh, wfl, OFF_CWNET + l * 12288, conv_bnet + (size_t)l * 64);

        k_gather_back<<<nodeWaveBlocks, 256, 0, stream>>>(s_hi, s_lo, g_hi, g_lo,
            src_start, s_net, node_start, e2_net, e2_w);
        k_conv_node<<<nodeTiles, 256, 0, stream>>>(h_hi, h_lo, s_hi, s_lo,
            wfh, wfl, OFF_CWNODE + l * 8192, conv_bnode + (size_t)l * 64);

        if (l < 2) {
            k_pool_gather<<<NUM_VN, 256, 0, stream>>>(pooled, h_hi, h_lo, vn_start, b_node);
            k_vn_update<<<vnBlocks, 256, 0, stream>>>(vn, pooled,
                vn_W1 + (size_t)l * 64 * 64, vn_b1 + (size_t)l * 64,
                vn_W2 + (size_t)l * 64 * 64, vn_b2 + (size_t)l * 64);
        }
    }

    // ---------- heads ----------
    k_fc_node<<<nodeTiles, 256, 0, stream>>>(out_node, h_hi, h_lo, wfh, wfl,
                                             fc1n_b, fc2n_W, fc2n_b);
    k_fc_net<<<netTiles, 256, 0, stream>>>(out_net, g_hi, g_lo, wfh, wfl,
                                           fc1e_b, fc2e_W, fc2e_b);
}

// Round 8
// 1779.155 us; speedup vs baseline: 1.6060x; 1.0071x over previous
//
#include <hip/hip_runtime.h>
#include <cstdint>

static constexpr int N_NODES = 300000;
static constexpr int N_NETS  = 200000;
static constexpr int E_SINK  = 1000000;
static constexpr int NODE_DIM = 32;
static constexpr int NET_DIM  = 16;
static constexpr int EMB = 64;
static constexpr int NUM_VN = 1000;
#define SLOPE 0.01f

typedef __attribute__((ext_vector_type(8))) short bhalf8;
typedef __attribute__((ext_vector_type(4))) float floatx4;
typedef unsigned short u16;

__device__ __forceinline__ float leaky(float x) { return x >= 0.f ? x : SLOPE * x; }

// ---------- bf16 split / reconstruct ----------
__device__ __forceinline__ unsigned bf16_rne(float x) {
    unsigned u = __float_as_uint(x);
    return (u + 0x7FFFu + ((u >> 16) & 1u)) >> 16;
}
__device__ __forceinline__ void split1(float x, u16& hh, u16& ll) {
    unsigned hb = bf16_rne(x);
    float fh = __uint_as_float(hb << 16);
    unsigned lb = bf16_rne(x - fh);
    hh = (u16)hb; ll = (u16)lb;
}
__device__ __forceinline__ void split8v(const float* x, bhalf8& ah, bhalf8& al) {
#pragma unroll
    for (int e = 0; e < 8; ++e) {
        u16 hh, ll; split1(x[e], hh, ll);
        ah[e] = (short)hh; al[e] = (short)ll;
    }
}
__device__ __forceinline__ float rec1(short h, short l) {
    return __uint_as_float(((unsigned)(u16)h) << 16) +
           __uint_as_float(((unsigned)(u16)l) << 16);
}

__device__ __forceinline__ void afrag_f32(const float* rowp, int kbase, bhalf8& ah, bhalf8& al) {
    float4 v0 = *(const float4*)(rowp + kbase);
    float4 v1 = *(const float4*)(rowp + kbase + 4);
    float x[8] = {v0.x, v0.y, v0.z, v0.w, v1.x, v1.y, v1.z, v1.w};
    split8v(x, ah, al);
}
__device__ __forceinline__ void afrag_hl(const u16* hi, const u16* lo, size_t off,
                                         bhalf8& ah, bhalf8& al) {
    ah = *(const bhalf8*)(hi + off);
    al = *(const bhalf8*)(lo + off);
}

__device__ __forceinline__ floatx4 mm3(bhalf8 ah, bhalf8 al, bhalf8 wh, bhalf8 wl, floatx4 c) {
    c = __builtin_amdgcn_mfma_f32_16x16x32_bf16(ah, wh, c, 0, 0, 0);
    c = __builtin_amdgcn_mfma_f32_16x16x32_bf16(ah, wl, c, 0, 0, 0);
    c = __builtin_amdgcn_mfma_f32_16x16x32_bf16(al, wh, c, 0, 0, 0);
    return c;
}

// ============ weight fragment prep ============
static constexpr int OFF_NEW1 = 0;
static constexpr int OFF_NEW2 = 4096;
static constexpr int OFF_TEW1 = 12288;
static constexpr int OFF_TEW2 = 14336;
static constexpr int OFF_CWNET = 18432;
static constexpr int OFF_CWNODE = 55296;
static constexpr int OFF_FC1N = 79872;
static constexpr int OFF_FC1E = 96256;
static constexpr int W_TOTAL  = 100352;

__global__ void k_prep_w(const float* __restrict__ neW1, const float* __restrict__ neW2,
                         const float* __restrict__ teW1, const float* __restrict__ teW2,
                         const float* __restrict__ cWnet, const float* __restrict__ cWnode,
                         const float* __restrict__ fc1n, const float* __restrict__ fc1e,
                         u16* __restrict__ wfh, u16* __restrict__ wfl)
{
    int i = blockIdx.x * 256 + threadIdx.x;
    if (i >= W_TOTAL) return;
    int r, ncols, K; const float* src;
    if (i < OFF_NEW2)        { r = i;             src = neW1;  ncols = 128; K = 32; }
    else if (i < OFF_TEW1)   { r = i - OFF_NEW2;  src = neW2;  ncols = 64;  K = 128; }
    else if (i < OFF_TEW2)   { r = i - OFF_TEW1;  src = teW1;  ncols = 64;  K = 16; }
    else if (i < OFF_CWNET)  { r = i - OFF_TEW2;  src = teW2;  ncols = 64;  K = 64; }
    else if (i < OFF_CWNODE) { int t = i - OFF_CWNET;  int l = t / 12288; r = t % 12288;
                               src = cWnet + (size_t)l * 192 * 64; ncols = 64; K = 192; }
    else if (i < OFF_FC1N)   { int t = i - OFF_CWNODE; int l = t / 8192;  r = t % 8192;
                               src = cWnode + (size_t)l * 128 * 64; ncols = 64; K = 128; }
    else if (i < OFF_FC1E)   { r = i - OFF_FC1N;  src = fc1n;  ncols = 256; K = 64; }
    else                     { r = i - OFF_FC1E;  src = fc1e;  ncols = 64;  K = 64; }
    int e = r & 7, g = (r >> 3) & 3;
    int cidx = r >> 5;
    int col = cidx % ncols, kt = cidx / ncols;
    int k = kt * 32 + g * 8 + e;
    float v = (k < K) ? src[(size_t)k * ncols + col] : 0.f;
    u16 hh, ll; split1(v, hh, ll);
    wfh[i] = hh; wfl[i] = ll;
}

__device__ __forceinline__ bhalf8 ldw(const u16* p, int idx) {
    return *(const bhalf8*)(p + idx);
}

// ===================== CSR build =====================
__global__ void k_hist_edges(const int* __restrict__ sink_nets, const int* __restrict__ sink_nodes,
                             int* __restrict__ cnt_net, int* __restrict__ cnt_node)
{
    int e = blockIdx.x * 256 + threadIdx.x;
    if (e >= E_SINK) return;
    atomicAdd(&cnt_net[sink_nets[e]], 1);
    atomicAdd(&cnt_node[sink_nodes[e]], 1);
}

__global__ void k_hist_misc(const int* __restrict__ src_nodes, const int* __restrict__ batch,
                            int* __restrict__ cnt_src, int* __restrict__ cnt_vn)
{
    int i = blockIdx.x * 256 + threadIdx.x;
    if (i < N_NETS) atomicAdd(&cnt_src[src_nodes[i]], 1);
    if (i < N_NODES) atomicAdd(&cnt_vn[batch[i]], 1);
}

__global__ void k_scan1(const int* __restrict__ cnt, int n, int* __restrict__ bsum) {
    __shared__ int s[256];
    int i = blockIdx.x * 256 + threadIdx.x;
    s[threadIdx.x] = (i < n) ? cnt[i] : 0;
    __syncthreads();
    for (int off = 128; off; off >>= 1) {
        if (threadIdx.x < off) s[threadIdx.x] += s[threadIdx.x + off];
        __syncthreads();
    }
    if (threadIdx.x == 0) bsum[blockIdx.x] = s[0];
}

__global__ void k_scan2(int* __restrict__ data, int n) {
    __shared__ int s[256];
    __shared__ int carry_s;
    int tid = threadIdx.x;
    if (tid == 0) carry_s = 0;
    __syncthreads();
    for (int base = 0; base < n; base += 256) {
        int i = base + tid;
        int v = (i < n) ? data[i] : 0;
        s[tid] = v;
        __syncthreads();
        for (int off = 1; off < 256; off <<= 1) {
            int t = (tid >= off) ? s[tid - off] : 0;
            __syncthreads();
            s[tid] += t;
            __syncthreads();
        }
        int excl = s[tid] - v + carry_s;
        if (i < n) data[i] = excl;
        __syncthreads();
        if (tid == 255) carry_s = excl + v;
        __syncthreads();
    }
}

__global__ void k_scan3(const int* __restrict__ cnt, int n, const int* __restrict__ bsum,
                        int* __restrict__ start) {
    __shared__ int s[256];
    int i = blockIdx.x * 256 + threadIdx.x;
    int v = (i < n) ? cnt[i] : 0;
    s[threadIdx.x] = v;
    __syncthreads();
    for (int off = 1; off < 256; off <<= 1) {
        int t = (threadIdx.x >= off) ? s[threadIdx.x - off] : 0;
        __syncthreads();
        s[threadIdx.x] += t;
        __syncthreads();
    }
    int excl = s[threadIdx.x] - v + bsum[blockIdx.x];
    if (i < n) start[i] = excl;
    if (i == n - 1) start[n] = excl + v;
}

__global__ void k_fill_edges(const int* __restrict__ sink_nets, const int* __restrict__ sink_nodes,
                             const float* __restrict__ ew,
                             const int* __restrict__ net_start, const int* __restrict__ node_start,
                             int* __restrict__ cur_net, int* __restrict__ cur_node,
                             int2* __restrict__ e_pack, int2* __restrict__ e2_pack)
{
    int e = blockIdx.x * 256 + threadIdx.x;
    if (e >= E_SINK) return;
    int tn = sink_nets[e], dn = sink_nodes[e];
    int wbits = __float_as_int(ew[e]);
    int p = net_start[tn] + atomicAdd(&cur_net[tn], 1);
    e_pack[p] = make_int2(dn, wbits);
    int q = node_start[dn] + atomicAdd(&cur_node[dn], 1);
    e2_pack[q] = make_int2(tn, wbits);
}

__global__ void k_fill_misc(const int* __restrict__ src_nodes, const int* __restrict__ batch,
                            const int* __restrict__ src_start, const int* __restrict__ vn_start,
                            int* __restrict__ cur_src, int* __restrict__ cur_vn,
                            int* __restrict__ s_net, int* __restrict__ b_node)
{
    int i = blockIdx.x * 256 + threadIdx.x;
    if (i < N_NETS) {
        int d = src_nodes[i];
        int p = src_start[d] + atomicAdd(&cur_src[d], 1);
        s_net[p] = i;
    }
    if (i < N_NODES) {
        int v = batch[i];
        int p = vn_start[v] + atomicAdd(&cur_vn[v], 1);
        b_node[p] = i;
    }
}

// ===================== gathers (wave per row, 8 lanes/edge) =====================
template<bool HF32>
__global__ __launch_bounds__(256) void k_gather_agg(
    u16* __restrict__ agg_hi, u16* __restrict__ agg_lo,
    const u16* __restrict__ h_hi, const u16* __restrict__ h_lo, const float* __restrict__ h_f32,
    const int* __restrict__ net_start, const int2* __restrict__ e_pack)
{
    int w = (blockIdx.x * 256 + threadIdx.x) >> 6;
    if (w >= N_NETS) return;
    int lane = threadIdx.x & 63;
    int grp = lane >> 3, l8 = lane & 7;
    int j0 = net_start[w], j1 = net_start[w + 1];
    float a[8] = {0.f, 0.f, 0.f, 0.f, 0.f, 0.f, 0.f, 0.f};
    for (int j = j0 + grp; j < j1; j += 8) {
        int2 pk = e_pack[j];
        float wt = __int_as_float(pk.y);
        if (HF32) {
            const float4* rp = (const float4*)(h_f32 + (size_t)pk.x * 64 + l8 * 8);
            float4 v0 = rp[0], v1 = rp[1];
            a[0] += wt * v0.x; a[1] += wt * v0.y; a[2] += wt * v0.z; a[3] += wt * v0.w;
            a[4] += wt * v1.x; a[5] += wt * v1.y; a[6] += wt * v1.z; a[7] += wt * v1.w;
        } else {
            size_t off = (size_t)pk.x * 64 + l8 * 8;
            bhalf8 vh = *(const bhalf8*)(h_hi + off);
            bhalf8 vl = *(const bhalf8*)(h_lo + off);
#pragma unroll
            for (int e = 0; e < 8; ++e) a[e] += wt * rec1(vh[e], vl[e]);
        }
    }
#pragma unroll
    for (int e = 0; e < 8; ++e) {
        a[e] += __shfl_xor(a[e], 8, 64);
        a[e] += __shfl_xor(a[e], 16, 64);
        a[e] += __shfl_xor(a[e], 32, 64);
    }
    if (grp == 0) {
        bhalf8 oh, ol;
        split8v(a, oh, ol);
        size_t off = (size_t)w * 64 + l8 * 8;
        *(bhalf8*)(agg_hi + off) = oh;
        *(bhalf8*)(agg_lo + off) = ol;
    }
}

// back = segsum(g_raw, src) + segsum(g_raw[sink_nets]*w, sink)
template<bool GF32>
__global__ __launch_bounds__(256) void k_gather_back(
    u16* __restrict__ back_hi, u16* __restrict__ back_lo,
    const u16* __restrict__ g_hi, const u16* __restrict__ g_lo, const float* __restrict__ g_raw,
    const int* __restrict__ src_start, const int* __restrict__ s_net,
    const int* __restrict__ node_start, const int2* __restrict__ e2_pack)
{
    int w = (blockIdx.x * 256 + threadIdx.x) >> 6;
    if (w >= N_NODES) return;
    int lane = threadIdx.x & 63;
    int grp = lane >> 3, l8 = lane & 7;
    float a[8] = {0.f, 0.f, 0.f, 0.f, 0.f, 0.f, 0.f, 0.f};
    int j0 = src_start[w], j1 = src_start[w + 1];
    for (int j = j0 + grp; j < j1; j += 8) {
        int idx = s_net[j];
        if (GF32) {
            const float4* rp = (const float4*)(g_raw + (size_t)idx * 64 + l8 * 8);
            float4 v0 = rp[0], v1 = rp[1];
            a[0] += v0.x; a[1] += v0.y; a[2] += v0.z; a[3] += v0.w;
            a[4] += v1.x; a[5] += v1.y; a[6] += v1.z; a[7] += v1.w;
        } else {
            size_t off = (size_t)idx * 64 + l8 * 8;
            bhalf8 vh = *(const bhalf8*)(g_hi + off);
            bhalf8 vl = *(const bhalf8*)(g_lo + off);
#pragma unroll
            for (int e = 0; e < 8; ++e) {
                float f = rec1(vh[e], vl[e]);
                a[e] += (f >= 0.f) ? f : f * 100.f;
            }
        }
    }
    j0 = node_start[w]; j1 = node_start[w + 1];
    for (int j = j0 + grp; j < j1; j += 8) {
        int2 pk = e2_pack[j];
        float wt = __int_as_float(pk.y);
        if (GF32) {
            const float4* rp = (const float4*)(g_raw + (size_t)pk.x * 64 + l8 * 8);
            float4 v0 = rp[0], v1 = rp[1];
            a[0] += wt * v0.x; a[1] += wt * v0.y; a[2] += wt * v0.z; a[3] += wt * v0.w;
            a[4] += wt * v1.x; a[5] += wt * v1.y; a[6] += wt * v1.z; a[7] += wt * v1.w;
        } else {
            size_t off = (size_t)pk.x * 64 + l8 * 8;
            bhalf8 vh = *(const bhalf8*)(g_hi + off);
            bhalf8 vl = *(const bhalf8*)(g_lo + off);
#pragma unroll
            for (int e = 0; e < 8; ++e) {
                float f = rec1(vh[e], vl[e]);
                a[e] += wt * ((f >= 0.f) ? f : f * 100.f);
            }
        }
    }
#pragma unroll
    for (int e = 0; e < 8; ++e) {
        a[e] += __shfl_xor(a[e], 8, 64);
        a[e] += __shfl_xor(a[e], 16, 64);
        a[e] += __shfl_xor(a[e], 32, 64);
    }
    if (grp == 0) {
        bhalf8 oh, ol;
        split8v(a, oh, ol);
        size_t off = (size_t)w * 64 + l8 * 8;
        *(bhalf8*)(back_hi + off) = oh;
        *(bhalf8*)(back_lo + off) = ol;
    }
}

// ================= pooling: block per VN =================
template<bool HF32>
__global__ __launch_bounds__(256) void k_pool_gather(
    float* __restrict__ pooled, const u16* __restrict__ h_hi, const u16* __restrict__ h_lo,
    const float* __restrict__ h_f32,
    const int* __restrict__ vn_start, const int* __restrict__ b_node)
{
    __shared__ float red[32][64];
    int tid = threadIdx.x;
    int grp = tid >> 3, l8 = tid & 7;
    int v = blockIdx.x;
    int j0 = vn_start[v], j1 = vn_start[v + 1];
    const float NEG = -__builtin_inff();
    float m[8] = {NEG, NEG, NEG, NEG, NEG, NEG, NEG, NEG};
    for (int j = j0 + grp; j < j1; j += 32) {
        int nd = b_node[j];
        if (HF32) {
            const float4* rp = (const float4*)(h_f32 + (size_t)nd * 64 + l8 * 8);
            float4 v0 = rp[0], v1 = rp[1];
            m[0] = fmaxf(m[0], v0.x); m[1] = fmaxf(m[1], v0.y);
            m[2] = fmaxf(m[2], v0.z); m[3] = fmaxf(m[3], v0.w);
            m[4] = fmaxf(m[4], v1.x); m[5] = fmaxf(m[5], v1.y);
            m[6] = fmaxf(m[6], v1.z); m[7] = fmaxf(m[7], v1.w);
        } else {
            size_t off = (size_t)nd * 64 + l8 * 8;
            bhalf8 vh = *(const bhalf8*)(h_hi + off);
            bhalf8 vl = *(const bhalf8*)(h_lo + off);
#pragma unroll
            for (int e = 0; e < 8; ++e) m[e] = fmaxf(m[e], rec1(vh[e], vl[e]));
        }
    }
#pragma unroll
    for (int e = 0; e < 8; ++e) red[grp][l8 * 8 + e] = m[e];
    __syncthreads();
    if (tid < 64) {
        float mm = red[0][tid];
#pragma unroll
        for (int q = 1; q < 32; ++q) mm = fmaxf(mm, red[q][tid]);
        pooled[(size_t)v * 64 + tid] = mm;
    }
}

// ================= encoders =================
__global__ __launch_bounds__(256) void k_node_enc(
    const float* __restrict__ x, const u16* __restrict__ wfh, const u16* __restrict__ wfl,
    const float* __restrict__ b1, const float* __restrict__ b2,
    u16* __restrict__ h_hi, u16* __restrict__ h_lo, float* __restrict__ h_f32)
{
    __shared__ u16 t_hi[64][136];
    __shared__ u16 t_lo[64][136];
    int lane = threadIdx.x & 63, wid = threadIdx.x >> 6;
    int g16 = lane >> 4, l15 = lane & 15;
    int rbase = blockIdx.x * 64;

    bhalf8 W1H[2], W1L[2];
#pragma unroll
    for (int s = 0; s < 2; ++s) {
        int col = wid * 16 + s * 64 + l15;
        int fo = OFF_NEW1 + (col * 4 + g16) * 8;
        W1H[s] = ldw(wfh, fo); W1L[s] = ldw(wfl, fo);
    }
    bhalf8 W2H[4], W2L[4];
    int cs = wid * 16 + l15;
#pragma unroll
    for (int kt = 0; kt < 4; ++kt) {
        int fo = OFF_NEW2 + ((kt * 64 + cs) * 4 + g16) * 8;
        W2H[kt] = ldw(wfh, fo); W2L[kt] = ldw(wfl, fo);
    }

#pragma unroll
    for (int ms = 0; ms < 4; ++ms) {
        int r = min(rbase + ms * 16 + l15, N_NODES - 1);
        bhalf8 ah, al;
        afrag_f32(x + (size_t)r * NODE_DIM, g16 * 8, ah, al);
#pragma unroll
        for (int s = 0; s < 2; ++s) {
            floatx4 acc = {0.f, 0.f, 0.f, 0.f};
            acc = mm3(ah, al, W1H[s], W1L[s], acc);
            int hc = wid * 16 + s * 64 + l15;
            float bb = b1[hc];
#pragma unroll
            for (int i = 0; i < 4; ++i) {
                u16 hh, ll;
                split1(leaky(acc[i] + bb), hh, ll);
                t_hi[ms * 16 + g16 * 4 + i][hc] = hh;
                t_lo[ms * 16 + g16 * 4 + i][hc] = ll;
            }
        }
    }
    __syncthreads();

    float bias = b2[cs];
#pragma unroll
    for (int ms = 0; ms < 4; ++ms) {
        floatx4 acc = {0.f, 0.f, 0.f, 0.f};
#pragma unroll
        for (int kt = 0; kt < 4; ++kt) {
            bhalf8 ah = *(const bhalf8*)(&t_hi[ms * 16 + l15][kt * 32 + g16 * 8]);
            bhalf8 al = *(const bhalf8*)(&t_lo[ms * 16 + l15][kt * 32 + g16 * 8]);
            acc = mm3(ah, al, W2H[kt], W2L[kt], acc);
        }
#pragma unroll
        for (int i = 0; i < 4; ++i) {
            int r = rbase + ms * 16 + g16 * 4 + i;
            if (r < N_NODES) {
                float v = acc[i] + bias;
                if (h_f32) h_f32[(size_t)r * 64 + cs] = v;
                u16 hh, ll;
                split1(v, hh, ll);
                h_hi[(size_t)r * 64 + cs] = hh;
                h_lo[(size_t)r * 64 + cs] = ll;
            }
        }
    }
}

__global__ __launch_bounds__(256) void k_net_enc(
    const float* __restrict__ x, const u16* __restrict__ wfh, const u16* __restrict__ wfl,
    const float* __restrict__ b1, const float* __restrict__ b2,
    u16* __restrict__ g_hi, u16* __restrict__ g_lo)
{
    __shared__ u16 t_hi[64][72];
    __shared__ u16 t_lo[64][72];
    int lane = threadIdx.x & 63, wid = threadIdx.x >> 6;
    int g16 = lane >> 4, l15 = lane & 15;
    int rbase = blockIdx.x * 64;
    int cs = wid * 16 + l15;

    int fo = OFF_TEW1 + (cs * 4 + g16) * 8;
    bhalf8 W1H = ldw(wfh, fo), W1L = ldw(wfl, fo);
    bhalf8 W2H[2], W2L[2];
#pragma unroll
    for (int kt = 0; kt < 2; ++kt) {
        int f2 = OFF_TEW2 + ((kt * 64 + cs) * 4 + g16) * 8;
        W2H[kt] = ldw(wfh, f2); W2L[kt] = ldw(wfl, f2);
    }

#pragma unroll
    for (int ms = 0; ms < 4; ++ms) {
        int r = min(rbase + ms * 16 + l15, N_NETS - 1);
        bhalf8 ah = {0,0,0,0,0,0,0,0}, al = {0,0,0,0,0,0,0,0};
        if (g16 < 2) afrag_f32(x + (size_t)r * NET_DIM, g16 * 8, ah, al);
        floatx4 acc = {0.f, 0.f, 0.f, 0.f};
        acc = mm3(ah, al, W1H, W1L, acc);
        float bb = b1[cs];
#pragma unroll
        for (int i = 0; i < 4; ++i) {
            u16 hh, ll;
            split1(leaky(acc[i] + bb), hh, ll);
            t_hi[ms * 16 + g16 * 4 + i][cs] = hh;
            t_lo[ms * 16 + g16 * 4 + i][cs] = ll;
        }
    }
    __syncthreads();

    float bias = b2[cs];
#pragma unroll
    for (int ms = 0; ms < 4; ++ms) {
        floatx4 acc = {0.f, 0.f, 0.f, 0.f};
#pragma unroll
        for (int kt = 0; kt < 2; ++kt) {
            bhalf8 ah = *(const bhalf8*)(&t_hi[ms * 16 + l15][kt * 32 + g16 * 8]);
            bhalf8 al = *(const bhalf8*)(&t_lo[ms * 16 + l15][kt * 32 + g16 * 8]);
            acc = mm3(ah, al, W2H[kt], W2L[kt], acc);
        }
#pragma unroll
        for (int i = 0; i < 4; ++i) {
            int r = rbase + ms * 16 + g16 * 4 + i;
            if (r < N_NETS) {
                u16 hh, ll;
                split1(acc[i] + bias, hh, ll);   // raw for l=0 cat
                g_hi[(size_t)r * 64 + cs] = hh;
                g_lo[(size_t)r * 64 + cs] = ll;
            }
        }
    }
}

// ================= misc elementwise =================
__global__ void k_vn_init(float* __restrict__ vn, const float* __restrict__ vn_emb) {
    int idx = blockIdx.x * blockDim.x + threadIdx.x;
    if (idx < NUM_VN * EMB) vn[idx] = vn_emb[idx & 63];
}

__global__ void k_add_vn(u16* __restrict__ h_hi, u16* __restrict__ h_lo, float* __restrict__ h_f32,
                         const float* __restrict__ vn, const int* __restrict__ batch) {
    int idx = blockIdx.x * blockDim.x + threadIdx.x;
    if (idx >= N_NODES * 8) return;
    int n = idx >> 3, c8 = idx & 7;
    size_t off = (size_t)n * 64 + c8 * 8;
    const float* vr = vn + (size_t)batch[n] * 64 + c8 * 8;
    float out[8];
    if (h_f32) {
        const float4* hp = (const float4*)(h_f32 + off);
        float4 v0 = hp[0], v1 = hp[1];
        out[0] = v0.x + vr[0]; out[1] = v0.y + vr[1]; out[2] = v0.z + vr[2]; out[3] = v0.w + vr[3];
        out[4] = v1.x + vr[4]; out[5] = v1.y + vr[5]; out[6] = v1.z + vr[6]; out[7] = v1.w + vr[7];
        float4* wp = (float4*)(h_f32 + off);
        wp[0] = make_float4(out[0], out[1], out[2], out[3]);
        wp[1] = make_float4(out[4], out[5], out[6], out[7]);
    } else {
        bhalf8 vh = *(const bhalf8*)(h_hi + off);
        bhalf8 vl = *(const bhalf8*)(h_lo + off);
#pragma unroll
        for (int e = 0; e < 8; ++e) out[e] = rec1(vh[e], vl[e]) + vr[e];
    }
    bhalf8 oh, ol;
    split8v(out, oh, ol);
    *(bhalf8*)(h_hi + off) = oh;
    *(bhalf8*)(h_lo + off) = ol;
}

// ========== conv_net ==========
__global__ __launch_bounds__(256) void k_conv_net(
    u16* g_hi, u16* g_lo, float* __restrict__ g_raw,
    const u16* __restrict__ h_hi, const u16* __restrict__ h_lo,
    const u16* __restrict__ s_hi, const u16* __restrict__ s_lo,
    const int* __restrict__ src,
    const u16* __restrict__ wfh, const u16* __restrict__ wfl, int wbase,
    const float* __restrict__ b)
{
    int lane = threadIdx.x & 63, wid = threadIdx.x >> 6;
    int g16 = lane >> 4, l15 = lane & 15;
    int rbase = blockIdx.x * 64;
    int cs = wid * 16 + l15;

    bhalf8 WH[6], WL[6];
#pragma unroll
    for (int kt = 0; kt < 6; ++kt) {
        int fo = wbase + ((kt * 64 + cs) * 4 + g16) * 8;
        WH[kt] = ldw(wfh, fo); WL[kt] = ldw(wfl, fo);
    }

    bhalf8 GH[4][2], GL[4][2];
#pragma unroll
    for (int ms = 0; ms < 4; ++ms) {
        int r = min(rbase + ms * 16 + l15, N_NETS - 1);
#pragma unroll
        for (int kt = 0; kt < 2; ++kt)
            afrag_hl(g_hi, g_lo, (size_t)r * 64 + kt * 32 + g16 * 8, GH[ms][kt], GL[ms][kt]);
    }
    __syncthreads();

    float bias = b[cs];
#pragma unroll
    for (int ms = 0; ms < 4; ++ms) {
        floatx4 acc = {0.f, 0.f, 0.f, 0.f};
#pragma unroll
        for (int kt = 0; kt < 2; ++kt) acc = mm3(GH[ms][kt], GL[ms][kt], WH[kt], WL[kt], acc);
        int ar = min(rbase + ms * 16 + l15, N_NETS - 1);
        size_t srow = (size_t)src[ar] * 64;
#pragma unroll
        for (int kt = 0; kt < 2; ++kt) {
            bhalf8 ah, al;
            afrag_hl(h_hi, h_lo, srow + kt * 32 + g16 * 8, ah, al);
            acc = mm3(ah, al, WH[2 + kt], WL[2 + kt], acc);
        }
#pragma unroll
        for (int kt = 0; kt < 2; ++kt) {
            bhalf8 ah, al;
            afrag_hl(s_hi, s_lo, (size_t)ar * 64 + kt * 32 + g16 * 8, ah, al);
            acc = mm3(ah, al, WH[4 + kt], WL[4 + kt], acc);
        }
#pragma unroll
        for (int i = 0; i < 4; ++i) {
            int r = rbase + ms * 16 + g16 * 4 + i;
            if (r < N_NETS) {
                float graw = acc[i] + bias;
                if (g_raw) g_raw[(size_t)r * 64 + cs] = graw;
                u16 hh, ll;
                split1(leaky(graw), hh, ll);
                g_hi[(size_t)r * 64 + cs] = hh;
                g_lo[(size_t)r * 64 + cs] = ll;
            }
        }
    }
}

// ========== conv_node ==========
__global__ __launch_bounds__(256) void k_conv_node(
    u16* h_hi, u16* h_lo, float* __restrict__ h_f32,
    const u16* __restrict__ s_hi, const u16* __restrict__ s_lo,
    const u16* __restrict__ wfh, const u16* __restrict__ wfl, int wbase,
    const float* __restrict__ b)
{
    int lane = threadIdx.x & 63, wid = threadIdx.x >> 6;
    int g16 = lane >> 4, l15 = lane & 15;
    int rbase = blockIdx.x * 64;
    int cs = wid * 16 + l15;

    bhalf8 WH[4], WL[4];
#pragma unroll
    for (int kt = 0; kt < 4; ++kt) {
        int fo = wbase + ((kt * 64 + cs) * 4 + g16) * 8;
        WH[kt] = ldw(wfh, fo); WL[kt] = ldw(wfl, fo);
    }

    bhalf8 HH[4][2], HL[4][2];
#pragma unroll
    for (int ms = 0; ms < 4; ++ms) {
        int r = min(rbase + ms * 16 + l15, N_NODES - 1);
#pragma unroll
        for (int kt = 0; kt < 2; ++kt)
            afrag_hl(h_hi, h_lo, (size_t)r * 64 + kt * 32 + g16 * 8, HH[ms][kt], HL[ms][kt]);
    }
    __syncthreads();

    float bias = b[cs];
#pragma unroll
    for (int ms = 0; ms < 4; ++ms) {
        floatx4 acc = {0.f, 0.f, 0.f, 0.f};
#pragma unroll
        for (int kt = 0; kt < 2; ++kt) acc = mm3(HH[ms][kt], HL[ms][kt], WH[kt], WL[kt], acc);
        int ar = min(rbase + ms * 16 + l15, N_NODES - 1);
#pragma unroll
        for (int kt = 0; kt < 2; ++kt) {
            bhalf8 ah, al;
            afrag_hl(s_hi, s_lo, (size_t)ar * 64 + kt * 32 + g16 * 8, ah, al);
            acc = mm3(ah, al, WH[2 + kt], WL[2 + kt], acc);
        }
#pragma unroll
        for (int i = 0; i < 4; ++i) {
            int r = rbase + ms * 16 + g16 * 4 + i;
            if (r < N_NODES) {
                float hval = leaky(acc[i] + bias);
                if (h_f32) h_f32[(size_t)r * 64 + cs] = hval;
                u16 hh, ll;
                split1(hval, hh, ll);
                h_hi[(size_t)r * 64 + cs] = hh;
                h_lo[(size_t)r * 64 + cs] = ll;
            }
        }
    }
}

// ================= virtual-node MLP =================
__global__ __launch_bounds__(256) void k_vn_update(
    float* __restrict__ vn, const float* __restrict__ pooled,
    const float* __restrict__ W1, const float* __restrict__ b1,
    const float* __restrict__ W2, const float* __restrict__ b2)
{
    int wv = threadIdx.x >> 6, lane = threadIdx.x & 63;
    int v = blockIdx.x * 4 + wv;
    if (v >= NUM_VN) return;
    float p = pooled[(size_t)v * 64 + lane];
    float vv = vn[v * 64 + lane];
    float tmp = p + vv;
    float t1 = b1[lane];
#pragma unroll 16
    for (int k = 0; k < 64; ++k) t1 += __shfl(tmp, k, 64) * W1[k * 64 + lane];
    t1 = leaky(t1);
    float t2 = b2[lane];
#pragma unroll 16
    for (int k = 0; k < 64; ++k) t2 += __shfl(t1, k, 64) * W2[k * 64 + lane];
    vn[v * 64 + lane] = vv + t2;
}

// ========== fc_node head ==========
__global__ __launch_bounds__(256) void k_fc_node(
    float* __restrict__ out, const u16* __restrict__ h_hi, const u16* __restrict__ h_lo,
    const u16* __restrict__ wfh, const u16* __restrict__ wfl,
    const float* __restrict__ b1, const float* __restrict__ W2, const float* __restrict__ b2)
{
    __shared__ float red[4][64][4];
    int lane = threadIdx.x & 63, wid = threadIdx.x >> 6;
    int g16 = lane >> 4, l15 = lane & 15;
    int rbase = blockIdx.x * 64;

    bhalf8 W1H[4][2], W1L[4][2];
    float4 w2v[4];
    float b1v[4];
#pragma unroll
    for (int s = 0; s < 4; ++s) {
        int hc = wid * 16 + s * 64 + l15;
#pragma unroll
        for (int kt = 0; kt < 2; ++kt) {
            int fo = OFF_FC1N + ((kt * 256 + hc) * 4 + g16) * 8;
            W1H[s][kt] = ldw(wfh, fo); W1L[s][kt] = ldw(wfl, fo);
        }
        w2v[s] = *(const float4*)(W2 + hc * 4);
        b1v[s] = b1[hc];
    }

#pragma unroll
    for (int ms = 0; ms < 4; ++ms) {
        int r = min(rbase + ms * 16 + l15, N_NODES - 1);
        bhalf8 ah[2], al[2];
#pragma unroll
        for (int kt = 0; kt < 2; ++kt)
            afrag_hl(h_hi, h_lo, (size_t)r * 64 + kt * 32 + g16 * 8, ah[kt], al[kt]);
        float po[4][4] = {{0.f,0.f,0.f,0.f},{0.f,0.f,0.f,0.f},{0.f,0.f,0.f,0.f},{0.f,0.f,0.f,0.f}};
#pragma unroll
        for (int s = 0; s < 4; ++s) {
            floatx4 acc = {0.f, 0.f, 0.f, 0.f};
#pragma unroll
            for (int kt = 0; kt < 2; ++kt) acc = mm3(ah[kt], al[kt], W1H[s][kt], W1L[s][kt], acc);
#pragma unroll
            for (int i = 0; i < 4; ++i) {
                float act = leaky(acc[i] + b1v[s]);
                po[i][0] += act * w2v[s].x;
                po[i][1] += act * w2v[s].y;
                po[i][2] += act * w2v[s].z;
                po[i][3] += act * w2v[s].w;
            }
        }
#pragma unroll
        for (int i = 0; i < 4; ++i)
#pragma unroll
            for (int o = 0; o < 4; ++o) {
                po[i][o] += __shfl_xor(po[i][o], 1, 64);
                po[i][o] += __shfl_xor(po[i][o], 2, 64);
                po[i][o] += __shfl_xor(po[i][o], 4, 64);
                po[i][o] += __shfl_xor(po[i][o], 8, 64);
            }
        if (l15 == 0) {
#pragma unroll
            for (int i = 0; i < 4; ++i)
#pragma unroll
                for (int o = 0; o < 4; ++o)
                    red[wid][ms * 16 + g16 * 4 + i][o] = po[i][o];
        }
    }
    __syncthreads();
    int tid = threadIdx.x;
    int row = tid >> 2, o = tid & 3;
    float sum = red[0][row][o] + red[1][row][o] + red[2][row][o] + red[3][row][o];
    int r = rbase + row;
    if (r < N_NODES) out[(size_t)r * 4 + o] = fabsf(sum + b2[o]);
}

// ========== fc_net head ==========
__global__ __launch_bounds__(256) void k_fc_net(
    float* __restrict__ out, const u16* __restrict__ g_hi, const u16* __restrict__ g_lo,
    const u16* __restrict__ wfh, const u16* __restrict__ wfl,
    const float* __restrict__ b1, const float* __restrict__ W2, const float* __restrict__ b2)
{
    __shared__ float red[4][64][4];
    int lane = threadIdx.x & 63, wid = threadIdx.x >> 6;
    int g16 = lane >> 4, l15 = lane & 15;
    int rbase = blockIdx.x * 64;
    int cs = wid * 16 + l15;

    bhalf8 W1H[2], W1L[2];
#pragma unroll
    for (int kt = 0; kt < 2; ++kt) {
        int fo = OFF_FC1E + ((kt * 64 + cs) * 4 + g16) * 8;
        W1H[kt] = ldw(wfh, fo); W1L[kt] = ldw(wfl, fo);
    }
    float4 w2v = *(const float4*)(W2 + cs * 4);
    float b1v = b1[cs];

#pragma unroll
    for (int ms = 0; ms < 4; ++ms) {
        int r = min(rbase + ms * 16 + l15, N_NETS - 1);
        bhalf8 ah[2], al[2];
#pragma unroll
        for (int kt = 0; kt < 2; ++kt)
            afrag_hl(g_hi, g_lo, (size_t)r * 64 + kt * 32 + g16 * 8, ah[kt], al[kt]);
        floatx4 acc = {0.f, 0.f, 0.f, 0.f};
#pragma unroll
        for (int kt = 0; kt < 2; ++kt) acc = mm3(ah[kt], al[kt], W1H[kt], W1L[kt], acc);
        float po[4][4];
#pragma unroll
        for (int i = 0; i < 4; ++i) {
            float act = leaky(acc[i] + b1v);
            po[i][0] = act * w2v.x;
            po[i][1] = act * w2v.y;
            po[i][2] = act * w2v.z;
            po[i][3] = act * w2v.w;
        }
#pragma unroll
        for (int i = 0; i < 4; ++i)
#pragma unroll
            for (int o = 0; o < 4; ++o) {
                po[i][o] += __shfl_xor(po[i][o], 1, 64);
                po[i][o] += __shfl_xor(po[i][o], 2, 64);
                po[i][o] += __shfl_xor(po[i][o], 4, 64);
                po[i][o] += __shfl_xor(po[i][o], 8, 64);
            }
        if (l15 == 0) {
#pragma unroll
            for (int i = 0; i < 4; ++i)
#pragma unroll
                for (int o = 0; o < 4; ++o)
                    red[wid][ms * 16 + g16 * 4 + i][o] = po[i][o];
        }
    }
    __syncthreads();
    int tid = threadIdx.x;
    int row = tid >> 2, o = tid & 3;
    float sum = red[0][row][o] + red[1][row][o] + red[2][row][o] + red[3][row][o];
    int r = rbase + row;
    if (r < N_NETS) out[(size_t)r * 4 + o] = fabsf(sum + b2[o]);
}

extern "C" void kernel_launch(void* const* d_in, const int* in_sizes, int n_in,
                              void* d_out, int out_size, void* d_ws, size_t ws_size,
                              hipStream_t stream)
{
    const float* node_features = (const float*)d_in[0];
    const float* net_features  = (const float*)d_in[1];
    const int*   src_nodes     = (const int*)d_in[2];
    const int*   sink_nodes    = (const int*)d_in[3];
    const int*   sink_nets     = (const int*)d_in[4];
    const float* edge_weight   = (const float*)d_in[5];
    const int*   batch         = (const int*)d_in[6];
    const float* ne_W1 = (const float*)d_in[7];
    const float* ne_b1 = (const float*)d_in[8];
    const float* ne_W2 = (const float*)d_in[9];
    const float* ne_b2 = (const float*)d_in[10];
    const float* te_W1 = (const float*)d_in[11];
    const float* te_b1 = (const float*)d_in[12];
    const float* te_W2 = (const float*)d_in[13];
    const float* te_b2 = (const float*)d_in[14];
    const float* vn_emb = (const float*)d_in[15];
    const float* conv_Wnet  = (const float*)d_in[16];
    const float* conv_bnet  = (const float*)d_in[17];
    const float* conv_Wnode = (const float*)d_in[18];
    const float* conv_bnode = (const float*)d_in[19];
    const float* vn_W1 = (const float*)d_in[20];
    const float* vn_b1 = (const float*)d_in[21];
    const float* vn_W2 = (const float*)d_in[22];
    const float* vn_b2 = (const float*)d_in[23];
    const float* fc1n_W = (const float*)d_in[24];
    const float* fc1n_b = (const float*)d_in[25];
    const float* fc2n_W = (const float*)d_in[26];
    const float* fc2n_b = (const float*)d_in[27];
    const float* fc1e_W = (const float*)d_in[28];
    const float* fc1e_b = (const float*)d_in[29];
    const float* fc2e_W = (const float*)d_in[30];
    const float* fc2e_b = (const float*)d_in[31];

    float* out_node = (float*)d_out;
    float* out_net  = out_node + (size_t)N_NODES * 4;

    // ---------- workspace (256B-aligned bump allocator) ----------
    char* wsp = (char*)d_ws;
    size_t used = 0;
    auto alloc = [&](size_t bytes) -> char* {
        char* r = wsp + used;
        used += (bytes + 255) & ~(size_t)255;
        return r;
    };
    u16* h_hi = (u16*)alloc((size_t)N_NODES * 64 * 2);
    u16* h_lo = (u16*)alloc((size_t)N_NODES * 64 * 2);
    u16* g_hi = (u16*)alloc((size_t)N_NETS * 64 * 2);
    u16* g_lo = (u16*)alloc((size_t)N_NETS * 64 * 2);
    u16* s_hi = (u16*)alloc((size_t)N_NODES * 64 * 2);
    u16* s_lo = (u16*)alloc((size_t)N_NODES * 64 * 2);
    u16* wfh  = (u16*)alloc((size_t)W_TOTAL * 2);
    u16* wfl  = (u16*)alloc((size_t)W_TOTAL * 2);
    float* vn     = (float*)alloc((size_t)NUM_VN * EMB * 4);
    float* pooled = (float*)alloc((size_t)NUM_VN * EMB * 4);
    int* net_start  = (int*)alloc((size_t)(N_NETS + 1) * 4);
    int* node_start = (int*)alloc((size_t)(N_NODES + 1) * 4);
    int* src_start  = (int*)alloc((size_t)(N_NODES + 1) * 4);
    int* vn_start   = (int*)alloc((size_t)(NUM_VN + 1) * 4);
    int2* e_pack  = (int2*)alloc((size_t)E_SINK * 8);
    int2* e2_pack = (int2*)alloc((size_t)E_SINK * 8);
    int* s_net  = (int*)alloc((size_t)N_NETS * 4);
    int* b_node = (int*)alloc((size_t)N_NODES * 4);
    const int CNT_TOTAL = N_NETS + N_NODES + N_NODES + NUM_VN;
    int* cnt  = (int*)alloc((size_t)CNT_TOTAL * 4);
    int* bsum = (int*)alloc(2048 * 4);
    int* cnt_net  = cnt;
    int* cnt_node = cnt + N_NETS;
    int* cnt_src  = cnt_node + N_NODES;
    int* cnt_vn   = cnt_src + N_NODES;

    // optional f32 mirrors (tiered on remaining workspace)
    float* g_raw = nullptr;
    if (used + (size_t)N_NETS * 64 * 4 + 256 <= ws_size)
        g_raw = (float*)alloc((size_t)N_NETS * 64 * 4);
    float* h_f32 = nullptr;
    if (used + (size_t)N_NODES * 64 * 4 + 256 <= ws_size)
        h_f32 = (float*)alloc((size_t)N_NODES * 64 * 4);

    const int nodeTiles = (N_NODES + 63) / 64;
    const int netTiles  = (N_NETS + 63) / 64;
    const int vnBlocks  = (NUM_VN + 3) / 4;
    const int vnElemBlocks  = (NUM_VN * EMB + 255) / 256;
    const int addVnBlocks  = (N_NODES * 8 + 255) / 256;
    const int edgeThreadBlocks = (E_SINK + 255) / 256;
    const int miscThreadBlocks = (N_NODES + 255) / 256;
    const int netWaveBlocks  = (N_NETS + 3) / 4;
    const int nodeWaveBlocks = (N_NODES + 3) / 4;
    const int prepBlocks = (W_TOTAL + 255) / 256;

    // ---------- CSR build ----------
    hipMemsetAsync(cnt, 0, (size_t)CNT_TOTAL * sizeof(int), stream);
    k_hist_edges<<<edgeThreadBlocks, 256, 0, stream>>>(sink_nets, sink_nodes, cnt_net, cnt_node);
    k_hist_misc<<<miscThreadBlocks, 256, 0, stream>>>(src_nodes, batch, cnt_src, cnt_vn);

    auto scan = [&](int* cnt_arr, int n, int* start_arr) {
        int nb = (n + 255) / 256;
        k_scan1<<<nb, 256, 0, stream>>>(cnt_arr, n, bsum);
        k_scan2<<<1, 256, 0, stream>>>(bsum, nb);
        k_scan3<<<nb, 256, 0, stream>>>(cnt_arr, n, bsum, start_arr);
    };
    scan(cnt_net, N_NETS, net_start);
    scan(cnt_node, N_NODES, node_start);
    scan(cnt_src, N_NODES, src_start);
    scan(cnt_vn, NUM_VN, vn_start);

    hipMemsetAsync(cnt, 0, (size_t)CNT_TOTAL * sizeof(int), stream);
    k_fill_edges<<<edgeThreadBlocks, 256, 0, stream>>>(sink_nets, sink_nodes, edge_weight,
        net_start, node_start, cnt_net, cnt_node, e_pack, e2_pack);
    k_fill_misc<<<miscThreadBlocks, 256, 0, stream>>>(src_nodes, batch, src_start, vn_start,
        cnt_src, cnt_vn, s_net, b_node);

    // ---------- weight frags + encoders ----------
    k_prep_w<<<prepBlocks, 256, 0, stream>>>(ne_W1, ne_W2, te_W1, te_W2,
                                             conv_Wnet, conv_Wnode, fc1n_W, fc1e_W, wfh, wfl);
    k_node_enc<<<nodeTiles, 256, 0, stream>>>(node_features, wfh, wfl, ne_b1, ne_b2,
                                              h_hi, h_lo, h_f32);
    k_net_enc<<<netTiles, 256, 0, stream>>>(net_features, wfh, wfl, te_b1, te_b2, g_hi, g_lo);
    k_vn_init<<<vnElemBlocks, 256, 0, stream>>>(vn, vn_emb);

    // ---------- layers ----------
    for (int l = 0; l < 3; ++l) {
        k_add_vn<<<addVnBlocks, 256, 0, stream>>>(h_hi, h_lo, h_f32, vn, batch);

        if (h_f32)
            k_gather_agg<true><<<netWaveBlocks, 256, 0, stream>>>(s_hi, s_lo, h_hi, h_lo, h_f32,
                                                                  net_start, e_pack);
        else
            k_gather_agg<false><<<netWaveBlocks, 256, 0, stream>>>(s_hi, s_lo, h_hi, h_lo, h_f32,
                                                                   net_start, e_pack);

        k_conv_net<<<netTiles, 256, 0, stream>>>(g_hi, g_lo, g_raw, h_hi, h_lo, s_hi, s_lo,
            src_nodes, wfh, wfl, OFF_CWNET + l * 12288, conv_bnet + (size_t)l * 64);

        if (g_raw)
            k_gather_back<true><<<nodeWaveBlocks, 256, 0, stream>>>(s_hi, s_lo, g_hi, g_lo, g_raw,
                src_start, s_net, node_start, e2_pack);
        else
            k_gather_back<false><<<nodeWaveBlocks, 256, 0, stream>>>(s_hi, s_lo, g_hi, g_lo, g_raw,
                src_start, s_net, node_start, e2_pack);

        k_conv_node<<<nodeTiles, 256, 0, stream>>>(h_hi, h_lo, h_f32, s_hi, s_lo,
            wfh, wfl, OFF_CWNODE + l * 8192, conv_bnode + (size_t)l * 64);

        if (l < 2) {
            if (h_f32)
                k_pool_gather<true><<<NUM_VN, 256, 0, stream>>>(pooled, h_hi, h_lo, h_f32,
                                                                vn_start, b_node);
            else
                k_pool_gather<false><<<NUM_VN, 256, 0, stream>>>(pooled, h_hi, h_lo, h_f32,
                                                                 vn_start, b_node);
            k_vn_update<<<vnBlocks, 256, 0, stream>>>(vn, pooled,
                vn_W1 + (size_t)l * 64 * 64, vn_b1 + (size_t)l * 64,
                vn_W2 + (size_t)l * 64 * 64, vn_b2 + (size_t)l * 64);
        }
    }

    // ---------- heads ----------
    k_fc_node<<<nodeTiles, 256, 0, stream>>>(out_node, h_hi, h_lo, wfh, wfl,
                                             fc1n_b, fc2n_W, fc2n_b);
    k_fc_net<<<netTiles, 256, 0, stream>>>(out_net, g_hi, g_lo, wfh, wfl,
                                           fc1e_b, fc2e_W, fc2e_b);
}

// Round 9
// 1678.525 us; speedup vs baseline: 1.7023x; 1.0600x over previous
//
#include <hip/hip_runtime.h>
#include <cstdint>

static constexpr int N_NODES = 300000;
static constexpr int N_NETS  = 200000;
static constexpr int E_SINK  = 1000000;
static constexpr int NODE_DIM = 32;
static constexpr int NET_DIM  = 16;
static constexpr int EMB = 64;
static constexpr int NUM_VN = 1000;
#define SLOPE 0.01f

typedef __attribute__((ext_vector_type(8))) short bhalf8;
typedef __attribute__((ext_vector_type(4))) float floatx4;
typedef unsigned short u16;

__device__ __forceinline__ float leaky(float x) { return x >= 0.f ? x : SLOPE * x; }

// ---------- RNE split (weights, one-time prep) ----------
__device__ __forceinline__ unsigned bf16_rne(float x) {
    unsigned u = __float_as_uint(x);
    return (u + 0x7FFFu + ((u >> 16) & 1u)) >> 16;
}
__device__ __forceinline__ void split1(float x, u16& hh, u16& ll) {
    unsigned hb = bf16_rne(x);
    float fh = __uint_as_float(hb << 16);
    unsigned lb = bf16_rne(x - fh);
    hh = (u16)hb; ll = (u16)lb;
}

// ---------- cheap truncation split (activation loads) ----------
__device__ __forceinline__ void csplit8(const float* x, bhalf8& ah, bhalf8& al) {
#pragma unroll
    for (int e = 0; e < 8; ++e) {
        unsigned u = __float_as_uint(x[e]);
        ah[e] = (short)(u >> 16);
        float d = x[e] - __uint_as_float(u & 0xFFFF0000u);
        al[e] = (short)(__float_as_uint(d) >> 16);
    }
}
template<bool LK>
__device__ __forceinline__ void afrag32(const float* rowp, int kbase, bhalf8& ah, bhalf8& al) {
    float4 v0 = *(const float4*)(rowp + kbase);
    float4 v1 = *(const float4*)(rowp + kbase + 4);
    float x[8] = {v0.x, v0.y, v0.z, v0.w, v1.x, v1.y, v1.z, v1.w};
    if (LK) {
#pragma unroll
        for (int e = 0; e < 8; ++e) x[e] = leaky(x[e]);
    }
    csplit8(x, ah, al);
}
__device__ __forceinline__ void afragl(const float* tp, bhalf8& ah, bhalf8& al) {
    float4 v0 = *(const float4*)tp;
    float4 v1 = *(const float4*)(tp + 4);
    float x[8] = {v0.x, v0.y, v0.z, v0.w, v1.x, v1.y, v1.z, v1.w};
    csplit8(x, ah, al);
}

__device__ __forceinline__ floatx4 mm3(bhalf8 ah, bhalf8 al, bhalf8 wh, bhalf8 wl, floatx4 c) {
    c = __builtin_amdgcn_mfma_f32_16x16x32_bf16(ah, wh, c, 0, 0, 0);
    c = __builtin_amdgcn_mfma_f32_16x16x32_bf16(ah, wl, c, 0, 0, 0);
    c = __builtin_amdgcn_mfma_f32_16x16x32_bf16(al, wh, c, 0, 0, 0);
    return c;
}

// ============ weight fragment prep ============
static constexpr int OFF_NEW1 = 0;
static constexpr int OFF_NEW2 = 4096;
static constexpr int OFF_TEW1 = 12288;
static constexpr int OFF_TEW2 = 14336;
static constexpr int OFF_CWNET = 18432;
static constexpr int OFF_CWNODE = 55296;
static constexpr int OFF_FC1N = 79872;
static constexpr int OFF_FC1E = 96256;
static constexpr int W_TOTAL  = 100352;

__global__ void k_prep_w(const float* __restrict__ neW1, const float* __restrict__ neW2,
                         const float* __restrict__ teW1, const float* __restrict__ teW2,
                         const float* __restrict__ cWnet, const float* __restrict__ cWnode,
                         const float* __restrict__ fc1n, const float* __restrict__ fc1e,
                         u16* __restrict__ wfh, u16* __restrict__ wfl)
{
    int i = blockIdx.x * 256 + threadIdx.x;
    if (i >= W_TOTAL) return;
    int r, ncols, K; const float* src;
    if (i < OFF_NEW2)        { r = i;             src = neW1;  ncols = 128; K = 32; }
    else if (i < OFF_TEW1)   { r = i - OFF_NEW2;  src = neW2;  ncols = 64;  K = 128; }
    else if (i < OFF_TEW2)   { r = i - OFF_TEW1;  src = teW1;  ncols = 64;  K = 16; }
    else if (i < OFF_CWNET)  { r = i - OFF_TEW2;  src = teW2;  ncols = 64;  K = 64; }
    else if (i < OFF_CWNODE) { int t = i - OFF_CWNET;  int l = t / 12288; r = t % 12288;
                               src = cWnet + (size_t)l * 192 * 64; ncols = 64; K = 192; }
    else if (i < OFF_FC1N)   { int t = i - OFF_CWNODE; int l = t / 8192;  r = t % 8192;
                               src = cWnode + (size_t)l * 128 * 64; ncols = 64; K = 128; }
    else if (i < OFF_FC1E)   { r = i - OFF_FC1N;  src = fc1n;  ncols = 256; K = 64; }
    else                     { r = i - OFF_FC1E;  src = fc1e;  ncols = 64;  K = 64; }
    int e = r & 7, g = (r >> 3) & 3;
    int cidx = r >> 5;
    int col = cidx % ncols, kt = cidx / ncols;
    int k = kt * 32 + g * 8 + e;
    float v = (k < K) ? src[(size_t)k * ncols + col] : 0.f;
    u16 hh, ll; split1(v, hh, ll);
    wfh[i] = hh; wfl[i] = ll;
}

__device__ __forceinline__ bhalf8 ldw(const u16* p, int idx) {
    return *(const bhalf8*)(p + idx);
}

// ===================== CSR build =====================
__global__ void k_hist_edges(const int* __restrict__ sink_nets, const int* __restrict__ sink_nodes,
                             int* __restrict__ cnt_net, int* __restrict__ cnt_node)
{
    int e = blockIdx.x * 256 + threadIdx.x;
    if (e >= E_SINK) return;
    atomicAdd(&cnt_net[sink_nets[e]], 1);
    atomicAdd(&cnt_node[sink_nodes[e]], 1);
}

__global__ void k_hist_misc(const int* __restrict__ src_nodes, const int* __restrict__ batch,
                            int* __restrict__ cnt_src, int* __restrict__ cnt_vn)
{
    int i = blockIdx.x * 256 + threadIdx.x;
    if (i < N_NETS) atomicAdd(&cnt_src[src_nodes[i]], 1);
    if (i < N_NODES) atomicAdd(&cnt_vn[batch[i]], 1);
}

__global__ void k_scan1(const int* __restrict__ cnt, int n, int* __restrict__ bsum) {
    __shared__ int s[256];
    int i = blockIdx.x * 256 + threadIdx.x;
    s[threadIdx.x] = (i < n) ? cnt[i] : 0;
    __syncthreads();
    for (int off = 128; off; off >>= 1) {
        if (threadIdx.x < off) s[threadIdx.x] += s[threadIdx.x + off];
        __syncthreads();
    }
    if (threadIdx.x == 0) bsum[blockIdx.x] = s[0];
}

__global__ void k_scan2(int* __restrict__ data, int n) {
    __shared__ int s[256];
    __shared__ int carry_s;
    int tid = threadIdx.x;
    if (tid == 0) carry_s = 0;
    __syncthreads();
    for (int base = 0; base < n; base += 256) {
        int i = base + tid;
        int v = (i < n) ? data[i] : 0;
        s[tid] = v;
        __syncthreads();
        for (int off = 1; off < 256; off <<= 1) {
            int t = (tid >= off) ? s[tid - off] : 0;
            __syncthreads();
            s[tid] += t;
            __syncthreads();
        }
        int excl = s[tid] - v + carry_s;
        if (i < n) data[i] = excl;
        __syncthreads();
        if (tid == 255) carry_s = excl + v;
        __syncthreads();
    }
}

__global__ void k_scan3(const int* __restrict__ cnt, int n, const int* __restrict__ bsum,
                        int* __restrict__ start) {
    __shared__ int s[256];
    int i = blockIdx.x * 256 + threadIdx.x;
    int v = (i < n) ? cnt[i] : 0;
    s[threadIdx.x] = v;
    __syncthreads();
    for (int off = 1; off < 256; off <<= 1) {
        int t = (threadIdx.x >= off) ? s[threadIdx.x - off] : 0;
        __syncthreads();
        s[threadIdx.x] += t;
        __syncthreads();
    }
    int excl = s[threadIdx.x] - v + bsum[blockIdx.x];
    if (i < n) start[i] = excl;
    if (i == n - 1) start[n] = excl + v;
}

__global__ void k_fill_edges(const int* __restrict__ sink_nets, const int* __restrict__ sink_nodes,
                             const float* __restrict__ ew,
                             const int* __restrict__ net_start, const int* __restrict__ node_start,
                             int* __restrict__ cur_net, int* __restrict__ cur_node,
                             int2* __restrict__ e_pack, int2* __restrict__ e2_pack)
{
    int e = blockIdx.x * 256 + threadIdx.x;
    if (e >= E_SINK) return;
    int tn = sink_nets[e], dn = sink_nodes[e];
    int wbits = __float_as_int(ew[e]);
    int p = net_start[tn] + atomicAdd(&cur_net[tn], 1);
    e_pack[p] = make_int2(dn, wbits);
    int q = node_start[dn] + atomicAdd(&cur_node[dn], 1);
    e2_pack[q] = make_int2(tn, wbits);
}

__global__ void k_fill_misc(const int* __restrict__ src_nodes, const int* __restrict__ batch,
                            const int* __restrict__ src_start, const int* __restrict__ vn_start,
                            int* __restrict__ cur_src, int* __restrict__ cur_vn,
                            int* __restrict__ s_net, int* __restrict__ b_node)
{
    int i = blockIdx.x * 256 + threadIdx.x;
    if (i < N_NETS) {
        int d = src_nodes[i];
        int p = src_start[d] + atomicAdd(&cur_src[d], 1);
        s_net[p] = i;
    }
    if (i < N_NODES) {
        int v = batch[i];
        int p = vn_start[v] + atomicAdd(&cur_vn[v], 1);
        b_node[p] = i;
    }
}

// ===================== gathers (wave per row, 8 lanes/edge, all f32) =====================
__global__ __launch_bounds__(256) void k_gather_agg(
    float* __restrict__ agg, const float* __restrict__ h,
    const int* __restrict__ net_start, const int2* __restrict__ e_pack)
{
    int w = (blockIdx.x * 256 + threadIdx.x) >> 6;
    if (w >= N_NETS) return;
    int lane = threadIdx.x & 63;
    int grp = lane >> 3, l8 = lane & 7;
    int j0 = net_start[w], j1 = net_start[w + 1];
    float a[8] = {0.f, 0.f, 0.f, 0.f, 0.f, 0.f, 0.f, 0.f};
    for (int j = j0 + grp; j < j1; j += 8) {
        int2 pk = e_pack[j];
        float wt = __int_as_float(pk.y);
        const float4* rp = (const float4*)(h + (size_t)pk.x * 64 + l8 * 8);
        float4 v0 = rp[0], v1 = rp[1];
        a[0] += wt * v0.x; a[1] += wt * v0.y; a[2] += wt * v0.z; a[3] += wt * v0.w;
        a[4] += wt * v1.x; a[5] += wt * v1.y; a[6] += wt * v1.z; a[7] += wt * v1.w;
    }
#pragma unroll
    for (int e = 0; e < 8; ++e) {
        a[e] += __shfl_xor(a[e], 8, 64);
        a[e] += __shfl_xor(a[e], 16, 64);
        a[e] += __shfl_xor(a[e], 32, 64);
    }
    if (grp == 0) {
        float4* op = (float4*)(agg + (size_t)w * 64 + l8 * 8);
        op[0] = make_float4(a[0], a[1], a[2], a[3]);
        op[1] = make_float4(a[4], a[5], a[6], a[7]);
    }
}

// back = segsum(g_raw, src) + segsum(g_raw[sink_nets]*w, sink)  (g stored raw -> direct)
__global__ __launch_bounds__(256) void k_gather_back(
    float* __restrict__ back, const float* __restrict__ g,
    const int* __restrict__ src_start, const int* __restrict__ s_net,
    const int* __restrict__ node_start, const int2* __restrict__ e2_pack)
{
    int w = (blockIdx.x * 256 + threadIdx.x) >> 6;
    if (w >= N_NODES) return;
    int lane = threadIdx.x & 63;
    int grp = lane >> 3, l8 = lane & 7;
    float a[8] = {0.f, 0.f, 0.f, 0.f, 0.f, 0.f, 0.f, 0.f};
    int j0 = src_start[w], j1 = src_start[w + 1];
    for (int j = j0 + grp; j < j1; j += 8) {
        int idx = s_net[j];
        const float4* rp = (const float4*)(g + (size_t)idx * 64 + l8 * 8);
        float4 v0 = rp[0], v1 = rp[1];
        a[0] += v0.x; a[1] += v0.y; a[2] += v0.z; a[3] += v0.w;
        a[4] += v1.x; a[5] += v1.y; a[6] += v1.z; a[7] += v1.w;
    }
    j0 = node_start[w]; j1 = node_start[w + 1];
    for (int j = j0 + grp; j < j1; j += 8) {
        int2 pk = e2_pack[j];
        float wt = __int_as_float(pk.y);
        const float4* rp = (const float4*)(g + (size_t)pk.x * 64 + l8 * 8);
        float4 v0 = rp[0], v1 = rp[1];
        a[0] += wt * v0.x; a[1] += wt * v0.y; a[2] += wt * v0.z; a[3] += wt * v0.w;
        a[4] += wt * v1.x; a[5] += wt * v1.y; a[6] += wt * v1.z; a[7] += wt * v1.w;
    }
#pragma unroll
    for (int e = 0; e < 8; ++e) {
        a[e] += __shfl_xor(a[e], 8, 64);
        a[e] += __shfl_xor(a[e], 16, 64);
        a[e] += __shfl_xor(a[e], 32, 64);
    }
    if (grp == 0) {
        float4* op = (float4*)(back + (size_t)w * 64 + l8 * 8);
        op[0] = make_float4(a[0], a[1], a[2], a[3]);
        op[1] = make_float4(a[4], a[5], a[6], a[7]);
    }
}

// ================= pooling: block per VN (f32) =================
__global__ __launch_bounds__(256) void k_pool_gather(
    float* __restrict__ pooled, const float* __restrict__ h,
    const int* __restrict__ vn_start, const int* __restrict__ b_node)
{
    __shared__ float red[32][64];
    int tid = threadIdx.x;
    int grp = tid >> 3, l8 = tid & 7;
    int v = blockIdx.x;
    int j0 = vn_start[v], j1 = vn_start[v + 1];
    const float NEG = -__builtin_inff();
    float m[8] = {NEG, NEG, NEG, NEG, NEG, NEG, NEG, NEG};
    for (int j = j0 + grp; j < j1; j += 32) {
        int nd = b_node[j];
        const float4* rp = (const float4*)(h + (size_t)nd * 64 + l8 * 8);
        float4 v0 = rp[0], v1 = rp[1];
        m[0] = fmaxf(m[0], v0.x); m[1] = fmaxf(m[1], v0.y);
        m[2] = fmaxf(m[2], v0.z); m[3] = fmaxf(m[3], v0.w);
        m[4] = fmaxf(m[4], v1.x); m[5] = fmaxf(m[5], v1.y);
        m[6] = fmaxf(m[6], v1.z); m[7] = fmaxf(m[7], v1.w);
    }
#pragma unroll
    for (int e = 0; e < 8; ++e) red[grp][l8 * 8 + e] = m[e];
    __syncthreads();
    if (tid < 64) {
        float mm = red[0][tid];
#pragma unroll
        for (int q = 1; q < 32; ++q) mm = fmaxf(mm, red[q][tid]);
        pooled[(size_t)v * 64 + tid] = mm;
    }
}

// ================= encoders (f32 state out) =================
__global__ __launch_bounds__(256) void k_node_enc(
    const float* __restrict__ x, const u16* __restrict__ wfh, const u16* __restrict__ wfl,
    const float* __restrict__ b1, const float* __restrict__ b2, float* __restrict__ h)
{
    __shared__ __align__(16) float t[64][132];
    int lane = threadIdx.x & 63, wid = threadIdx.x >> 6;
    int g16 = lane >> 4, l15 = lane & 15;
    int rbase = blockIdx.x * 64;
    int cs = wid * 16 + l15;

    bhalf8 W1H[2], W1L[2];
#pragma unroll
    for (int s = 0; s < 2; ++s) {
        int col = wid * 16 + s * 64 + l15;
        int fo = OFF_NEW1 + (col * 4 + g16) * 8;
        W1H[s] = ldw(wfh, fo); W1L[s] = ldw(wfl, fo);
    }
    bhalf8 W2H[4], W2L[4];
#pragma unroll
    for (int kt = 0; kt < 4; ++kt) {
        int fo = OFF_NEW2 + ((kt * 64 + cs) * 4 + g16) * 8;
        W2H[kt] = ldw(wfh, fo); W2L[kt] = ldw(wfl, fo);
    }

#pragma unroll
    for (int ms = 0; ms < 4; ++ms) {
        int r = min(rbase + ms * 16 + l15, N_NODES - 1);
        bhalf8 ah, al;
        afrag32<false>(x + (size_t)r * NODE_DIM, g16 * 8, ah, al);
#pragma unroll
        for (int s = 0; s < 2; ++s) {
            floatx4 acc = {0.f, 0.f, 0.f, 0.f};
            acc = mm3(ah, al, W1H[s], W1L[s], acc);
            int hc = wid * 16 + s * 64 + l15;
            float bb = b1[hc];
#pragma unroll
            for (int i = 0; i < 4; ++i)
                t[ms * 16 + g16 * 4 + i][hc] = leaky(acc[i] + bb);
        }
    }
    __syncthreads();

    float bias = b2[cs];
#pragma unroll
    for (int ms = 0; ms < 4; ++ms) {
        floatx4 acc = {0.f, 0.f, 0.f, 0.f};
#pragma unroll
        for (int kt = 0; kt < 4; ++kt) {
            bhalf8 ah, al;
            afragl(&t[ms * 16 + l15][kt * 32 + g16 * 8], ah, al);
            acc = mm3(ah, al, W2H[kt], W2L[kt], acc);
        }
#pragma unroll
        for (int i = 0; i < 4; ++i) {
            int r = rbase + ms * 16 + g16 * 4 + i;
            if (r < N_NODES) h[(size_t)r * 64 + cs] = acc[i] + bias;
        }
    }
}

__global__ __launch_bounds__(256) void k_net_enc(
    const float* __restrict__ x, const u16* __restrict__ wfh, const u16* __restrict__ wfl,
    const float* __restrict__ b1, const float* __restrict__ b2, float* __restrict__ g)
{
    __shared__ __align__(16) float t[64][68];
    int lane = threadIdx.x & 63, wid = threadIdx.x >> 6;
    int g16 = lane >> 4, l15 = lane & 15;
    int rbase = blockIdx.x * 64;
    int cs = wid * 16 + l15;

    int fo = OFF_TEW1 + (cs * 4 + g16) * 8;
    bhalf8 W1H = ldw(wfh, fo), W1L = ldw(wfl, fo);
    bhalf8 W2H[2], W2L[2];
#pragma unroll
    for (int kt = 0; kt < 2; ++kt) {
        int f2 = OFF_TEW2 + ((kt * 64 + cs) * 4 + g16) * 8;
        W2H[kt] = ldw(wfh, f2); W2L[kt] = ldw(wfl, f2);
    }

#pragma unroll
    for (int ms = 0; ms < 4; ++ms) {
        int r = min(rbase + ms * 16 + l15, N_NETS - 1);
        bhalf8 ah = {0,0,0,0,0,0,0,0}, al = {0,0,0,0,0,0,0,0};
        if (g16 < 2) afrag32<false>(x + (size_t)r * NET_DIM, g16 * 8, ah, al);
        floatx4 acc = {0.f, 0.f, 0.f, 0.f};
        acc = mm3(ah, al, W1H, W1L, acc);
        float bb = b1[cs];
#pragma unroll
        for (int i = 0; i < 4; ++i)
            t[ms * 16 + g16 * 4 + i][cs] = leaky(acc[i] + bb);
    }
    __syncthreads();

    float bias = b2[cs];
#pragma unroll
    for (int ms = 0; ms < 4; ++ms) {
        floatx4 acc = {0.f, 0.f, 0.f, 0.f};
#pragma unroll
        for (int kt = 0; kt < 2; ++kt) {
            bhalf8 ah, al;
            afragl(&t[ms * 16 + l15][kt * 32 + g16 * 8], ah, al);
            acc = mm3(ah, al, W2H[kt], W2L[kt], acc);
        }
#pragma unroll
        for (int i = 0; i < 4; ++i) {
            int r = rbase + ms * 16 + g16 * 4 + i;
            if (r < N_NETS) g[(size_t)r * 64 + cs] = acc[i] + bias;   // raw
        }
    }
}

// ================= misc elementwise =================
__global__ void k_vn_init(float* __restrict__ vn, const float* __restrict__ vn_emb) {
    int idx = blockIdx.x * blockDim.x + threadIdx.x;
    if (idx < NUM_VN * EMB) vn[idx] = vn_emb[idx & 63];
}

__global__ void k_add_vn(float4* __restrict__ h4, const float* __restrict__ vn,
                         const int* __restrict__ batch) {
    int idx = blockIdx.x * blockDim.x + threadIdx.x;
    if (idx >= N_NODES * 16) return;
    int n = idx >> 4, c4 = idx & 15;
    const float4* vr = (const float4*)(vn + (size_t)batch[n] * 64);
    float4 hv = h4[idx], vv = vr[c4];
    h4[idx] = make_float4(hv.x + vv.x, hv.y + vv.y, hv.z + vv.z, hv.w + vv.w);
}

// ========== conv_net: g_new = cat(g|leaky, h[src], agg) @ W + b  (stored RAW f32) ==========
__global__ __launch_bounds__(256) void k_conv_net(
    float* __restrict__ g, const float* __restrict__ h, const float* __restrict__ s,
    const int* __restrict__ src,
    const u16* __restrict__ wfh, const u16* __restrict__ wfl, int wbase,
    const float* __restrict__ b, int lk0)
{
    int lane = threadIdx.x & 63, wid = threadIdx.x >> 6;
    int g16 = lane >> 4, l15 = lane & 15;
    int rbase = blockIdx.x * 64;
    int cs = wid * 16 + l15;

    bhalf8 WH[6], WL[6];
#pragma unroll
    for (int kt = 0; kt < 6; ++kt) {
        int fo = wbase + ((kt * 64 + cs) * 4 + g16) * 8;
        WH[kt] = ldw(wfh, fo); WL[kt] = ldw(wfl, fo);
    }

    // prefetch own g rows (in-place hazard) then barrier
    bhalf8 GH[4][2], GL[4][2];
#pragma unroll
    for (int ms = 0; ms < 4; ++ms) {
        int r = min(rbase + ms * 16 + l15, N_NETS - 1);
        const float* rp = g + (size_t)r * 64;
#pragma unroll
        for (int kt = 0; kt < 2; ++kt) {
            if (lk0) afrag32<true>(rp, kt * 32 + g16 * 8, GH[ms][kt], GL[ms][kt]);
            else     afrag32<false>(rp, kt * 32 + g16 * 8, GH[ms][kt], GL[ms][kt]);
        }
    }
    __syncthreads();

    float bias = b[cs];
#pragma unroll
    for (int ms = 0; ms < 4; ++ms) {
        floatx4 acc = {0.f, 0.f, 0.f, 0.f};
#pragma unroll
        for (int kt = 0; kt < 2; ++kt) acc = mm3(GH[ms][kt], GL[ms][kt], WH[kt], WL[kt], acc);
        int ar = min(rbase + ms * 16 + l15, N_NETS - 1);
        const float* hp = h + (size_t)src[ar] * 64;
#pragma unroll
        for (int kt = 0; kt < 2; ++kt) {
            bhalf8 ah, al;
            afrag32<false>(hp, kt * 32 + g16 * 8, ah, al);
            acc = mm3(ah, al, WH[2 + kt], WL[2 + kt], acc);
        }
        const float* ap = s + (size_t)ar * 64;
#pragma unroll
        for (int kt = 0; kt < 2; ++kt) {
            bhalf8 ah, al;
            afrag32<false>(ap, kt * 32 + g16 * 8, ah, al);
            acc = mm3(ah, al, WH[4 + kt], WL[4 + kt], acc);
        }
#pragma unroll
        for (int i = 0; i < 4; ++i) {
            int r = rbase + ms * 16 + g16 * 4 + i;
            if (r < N_NETS) g[(size_t)r * 64 + cs] = acc[i] + bias;   // raw (pre-leaky)
        }
    }
}

// ========== conv_node: h_new = leaky(cat(h, back) @ W + b)  (stored f32) ==========
__global__ __launch_bounds__(256) void k_conv_node(
    float* __restrict__ h, const float* __restrict__ s,
    const u16* __restrict__ wfh, const u16* __restrict__ wfl, int wbase,
    const float* __restrict__ b)
{
    int lane = threadIdx.x & 63, wid = threadIdx.x >> 6;
    int g16 = lane >> 4, l15 = lane & 15;
    int rbase = blockIdx.x * 64;
    int cs = wid * 16 + l15;

    bhalf8 WH[4], WL[4];
#pragma unroll
    for (int kt = 0; kt < 4; ++kt) {
        int fo = wbase + ((kt * 64 + cs) * 4 + g16) * 8;
        WH[kt] = ldw(wfh, fo); WL[kt] = ldw(wfl, fo);
    }

    bhalf8 HH[4][2], HL[4][2];
#pragma unroll
    for (int ms = 0; ms < 4; ++ms) {
        int r = min(rbase + ms * 16 + l15, N_NODES - 1);
        const float* rp = h + (size_t)r * 64;
#pragma unroll
        for (int kt = 0; kt < 2; ++kt)
            afrag32<false>(rp, kt * 32 + g16 * 8, HH[ms][kt], HL[ms][kt]);
    }
    __syncthreads();

    float bias = b[cs];
#pragma unroll
    for (int ms = 0; ms < 4; ++ms) {
        floatx4 acc = {0.f, 0.f, 0.f, 0.f};
#pragma unroll
        for (int kt = 0; kt < 2; ++kt) acc = mm3(HH[ms][kt], HL[ms][kt], WH[kt], WL[kt], acc);
        int ar = min(rbase + ms * 16 + l15, N_NODES - 1);
        const float* bp = s + (size_t)ar * 64;
#pragma unroll
        for (int kt = 0; kt < 2; ++kt) {
            bhalf8 ah, al;
            afrag32<false>(bp, kt * 32 + g16 * 8, ah, al);
            acc = mm3(ah, al, WH[2 + kt], WL[2 + kt], acc);
        }
#pragma unroll
        for (int i = 0; i < 4; ++i) {
            int r = rbase + ms * 16 + g16 * 4 + i;
            if (r < N_NODES) h[(size_t)r * 64 + cs] = leaky(acc[i] + bias);
        }
    }
}

// ================= virtual-node MLP =================
__global__ __launch_bounds__(256) void k_vn_update(
    float* __restrict__ vn, const float* __restrict__ pooled,
    const float* __restrict__ W1, const float* __restrict__ b1,
    const float* __restrict__ W2, const float* __restrict__ b2)
{
    int wv = threadIdx.x >> 6, lane = threadIdx.x & 63;
    int v = blockIdx.x * 4 + wv;
    if (v >= NUM_VN) return;
    float p = pooled[(size_t)v * 64 + lane];
    float vv = vn[v * 64 + lane];
    float tmp = p + vv;
    float t1 = b1[lane];
#pragma unroll 16
    for (int k = 0; k < 64; ++k) t1 += __shfl(tmp, k, 64) * W1[k * 64 + lane];
    t1 = leaky(t1);
    float t2 = b2[lane];
#pragma unroll 16
    for (int k = 0; k < 64; ++k) t2 += __shfl(t1, k, 64) * W2[k * 64 + lane];
    vn[v * 64 + lane] = vv + t2;
}

// ========== fc_node head: 64 -> 256 (leaky) -> 4, abs ==========
__global__ __launch_bounds__(256) void k_fc_node(
    float* __restrict__ out, const float* __restrict__ h,
    const u16* __restrict__ wfh, const u16* __restrict__ wfl,
    const float* __restrict__ b1, const float* __restrict__ W2, const float* __restrict__ b2)
{
    __shared__ float red[4][64][4];
    int lane = threadIdx.x & 63, wid = threadIdx.x >> 6;
    int g16 = lane >> 4, l15 = lane & 15;
    int rbase = blockIdx.x * 64;

    bhalf8 W1H[4][2], W1L[4][2];
    float4 w2v[4];
    float b1v[4];
#pragma unroll
    for (int s = 0; s < 4; ++s) {
        int hc = wid * 16 + s * 64 + l15;
#pragma unroll
        for (int kt = 0; kt < 2; ++kt) {
            int fo = OFF_FC1N + ((kt * 256 + hc) * 4 + g16) * 8;
            W1H[s][kt] = ldw(wfh, fo); W1L[s][kt] = ldw(wfl, fo);
        }
        w2v[s] = *(const float4*)(W2 + hc * 4);
        b1v[s] = b1[hc];
    }

#pragma unroll
    for (int ms = 0; ms < 4; ++ms) {
        int r = min(rbase + ms * 16 + l15, N_NODES - 1);
        bhalf8 ah[2], al[2];
#pragma unroll
        for (int kt = 0; kt < 2; ++kt)
            afrag32<false>(h + (size_t)r * 64, kt * 32 + g16 * 8, ah[kt], al[kt]);
        float po[4][4] = {{0.f,0.f,0.f,0.f},{0.f,0.f,0.f,0.f},{0.f,0.f,0.f,0.f},{0.f,0.f,0.f,0.f}};
#pragma unroll
        for (int s = 0; s < 4; ++s) {
            floatx4 acc = {0.f, 0.f, 0.f, 0.f};
#pragma unroll
            for (int kt = 0; kt < 2; ++kt) acc = mm3(ah[kt], al[kt], W1H[s][kt], W1L[s][kt], acc);
#pragma unroll
            for (int i = 0; i < 4; ++i) {
                float act = leaky(acc[i] + b1v[s]);
                po[i][0] += act * w2v[s].x;
                po[i][1] += act * w2v[s].y;
                po[i][2] += act * w2v[s].z;
                po[i][3] += act * w2v[s].w;
            }
        }
#pragma unroll
        for (int i = 0; i < 4; ++i)
#pragma unroll
            for (int o = 0; o < 4; ++o) {
                po[i][o] += __shfl_xor(po[i][o], 1, 64);
                po[i][o] += __shfl_xor(po[i][o], 2, 64);
                po[i][o] += __shfl_xor(po[i][o], 4, 64);
                po[i][o] += __shfl_xor(po[i][o], 8, 64);
            }
        if (l15 == 0) {
#pragma unroll
            for (int i = 0; i < 4; ++i)
#pragma unroll
                for (int o = 0; o < 4; ++o)
                    red[wid][ms * 16 + g16 * 4 + i][o] = po[i][o];
        }
    }
    __syncthreads();
    int tid = threadIdx.x;
    int row = tid >> 2, o = tid & 3;
    float sum = red[0][row][o] + red[1][row][o] + red[2][row][o] + red[3][row][o];
    int r = rbase + row;
    if (r < N_NODES) out[(size_t)r * 4 + o] = fabsf(sum + b2[o]);
}

// ========== fc_net head: 64 -> 64 (leaky) -> 4, abs  (g raw -> leaky on load) ==========
__global__ __launch_bounds__(256) void k_fc_net(
    float* __restrict__ out, const float* __restrict__ g,
    const u16* __restrict__ wfh, const u16* __restrict__ wfl,
    const float* __restrict__ b1, const float* __restrict__ W2, const float* __restrict__ b2)
{
    __shared__ float red[4][64][4];
    int lane = threadIdx.x & 63, wid = threadIdx.x >> 6;
    int g16 = lane >> 4, l15 = lane & 15;
    int rbase = blockIdx.x * 64;
    int cs = wid * 16 + l15;

    bhalf8 W1H[2], W1L[2];
#pragma unroll
    for (int kt = 0; kt < 2; ++kt) {
        int fo = OFF_FC1E + ((kt * 64 + cs) * 4 + g16) * 8;
        W1H[kt] = ldw(wfh, fo); W1L[kt] = ldw(wfl, fo);
    }
    float4 w2v = *(const float4*)(W2 + cs * 4);
    float b1v = b1[cs];

#pragma unroll
    for (int ms = 0; ms < 4; ++ms) {
        int r = min(rbase + ms * 16 + l15, N_NETS - 1);
        bhalf8 ah[2], al[2];
#pragma unroll
        for (int kt = 0; kt < 2; ++kt)
            afrag32<true>(g + (size_t)r * 64, kt * 32 + g16 * 8, ah[kt], al[kt]);
        floatx4 acc = {0.f, 0.f, 0.f, 0.f};
#pragma unroll
        for (int kt = 0; kt < 2; ++kt) acc = mm3(ah[kt], al[kt], W1H[kt], W1L[kt], acc);
        float po[4][4];
#pragma unroll
        for (int i = 0; i < 4; ++i) {
            float act = leaky(acc[i] + b1v);
            po[i][0] = act * w2v.x;
            po[i][1] = act * w2v.y;
            po[i][2] = act * w2v.z;
            po[i][3] = act * w2v.w;
        }
#pragma unroll
        for (int i = 0; i < 4; ++i)
#pragma unroll
            for (int o = 0; o < 4; ++o) {
                po[i][o] += __shfl_xor(po[i][o], 1, 64);
                po[i][o] += __shfl_xor(po[i][o], 2, 64);
                po[i][o] += __shfl_xor(po[i][o], 4, 64);
                po[i][o] += __shfl_xor(po[i][o], 8, 64);
            }
        if (l15 == 0) {
#pragma unroll
            for (int i = 0; i < 4; ++i)
#pragma unroll
                for (int o = 0; o < 4; ++o)
                    red[wid][ms * 16 + g16 * 4 + i][o] = po[i][o];
        }
    }
    __syncthreads();
    int tid = threadIdx.x;
    int row = tid >> 2, o = tid & 3;
    float sum = red[0][row][o] + red[1][row][o] + red[2][row][o] + red[3][row][o];
    int r = rbase + row;
    if (r < N_NETS) out[(size_t)r * 4 + o] = fabsf(sum + b2[o]);
}

extern "C" void kernel_launch(void* const* d_in, const int* in_sizes, int n_in,
                              void* d_out, int out_size, void* d_ws, size_t ws_size,
                              hipStream_t stream)
{
    const float* node_features = (const float*)d_in[0];
    const float* net_features  = (const float*)d_in[1];
    const int*   src_nodes     = (const int*)d_in[2];
    const int*   sink_nodes    = (const int*)d_in[3];
    const int*   sink_nets     = (const int*)d_in[4];
    const float* edge_weight   = (const float*)d_in[5];
    const int*   batch         = (const int*)d_in[6];
    const float* ne_W1 = (const float*)d_in[7];
    const float* ne_b1 = (const float*)d_in[8];
    const float* ne_W2 = (const float*)d_in[9];
    const float* ne_b2 = (const float*)d_in[10];
    const float* te_W1 = (const float*)d_in[11];
    const float* te_b1 = (const float*)d_in[12];
    const float* te_W2 = (const float*)d_in[13];
    const float* te_b2 = (const float*)d_in[14];
    const float* vn_emb = (const float*)d_in[15];
    const float* conv_Wnet  = (const float*)d_in[16];
    const float* conv_bnet  = (const float*)d_in[17];
    const float* conv_Wnode = (const float*)d_in[18];
    const float* conv_bnode = (const float*)d_in[19];
    const float* vn_W1 = (const float*)d_in[20];
    const float* vn_b1 = (const float*)d_in[21];
    const float* vn_W2 = (const float*)d_in[22];
    const float* vn_b2 = (const float*)d_in[23];
    const float* fc1n_W = (const float*)d_in[24];
    const float* fc1n_b = (const float*)d_in[25];
    const float* fc2n_W = (const float*)d_in[26];
    const float* fc2n_b = (const float*)d_in[27];
    const float* fc1e_W = (const float*)d_in[28];
    const float* fc1e_b = (const float*)d_in[29];
    const float* fc2e_W = (const float*)d_in[30];
    const float* fc2e_b = (const float*)d_in[31];

    float* out_node = (float*)d_out;
    float* out_net  = out_node + (size_t)N_NODES * 4;

    // ---------- workspace (256B-aligned bump allocator), all-f32 state ----------
    char* wsp = (char*)d_ws;
    size_t used = 0;
    auto alloc = [&](size_t bytes) -> char* {
        char* r = wsp + used;
        used += (bytes + 255) & ~(size_t)255;
        return r;
    };
    float* h  = (float*)alloc((size_t)N_NODES * 64 * 4);   // 76.8 MB
    float* g  = (float*)alloc((size_t)N_NETS * 64 * 4);    // 51.2 MB (raw, pre-leaky)
    float* s  = (float*)alloc((size_t)N_NODES * 64 * 4);   // 76.8 MB (agg then back)
    u16* wfh  = (u16*)alloc((size_t)W_TOTAL * 2);
    u16* wfl  = (u16*)alloc((size_t)W_TOTAL * 2);
    float* vn     = (float*)alloc((size_t)NUM_VN * EMB * 4);
    float* pooled = (float*)alloc((size_t)NUM_VN * EMB * 4);
    int* net_start  = (int*)alloc((size_t)(N_NETS + 1) * 4);
    int* node_start = (int*)alloc((size_t)(N_NODES + 1) * 4);
    int* src_start  = (int*)alloc((size_t)(N_NODES + 1) * 4);
    int* vn_start   = (int*)alloc((size_t)(NUM_VN + 1) * 4);
    int2* e_pack  = (int2*)alloc((size_t)E_SINK * 8);
    int2* e2_pack = (int2*)alloc((size_t)E_SINK * 8);
    int* s_net  = (int*)alloc((size_t)N_NETS * 4);
    int* b_node = (int*)alloc((size_t)N_NODES * 4);
    const int CNT_TOTAL = N_NETS + N_NODES + N_NODES + NUM_VN;
    int* cnt  = (int*)alloc((size_t)CNT_TOTAL * 4);
    int* bsum = (int*)alloc(2048 * 4);
    int* cnt_net  = cnt;
    int* cnt_node = cnt + N_NETS;
    int* cnt_src  = cnt_node + N_NODES;
    int* cnt_vn   = cnt_src + N_NODES;

    const int nodeTiles = (N_NODES + 63) / 64;
    const int netTiles  = (N_NETS + 63) / 64;
    const int vnBlocks  = (NUM_VN + 3) / 4;
    const int vnElemBlocks  = (NUM_VN * EMB + 255) / 256;
    const int addVnBlocks  = (N_NODES * 16 + 255) / 256;
    const int edgeThreadBlocks = (E_SINK + 255) / 256;
    const int miscThreadBlocks = (N_NODES + 255) / 256;
    const int netWaveBlocks  = (N_NETS + 3) / 4;
    const int nodeWaveBlocks = (N_NODES + 3) / 4;
    const int prepBlocks = (W_TOTAL + 255) / 256;

    // ---------- CSR build ----------
    hipMemsetAsync(cnt, 0, (size_t)CNT_TOTAL * sizeof(int), stream);
    k_hist_edges<<<edgeThreadBlocks, 256, 0, stream>>>(sink_nets, sink_nodes, cnt_net, cnt_node);
    k_hist_misc<<<miscThreadBlocks, 256, 0, stream>>>(src_nodes, batch, cnt_src, cnt_vn);

    auto scan = [&](int* cnt_arr, int n, int* start_arr) {
        int nb = (n + 255) / 256;
        k_scan1<<<nb, 256, 0, stream>>>(cnt_arr, n, bsum);
        k_scan2<<<1, 256, 0, stream>>>(bsum, nb);
        k_scan3<<<nb, 256, 0, stream>>>(cnt_arr, n, bsum, start_arr);
    };
    scan(cnt_net, N_NETS, net_start);
    scan(cnt_node, N_NODES, node_start);
    scan(cnt_src, N_NODES, src_start);
    scan(cnt_vn, NUM_VN, vn_start);

    hipMemsetAsync(cnt, 0, (size_t)CNT_TOTAL * sizeof(int), stream);
    k_fill_edges<<<edgeThreadBlocks, 256, 0, stream>>>(sink_nets, sink_nodes, edge_weight,
        net_start, node_start, cnt_net, cnt_node, e_pack, e2_pack);
    k_fill_misc<<<miscThreadBlocks, 256, 0, stream>>>(src_nodes, batch, src_start, vn_start,
        cnt_src, cnt_vn, s_net, b_node);

    // ---------- weight frags + encoders ----------
    k_prep_w<<<prepBlocks, 256, 0, stream>>>(ne_W1, ne_W2, te_W1, te_W2,
                                             conv_Wnet, conv_Wnode, fc1n_W, fc1e_W, wfh, wfl);
    k_node_enc<<<nodeTiles, 256, 0, stream>>>(node_features, wfh, wfl, ne_b1, ne_b2, h);
    k_net_enc<<<netTiles, 256, 0, stream>>>(net_features, wfh, wfl, te_b1, te_b2, g);
    k_vn_init<<<vnElemBlocks, 256, 0, stream>>>(vn, vn_emb);

    // ---------- layers ----------
    for (int l = 0; l < 3; ++l) {
        k_add_vn<<<addVnBlocks, 256, 0, stream>>>((float4*)h, vn, batch);

        k_gather_agg<<<netWaveBlocks, 256, 0, stream>>>(s, h, net_start, e_pack);
        k_conv_net<<<netTiles, 256, 0, stream>>>(g, h, s, src_nodes,
            wfh, wfl, OFF_CWNET + l * 12288, conv_bnet + (size_t)l * 64, l > 0 ? 1 : 0);

        k_gather_back<<<nodeWaveBlocks, 256, 0, stream>>>(s, g,
            src_start, s_net, node_start, e2_pack);
        k_conv_node<<<nodeTiles, 256, 0, stream>>>(h, s,
            wfh, wfl, OFF_CWNODE + l * 8192, conv_bnode + (size_t)l * 64);

        if (l < 2) {
            k_pool_gather<<<NUM_VN, 256, 0, stream>>>(pooled, h, vn_start, b_node);
            k_vn_update<<<vnBlocks, 256, 0, stream>>>(vn, pooled,
                vn_W1 + (size_t)l * 64 * 64, vn_b1 + (size_t)l * 64,
                vn_W2 + (size_t)l * 64 * 64, vn_b2 + (size_t)l * 64);
        }
    }

    // ---------- heads ----------
    k_fc_node<<<nodeTiles, 256, 0, stream>>>(out_node, h, wfh, wfl, fc1n_b, fc2n_W, fc2n_b);
    k_fc_net<<<netTiles, 256, 0, stream>>>(out_net, g, wfh, wfl, fc1e_b, fc2e_W, fc2e_b);
}